// Round 1
// 285.286 us; speedup vs baseline: 1.1405x; 1.1405x over previous
//
#include <hip/hip_runtime.h>
#include <hip/hip_bf16.h>
#include <cstdint>
#include <cstddef>

// B=4, S=2048, D=1024, H=16, DH=64.  M = B*S = 8192.
// cast->bf16; fused QKV GEMM (MFMA, Q pre-scaled by 0.125*log2e) -> split heads;
// V transpose; MFMA flash attention with PAIRED q-tiles: block = (pair p, bh)
// processes q-tiles p and 15-p over ONE shared K/V stream -> constant 34
// tile-units/block, 512 blocks = exactly 2 resident blocks/CU, no tail.
// XCD-aware decode: bh % 8 == blockIdx.x % 8 so each XCD's L2 holds its 8
// heads' K+V^T (8 x 512 KB = 4 MB).  Inner pipeline unchanged: 32 q-rows/wave,
// S^T = K Q^T, no-max softmax, PV deferred one tile.
// Workspace: 92,274,688 B (VT aliases xb's dead region).

typedef unsigned short u16;
typedef __bf16 bf16x8 __attribute__((ext_vector_type(8)));
typedef float  f32x4  __attribute__((ext_vector_type(4)));

__device__ __forceinline__ u16 f2bf(float f) {
  unsigned u = __float_as_uint(f);
  unsigned r = u + 0x7fffu + ((u >> 16) & 1u);   // RNE
  return (u16)(r >> 16);
}

// async global->LDS, 16B per lane (dest = wave-uniform base + lane*16)
__device__ __forceinline__ void llds16(const u16* g, u16* l) {
  __builtin_amdgcn_global_load_lds(
      (const __attribute__((address_space(1))) void*)g,
      (__attribute__((address_space(3))) void*)l, 16, 0, 0);
}

// ---------------- cast fp32 -> bf16 ----------------
__global__ void cast_bf16_kernel(const float* __restrict__ in, u16* __restrict__ out, int n4) {
  int i = blockIdx.x * blockDim.x + threadIdx.x;
  if (i >= n4) return;
  float4 f = ((const float4*)in)[i];
  ushort4 u;
  u.x = f2bf(f.x); u.y = f2bf(f.y); u.z = f2bf(f.z); u.w = f2bf(f.w);
  ((ushort4*)out)[i] = u;
}

// 4 weight matrices in one launch (grid.y selects)
__global__ void cast4_kernel(const float* __restrict__ a, const float* __restrict__ b,
                             const float* __restrict__ c, const float* __restrict__ d,
                             u16* __restrict__ oa, u16* __restrict__ ob,
                             u16* __restrict__ oc, u16* __restrict__ od, int n4) {
  const int w = blockIdx.y;
  const float* src = (w == 0) ? a : (w == 1) ? b : (w == 2) ? c : d;
  u16* dst = (w == 0) ? oa : (w == 1) ? ob : (w == 2) ? oc : od;
  int i = blockIdx.x * blockDim.x + threadIdx.x;
  if (i >= n4) return;
  float4 f = ((const float4*)src)[i];
  ushort4 u;
  u.x = f2bf(f.x); u.y = f2bf(f.y); u.z = f2bf(f.z); u.w = f2bf(f.w);
  ((ushort4*)dst)[i] = u;
}

// ---------------- bf16 MFMA GEMM (m97-style), C = A*Bw^T + bias ----------------
__global__ __launch_bounds__(256) void gemm_bt(
    const u16* __restrict__ A, const u16* __restrict__ Bw,
    const float* __restrict__ b0, const float* __restrict__ b1, const float* __restrict__ b2,
    u16* __restrict__ qkv_out, float* __restrict__ flat_out,
    int K, int mode)
{
  __shared__ u16 As[128 * 32];
  __shared__ u16 Bs[128 * 32];

  const int tid = threadIdx.x;
  const int n0 = blockIdx.x * 128;
  const int m0 = blockIdx.y * 128;

  const int srow = tid >> 2;
  const int soff = (tid & 3) * 8;
  const u16* gA0 = A  + (size_t)(m0 + srow) * K + soff;
  const u16* gA1 = gA0 + (size_t)64 * K;
  const u16* gB0 = Bw + (size_t)(n0 + srow) * K + soff;
  const u16* gB1 = gB0 + (size_t)64 * K;
  u16* lA0 = As + tid * 8;
  u16* lA1 = As + 2048 + tid * 8;
  u16* lB0 = Bs + tid * 8;
  u16* lB1 = Bs + 2048 + tid * 8;

  const int lane = tid & 63;
  const int wave = tid >> 6;
  const int wm = (wave >> 1) * 64;
  const int wn = (wave & 1) * 64;
  const int fr = lane & 15;
  const int k8 = (lane >> 4) * 8;

  f32x4 zero = {0.f, 0.f, 0.f, 0.f};
  f32x4 acc[4][4];
#pragma unroll
  for (int i = 0; i < 4; i++)
#pragma unroll
    for (int j = 0; j < 4; j++) acc[i][j] = zero;

  for (int k0 = 0; k0 < K; k0 += 32) {
    llds16(gA0 + k0, lA0);
    llds16(gA1 + k0, lA1);
    llds16(gB0 + k0, lB0);
    llds16(gB1 + k0, lB1);
    __syncthreads();
    bf16x8 af[4], bfr[4];
#pragma unroll
    for (int i = 0; i < 4; i++)
      af[i] = *(const bf16x8*)(As + (wm + i * 16 + fr) * 32 + k8);
#pragma unroll
    for (int j = 0; j < 4; j++)
      bfr[j] = *(const bf16x8*)(Bs + (wn + j * 16 + fr) * 32 + k8);
#pragma unroll
    for (int i = 0; i < 4; i++)
#pragma unroll
      for (int j = 0; j < 4; j++)
        acc[i][j] = __builtin_amdgcn_mfma_f32_16x16x32_bf16(af[i], bfr[j], acc[i][j], 0, 0, 0);
    __syncthreads();
  }

  const int rbase = (lane >> 4) * 4;
  if (mode == 0) {
    const int which = n0 >> 10;
    const float* bias = (which == 0) ? b0 : ((which == 1) ? b1 : b2);
    const float post = (which == 0) ? 0.18033688011f : 1.0f;  // 0.125*log2(e)
    u16* outb = qkv_out + (size_t)which * 8388608;
#pragma unroll
    for (int j = 0; j < 4; j++) {
      const int nn = (n0 + wn + j * 16 + fr) & 1023;
      const float bb = bias[nn];
      const int h = nn >> 6, dh = nn & 63;
#pragma unroll
      for (int i = 0; i < 4; i++) {
#pragma unroll
        for (int r = 0; r < 4; r++) {
          const int m = m0 + wm + i * 16 + rbase + r;
          const int bI = m >> 11, s = m & 2047;
          outb[(((size_t)bI * 16 + h) * 2048 + s) * 64 + dh] = f2bf((acc[i][j][r] + bb) * post);
        }
      }
    }
  } else {
#pragma unroll
    for (int j = 0; j < 4; j++) {
      const int n = n0 + wn + j * 16 + fr;
      const float bb = b0[n];
#pragma unroll
      for (int i = 0; i < 4; i++) {
#pragma unroll
        for (int r = 0; r < 4; r++) {
          const int m = m0 + wm + i * 16 + rbase + r;
          flat_out[(size_t)m * 1024 + n] = acc[i][j][r] + bb;
        }
      }
    }
  }
}

// ---------------- V transpose: [BH][S][64] -> [BH][64][S] ----------------
__global__ __launch_bounds__(256) void transpose_v(const u16* __restrict__ V, u16* __restrict__ VT) {
  __shared__ u16 t_s[64 * 72];
  const int tid = threadIdx.x;
  const int st = blockIdx.x << 6;
  const int bh = blockIdx.y;
  const u16* src = V + ((size_t)bh * 2048 + st) * 64;
#pragma unroll
  for (int p = 0; p < 2; p++) {
    int i = p * 256 + tid;
    int row = i >> 3, ch = i & 7;
    bf16x8 v = *(const bf16x8*)(src + row * 64 + ch * 8);
    *(bf16x8*)(t_s + row * 72 + ch * 8) = v;
  }
  __syncthreads();
  u16* dst = VT + (size_t)bh * 131072 + st;
#pragma unroll
  for (int p = 0; p < 2; p++) {
    int i = p * 256 + tid;
    int dh = i >> 3, ch = i & 7;
    union { u16 s[8]; bf16x8 v; } u;
#pragma unroll
    for (int e = 0; e < 8; e++) u.s[e] = t_s[(ch * 8 + e) * 72 + dh];
    *(bf16x8*)(dst + (size_t)dh * 2048 + ch * 8) = u.v;
  }
}

// ---------------- MFMA flash attention: paired q-tiles, PV deferred ----------------
// Grid: 512 flat blocks = 8 xcd x (8 bh-hi x 8 pairs), block 256 = 4 waves.
// Block handles q-tiles qtA=p (small) and qtB=15-p (big) of head bh, sharing
// one K/V stream (jt = 0..2*qtB+1).  Per iteration: barrier; issue DMA
// K(jt+1),V(jt); deferred PV(jt-1) for B then A from resident P/V; S(jt) for
// B then A; softmax; write P.  Work per block = 34 tile-units, constant.
__global__ __launch_bounds__(256, 2) void attn_fa(
    const u16* __restrict__ Qb, const u16* __restrict__ Kb,
    const u16* __restrict__ VT, u16* __restrict__ Ob)
{
  __shared__ u16 k_s[2 * 4096];      // dbuf [kn][d], 16B-chunks XOR'd by row
  __shared__ u16 v_s[2 * 4096];      // dbuf [dn][k], same swizzle (lags K by 1 tile)
  __shared__ u16 p_s[2 * 9216];      // [tile][q(128)][key(72)] bf16 (wave-private rows)
  __shared__ float l_s[256];

  const int tid = threadIdx.x;
  const int lane = tid & 63;
  const int wave = tid >> 6;

  // decode: c = xcd + 8*(pair + 8*bh_hi); all 16 blocks of head bh share XCD bh%8
  const int c = (int)blockIdx.x;
  const int xcd = c & 7;
  const int rr_ = c >> 3;
  const int bh = xcd + ((rr_ >> 3) << 3);
  const int pr = rr_ & 7;
  const int qtA = pr;            // small tile (finishes early)
  const int qtB = 15 - pr;       // big tile (drives the K/V stream)

  const size_t head = (size_t)bh << 17;
  const int fr = lane & 15;
  const int g = lane >> 4;
  const int k8 = g << 3;
  const int q0A = qtA << 7;
  const int q0B = qtB << 7;
  const int wrow = wave << 5;

  // Q fragments (pre-scaled); loop-invariant B-operands, both tiles
  bf16x8 aqA[2][2], aqB[2][2];
#pragma unroll
  for (int f = 0; f < 2; f++) {
    const u16* qpA = Qb + head + (size_t)(q0A + wrow + (f << 4) + fr) * 64;
    aqA[f][0] = *(const bf16x8*)(qpA + k8);
    aqA[f][1] = *(const bf16x8*)(qpA + 32 + k8);
    const u16* qpB = Qb + head + (size_t)(q0B + wrow + (f << 4) + fr) * 64;
    aqB[f][0] = *(const bf16x8*)(qpB + k8);
    aqB[f][1] = *(const bf16x8*)(qpB + 32 + k8);
  }

  // ---- hoisted lane-constant offsets ----
  const int r0 = tid >> 3, c0 = tid & 7;
  const int r1 = 32 + r0;
  const int koff0 = r0 * 64 + (((c0 ^ r0) & 7) << 3);     // K staging src offsets
  const int koff1 = r1 * 64 + (((c0 ^ r1) & 7) << 3);
  const int voff0 = r0 * 2048 + (((c0 ^ r0) & 7) << 3);   // V^T staging src offsets
  const int voff1 = r1 * 2048 + (((c0 ^ r1) & 7) << 3);
  int kaddr[4][2], vaddr[2][4];                           // fragment-read offsets
#pragma unroll
  for (int j = 0; j < 4; j++) {
    const int kn = (j << 4) + fr;
    kaddr[j][0] = kn * 64 + (((g ^ kn) & 7) << 3);
    kaddr[j][1] = kn * 64 + ((((g + 4) ^ kn) & 7) << 3);
#pragma unroll
    for (int s2 = 0; s2 < 2; s2++)
      vaddr[s2][j] = kn * 64 + ((((s2 << 2) + g) ^ (kn & 7)) << 3);
  }
  u16* const prowA0 = p_s + (wrow + fr) * 72;
  u16* const prowA1 = p_s + (wrow + 16 + fr) * 72;
  u16* const prowB0 = p_s + 9216 + (wrow + fr) * 72;
  u16* const prowB1 = p_s + 9216 + (wrow + 16 + fr) * 72;
  const u16* Kbase = Kb + head;
  const u16* Vbase = VT + head;

  auto issueK = [&](int jt2, int buf) {
    const u16* Kt = Kbase + ((size_t)jt2 << 12);
    llds16(Kt + koff0, k_s + (buf << 12) + tid * 8);
    llds16(Kt + koff1, k_s + (buf << 12) + 2048 + tid * 8);
  };
  auto issueV = [&](int jt2, int buf) {
    const u16* Vt = Vbase + (jt2 << 6);
    llds16(Vt + voff0, v_s + (buf << 12) + tid * 8);
    llds16(Vt + voff1, v_s + (buf << 12) + 2048 + tid * 8);
  };

  f32x4 oA[2][4], oB[2][4];
  const f32x4 zero = {0.f, 0.f, 0.f, 0.f};
#pragma unroll
  for (int f = 0; f < 2; f++)
#pragma unroll
    for (int j = 0; j < 4; j++) { oA[f][j] = zero; oB[f][j] = zero; }
  float lA[2] = {0.f, 0.f}, lB[2] = {0.f, 0.f};

  const int jmax = 2 * qtB + 1;                 // stream length (big tile)
  const int diagA = 2 * qtA + (wave >> 1);      // per-wave diagonal tiles
  const int diagB = 2 * qtB + (wave >> 1);

  auto do_pv = [&](const u16* vs, f32x4 (&oacc)[2][4], const u16* p0r, const u16* p1r) {
#pragma unroll
    for (int s2 = 0; s2 < 2; s2++) {
      const bf16x8 ap0 = *(const bf16x8*)(p0r + (s2 << 5) + k8);
      const bf16x8 ap1 = *(const bf16x8*)(p1r + (s2 << 5) + k8);
#pragma unroll
      for (int j = 0; j < 4; j++) {
        const bf16x8 bv = *(const bf16x8*)(vs + vaddr[s2][j]);
        oacc[0][j] = __builtin_amdgcn_mfma_f32_16x16x32_bf16(ap0, bv, oacc[0][j], 0, 0, 0);
        oacc[1][j] = __builtin_amdgcn_mfma_f32_16x16x32_bf16(ap1, bv, oacc[1][j], 0, 0, 0);
      }
    }
  };

  auto do_s = [&](const u16* ks, int jt, bool dodiag, int q0t,
                  const bf16x8 (&aqt)[2][2], float (&lr)[2], u16* p0r, u16* p1r) {
    f32x4 s_acc[2][4];
#pragma unroll
    for (int f = 0; f < 2; f++)
#pragma unroll
      for (int j = 0; j < 4; j++) s_acc[f][j] = zero;
#pragma unroll
    for (int j = 0; j < 4; j++) {
      const bf16x8 ka0 = *(const bf16x8*)(ks + kaddr[j][0]);
      const bf16x8 ka1 = *(const bf16x8*)(ks + kaddr[j][1]);
      s_acc[0][j] = __builtin_amdgcn_mfma_f32_16x16x32_bf16(ka0, aqt[0][0], s_acc[0][j], 0, 0, 0);
      s_acc[0][j] = __builtin_amdgcn_mfma_f32_16x16x32_bf16(ka1, aqt[0][1], s_acc[0][j], 0, 0, 0);
      s_acc[1][j] = __builtin_amdgcn_mfma_f32_16x16x32_bf16(ka0, aqt[1][0], s_acc[1][j], 0, 0, 0);
      s_acc[1][j] = __builtin_amdgcn_mfma_f32_16x16x32_bf16(ka1, aqt[1][1], s_acc[1][j], 0, 0, 0);
    }
#pragma unroll
    for (int f = 0; f < 2; f++) {
      const int qa = q0t + wrow + (f << 4) + fr;
      u16* prow = (f == 0) ? p0r : p1r;
      if (dodiag) {
#pragma unroll
        for (int j = 0; j < 4; j++) {
          const int ka = (jt << 6) + (j << 4) + (g << 2);
          float p0 = (ka + 0 > qa) ? 0.f : __builtin_amdgcn_exp2f(s_acc[f][j][0]);
          float p1 = (ka + 1 > qa) ? 0.f : __builtin_amdgcn_exp2f(s_acc[f][j][1]);
          float p2 = (ka + 2 > qa) ? 0.f : __builtin_amdgcn_exp2f(s_acc[f][j][2]);
          float p3 = (ka + 3 > qa) ? 0.f : __builtin_amdgcn_exp2f(s_acc[f][j][3]);
          lr[f] += (p0 + p1) + (p2 + p3);
          union { __hip_bfloat162 h; unsigned u; } ca, cb;
          ca.h = __float22bfloat162_rn(make_float2(p0, p1));
          cb.h = __float22bfloat162_rn(make_float2(p2, p3));
          *(uint2*)(prow + (j << 4) + (g << 2)) = make_uint2(ca.u, cb.u);
        }
      } else {
#pragma unroll
        for (int j = 0; j < 4; j++) {
          float p0 = __builtin_amdgcn_exp2f(s_acc[f][j][0]);
          float p1 = __builtin_amdgcn_exp2f(s_acc[f][j][1]);
          float p2 = __builtin_amdgcn_exp2f(s_acc[f][j][2]);
          float p3 = __builtin_amdgcn_exp2f(s_acc[f][j][3]);
          lr[f] += (p0 + p1) + (p2 + p3);
          union { __hip_bfloat162 h; unsigned u; } ca, cb;
          ca.h = __float22bfloat162_rn(make_float2(p0, p1));
          cb.h = __float22bfloat162_rn(make_float2(p2, p3));
          *(uint2*)(prow + (j << 4) + (g << 2)) = make_uint2(ca.u, cb.u);
        }
      }
    }
  };

  issueK(0, 0);   // prime K pipeline (V(0) issued inside iteration 0)

  for (int jt = 0; jt <= jmax; jt++) {
    const int buf = jt & 1;
    __syncthreads();                       // K(jt) + V(jt-1) landed; LDS reads drained
    if (jt < jmax) issueK(jt + 1, buf ^ 1);
    issueV(jt, buf);
    if (jt > 0) {
      const u16* vprev = v_s + ((buf ^ 1) << 12);
      if (jt - 1 <= diagB) do_pv(vprev, oB, prowB0, prowB1);   // deferred PV, big tile
      if (jt - 1 <= diagA) do_pv(vprev, oA, prowA0, prowA1);   // deferred PV, small tile
    }
    if (jt <= diagB) do_s(k_s + (buf << 12), jt, jt == diagB, q0B, aqB, lB, prowB0, prowB1);
    if (jt <= diagA) do_s(k_s + (buf << 12), jt, jt == diagA, q0A, aqA, lA, prowA0, prowA1);
  }
  __syncthreads();                         // V(jmax) landed
  if (diagB == jmax) do_pv(v_s + ((jmax & 1) << 12), oB, prowB0, prowB1);  // waves 2,3 final PV (B)
  // tile A's final PV always completes inside the loop (diagA+1 <= 16 <= jmax)

  // epilogue: reduce l (q-col lives in lanes fr, fr+16, fr+32, fr+48)
#pragma unroll
  for (int f = 0; f < 2; f++) {
    float la = lA[f];
    la += __shfl_xor(la, 16);
    la += __shfl_xor(la, 32);
    if (g == 0) l_s[wrow + (f << 4) + fr] = la;        // tile A slots [0,128)
    float lb = lB[f];
    lb += __shfl_xor(lb, 16);
    lb += __shfl_xor(lb, 32);
    if (g == 0) l_s[128 + wrow + (f << 4) + fr] = lb;  // tile B slots [128,256)
  }
  const int b = bh >> 4, h = bh & 15;
#pragma unroll
  for (int f = 0; f < 2; f++) {
#pragma unroll
    for (int r = 0; r < 4; r++) {
      const int qloc = wrow + (f << 4) + (g << 2) + r;
      const float invA = 1.f / l_s[qloc];
      const float invB = 1.f / l_s[128 + qloc];
      const int qA_abs = q0A + qloc;
      const int qB_abs = q0B + qloc;
#pragma unroll
      for (int j = 0; j < 4; j++) {
        Ob[((size_t)b * 2048 + qA_abs) * 1024 + (h << 6) + (j << 4) + fr] =
            f2bf(oA[f][j][r] * invA);
        Ob[((size_t)b * 2048 + qB_abs) * 1024 + (h << 6) + (j << 4) + fr] =
            f2bf(oB[f][j][r] * invB);
      }
    }
  }
}

// ---------------- launch ----------------
extern "C" void kernel_launch(void* const* d_in, const int* in_sizes, int n_in,
                              void* d_out, int out_size, void* d_ws, size_t ws_size,
                              hipStream_t stream) {
  const float* x  = (const float*)d_in[0];
  const float* Wq = (const float*)d_in[1];
  const float* bq = (const float*)d_in[2];
  const float* Wk = (const float*)d_in[3];
  const float* bk = (const float*)d_in[4];
  const float* Wv = (const float*)d_in[5];
  const float* bv = (const float*)d_in[6];
  const float* Wo = (const float*)d_in[7];
  const float* bo = (const float*)d_in[8];
  float* out = (float*)d_out;

  char* ws = (char*)d_ws;
  u16* xb    = (u16*)(ws);                 // 16 MB; dead after QKV GEMM
  u16* vT    = (u16*)(ws);                 // aliases xb: V^T [BH][64][S]
  u16* wqkv  = (u16*)(ws + 16777216);      // 6 MB packed q|k|v weights
  u16* wo    = (u16*)(ws + 23068672);      // 2 MB
  u16* qkv   = (u16*)(ws + 25165824);      // 48 MB, [3][BH][S][DH]
  u16* attnb = (u16*)(ws + 75497472);      // 16 MB, [B,S,D]
  // total ws: 92,274,688 B

  cast_bf16_kernel<<<8192, 256, 0, stream>>>(x, xb, 2097152);
  cast4_kernel<<<dim3(1024, 4), 256, 0, stream>>>(
      Wq, Wk, Wv, Wo, wqkv, wqkv + 1048576, wqkv + 2097152, wo, 262144);

  // fused QKV projection: M=8192, N=3072, K=1024 (Q chunk pre-scaled)
  gemm_bt<<<dim3(24, 64), 256, 0, stream>>>(xb, wqkv, bq, bk, bv, qkv, nullptr, 1024, 0);

  // V [BH][S][64] -> V^T [BH][64][S]  (xb dead; vT aliases it)
  transpose_v<<<dim3(32, 64), 256, 0, stream>>>(qkv + 16777216, vT);

  // MFMA flash attention (paired q-tiles, 512 balanced blocks, XCD-grouped)
  attn_fa<<<dim3(512), 256, 0, stream>>>(qkv, qkv + 8388608, vT, attnb);

  // output projection: M=8192, N=1024, K=1024 -> fp32 d_out
  gemm_bt<<<dim3(8, 64), 256, 0, stream>>>(attnb, wo, bo, bo, bo, nullptr, out, 1024, 1);
}

// Round 2
// 269.173 us; speedup vs baseline: 1.2088x; 1.0599x over previous
//
#include <hip/hip_runtime.h>
#include <hip/hip_bf16.h>
#include <cstdint>
#include <cstddef>

// B=4, S=2048, D=1024, H=16, DH=64.  M = B*S = 8192.
// cast->bf16; fused QKV GEMM via 256x256 8-phase pipelined MFMA kernel
// (T2 swizzle + T3/T4 counted-vmcnt phases + T5 setprio, raw s_barrier only);
// V transpose; MFMA flash attention with PAIRED q-tiles (constant work/block,
// 512 blocks, XCD-grouped); output GEMM on the 128^2 kernel.
// Workspace: 92,274,688 B (VT aliases xb's dead region).

typedef unsigned short u16;
typedef __bf16 bf16x8 __attribute__((ext_vector_type(8)));
typedef float  f32x4  __attribute__((ext_vector_type(4)));

__device__ __forceinline__ u16 f2bf(float f) {
  unsigned u = __float_as_uint(f);
  unsigned r = u + 0x7fffu + ((u >> 16) & 1u);   // RNE
  return (u16)(r >> 16);
}

// async global->LDS, 16B per lane (dest = wave-uniform base + lane*16)
__device__ __forceinline__ void llds16(const u16* g, u16* l) {
  __builtin_amdgcn_global_load_lds(
      (const __attribute__((address_space(1))) void*)g,
      (__attribute__((address_space(3))) void*)l, 16, 0, 0);
}

// ---------------- cast fp32 -> bf16 ----------------
__global__ void cast_bf16_kernel(const float* __restrict__ in, u16* __restrict__ out, int n4) {
  int i = blockIdx.x * blockDim.x + threadIdx.x;
  if (i >= n4) return;
  float4 f = ((const float4*)in)[i];
  ushort4 u;
  u.x = f2bf(f.x); u.y = f2bf(f.y); u.z = f2bf(f.z); u.w = f2bf(f.w);
  ((ushort4*)out)[i] = u;
}

// 4 weight matrices in one launch (grid.y selects)
__global__ void cast4_kernel(const float* __restrict__ a, const float* __restrict__ b,
                             const float* __restrict__ c, const float* __restrict__ d,
                             u16* __restrict__ oa, u16* __restrict__ ob,
                             u16* __restrict__ oc, u16* __restrict__ od, int n4) {
  const int w = blockIdx.y;
  const float* src = (w == 0) ? a : (w == 1) ? b : (w == 2) ? c : d;
  u16* dst = (w == 0) ? oa : (w == 1) ? ob : (w == 2) ? oc : od;
  int i = blockIdx.x * blockDim.x + threadIdx.x;
  if (i >= n4) return;
  float4 f = ((const float4*)src)[i];
  ushort4 u;
  u.x = f2bf(f.x); u.y = f2bf(f.y); u.z = f2bf(f.z); u.w = f2bf(f.w);
  ((ushort4*)dst)[i] = u;
}

// ---------------- 256x256 8-phase QKV GEMM: qkv = x * Wqkv^T + bias ----------------
// M=8192, N=3072, K=1024.  512 threads = 8 waves (2M x 4N); per-wave C = 128x64.
// LDS 128 KiB: buf{0,1} x [A0|A1|B0|B1] half-tiles (128 rows x 64 cols bf16,
// 16B chunks XOR-swizzled by row&7).  K-tile k lives in buf[k&1].
// Iteration t: phases 0-3 read buf0 (kt=2t), phases 4-7 read buf1 (kt=2t+1).
// Stages (1 half-tile = 2 global_load_lds/thread per phase):
//   p0:buf1.A1(2t+1) p1:buf1.B0 p2:buf1.B1 p3:buf0.A0(2t+2) p4:buf0.A1
//   p5:buf0.B0 p6:buf0.B1 p7:buf1.A0(2t+3)
// vmcnt(2) before trailing barrier of p3 and p7 (counted, never 0 mid-loop).
__global__ __launch_bounds__(512, 2) void gemm_qkv_256(
    const u16* __restrict__ A, const u16* __restrict__ Bw,
    const float* __restrict__ b0, const float* __restrict__ b1, const float* __restrict__ b2,
    u16* __restrict__ qkv_out)
{
  __shared__ u16 lds[65536];   // 128 KiB

  const int tid = threadIdx.x;
  const int lane = tid & 63;
  const int wave = tid >> 6;

  // XCD-bijective swizzle: 384 blocks = 48/XCD; within XCD n-tile fastest
  const int bid = (int)blockIdx.x;
  const int c2 = (bid & 7) * 48 + (bid >> 3);
  const int mt = c2 / 12;
  const int nt = c2 - mt * 12;
  const int m0 = mt << 8;
  const int n0 = nt << 8;

  const int warp_m = wave >> 2;       // 0..1
  const int warp_n = wave & 3;        // 0..3
  const int wm = warp_m << 7;
  const int wn = warp_n << 6;
  const int fr = lane & 15;
  const int g  = lane >> 4;           // 0..3

  // staging source (pre-swizzled global addr so linear LDS dest lands swizzled)
  const int srow = tid >> 3;                       // 0..63
  const int schk = ((tid & 7) ^ (srow & 7)) << 3;  // stored chunk -> logical col
  const u16* pA = A  + (size_t)(m0 + srow) * 1024 + schk;
  const u16* pB = Bw + (size_t)(n0 + srow) * 1024 + schk;

  // fragment-read swizzled chunk offsets (chunk = s*4+g, stored = chunk^(fr&7))
  const int rsw0 = ((g    ) ^ (fr & 7)) << 3;
  const int rsw1 = ((g ^ 4) ^ (fr & 7)) << 3;

  // read bases (include fr*64 row offset)
  const u16* Ab0 = lds + warp_m * 8192 + fr * 64;
  const u16* Bb0 = lds + 16384 + (warp_n >> 1) * 8192 + (warp_n & 1) * 4096 + fr * 64;
  const u16* Ab1 = Ab0 + 32768;
  const u16* Bb1 = Bb0 + 32768;

  f32x4 acc[8][4];
  const f32x4 zero = {0.f, 0.f, 0.f, 0.f};
#pragma unroll
  for (int i = 0; i < 8; i++)
#pragma unroll
    for (int j = 0; j < 4; j++) acc[i][j] = zero;

  bf16x8 a_[4][2];
  bf16x8 b_[4][2];

  auto stage = [&](int kt, int buf, int matBoff, int half, const u16* psrc) {
    const u16* src = psrc + (size_t)half * 131072 + (kt << 6);
    u16* dst = lds + buf * 32768 + matBoff + half * 8192 + tid * 8;
    llds16(src, dst);
    llds16(src + 65536, dst + 4096);
  };
  auto loadA = [&](const u16* Ab, int ib) {
#pragma unroll
    for (int ii = 0; ii < 4; ii++) {
      const u16* r = Ab + (ib + ii) * 1024;
      a_[ii][0] = *(const bf16x8*)(r + rsw0);
      a_[ii][1] = *(const bf16x8*)(r + rsw1);
    }
  };
  auto loadB2 = [&](const u16* Bb, int jb) {
#pragma unroll
    for (int jj = 0; jj < 2; jj++) {
      const u16* r = Bb + (jb + jj) * 1024;
      b_[jb + jj][0] = *(const bf16x8*)(r + rsw0);
      b_[jb + jj][1] = *(const bf16x8*)(r + rsw1);
    }
  };
  auto mfma8 = [&](int ib, int jb) {
    __builtin_amdgcn_s_setprio(1);
#pragma unroll
    for (int jj = 0; jj < 2; jj++)
#pragma unroll
      for (int ii = 0; ii < 4; ii++) {
        acc[ib+ii][jb+jj] = __builtin_amdgcn_mfma_f32_16x16x32_bf16(
            a_[ii][0], b_[jb+jj][0], acc[ib+ii][jb+jj], 0, 0, 0);
        acc[ib+ii][jb+jj] = __builtin_amdgcn_mfma_f32_16x16x32_bf16(
            a_[ii][1], b_[jb+jj][1], acc[ib+ii][jb+jj], 0, 0, 0);
      }
    __builtin_amdgcn_s_setprio(0);
  };

  // prologue: buf0 <- K-tile 0 (A0,A1,B0,B1), buf1.A0 <- K-tile 1
  stage(0, 0, 0,     0, pA);
  stage(0, 0, 0,     1, pA);
  stage(0, 0, 16384, 0, pB);
  stage(0, 0, 16384, 1, pB);
  stage(1, 1, 0,     0, pA);
  asm volatile("s_waitcnt vmcnt(2)" ::: "memory");
  __builtin_amdgcn_s_barrier();

  const int NTI = 8;   // K/128
  for (int t = 0; t < NTI; ++t) {
    const bool st = (t < NTI - 1);
    const int ka = 2 * t + 1;
    const int kb = 2 * t + 2;
    const int kc = 2 * t + 3;

    // ---- K-tile 2t from buf0 ----
    // p0
    loadA(Ab0, 0); loadB2(Bb0, 0);
    stage(ka, 1, 0, 1, pA);
    __builtin_amdgcn_s_barrier();
    mfma8(0, 0);
    __builtin_amdgcn_s_barrier();
    // p1
    loadB2(Bb0, 2);
    stage(ka, 1, 16384, 0, pB);
    __builtin_amdgcn_s_barrier();
    mfma8(0, 2);
    __builtin_amdgcn_s_barrier();
    // p2
    loadA(Ab0, 4);
    stage(ka, 1, 16384, 1, pB);
    __builtin_amdgcn_s_barrier();
    mfma8(4, 2);
    __builtin_amdgcn_s_barrier();
    // p3
    if (st) stage(kb, 0, 0, 0, pA);
    __builtin_amdgcn_s_barrier();
    mfma8(4, 0);
    if (st) { asm volatile("s_waitcnt vmcnt(2)" ::: "memory"); }
    else    { asm volatile("s_waitcnt vmcnt(0)" ::: "memory"); }
    __builtin_amdgcn_s_barrier();

    // ---- K-tile 2t+1 from buf1 ----
    // p4
    loadA(Ab1, 0); loadB2(Bb1, 0);
    if (st) stage(kb, 0, 0, 1, pA);
    __builtin_amdgcn_s_barrier();
    mfma8(0, 0);
    __builtin_amdgcn_s_barrier();
    // p5
    loadB2(Bb1, 2);
    if (st) stage(kb, 0, 16384, 0, pB);
    __builtin_amdgcn_s_barrier();
    mfma8(0, 2);
    __builtin_amdgcn_s_barrier();
    // p6
    loadA(Ab1, 4);
    if (st) stage(kb, 0, 16384, 1, pB);
    __builtin_amdgcn_s_barrier();
    mfma8(4, 2);
    __builtin_amdgcn_s_barrier();
    // p7
    if (st) stage(kc, 1, 0, 0, pA);
    __builtin_amdgcn_s_barrier();
    mfma8(4, 0);
    if (st) { asm volatile("s_waitcnt vmcnt(2)" ::: "memory"); }
    __builtin_amdgcn_s_barrier();
  }

  // epilogue: split-head scatter store with bias (+ Q pre-scale)
  const int rbase = g * 4;
  const int which = n0 >> 10;
  const float* bias = (which == 0) ? b0 : ((which == 1) ? b1 : b2);
  const float post = (which == 0) ? 0.18033688011f : 1.0f;  // 0.125*log2(e)
  u16* outb = qkv_out + (size_t)which * 8388608;
#pragma unroll
  for (int j = 0; j < 4; j++) {
    const int nn = (n0 + wn + j * 16 + fr) & 1023;
    const float bb = bias[nn];
    const int h = nn >> 6, dh = nn & 63;
#pragma unroll
    for (int i = 0; i < 8; i++) {
#pragma unroll
      for (int r = 0; r < 4; r++) {
        const int m = m0 + wm + i * 16 + rbase + r;
        const int bI = m >> 11, s = m & 2047;
        outb[(((size_t)bI * 16 + h) * 2048 + s) * 64 + dh] = f2bf((acc[i][j][r] + bb) * post);
      }
    }
  }
}

// ---------------- bf16 MFMA GEMM (m97-style), C = A*Bw^T + bias ----------------
__global__ __launch_bounds__(256) void gemm_bt(
    const u16* __restrict__ A, const u16* __restrict__ Bw,
    const float* __restrict__ b0, const float* __restrict__ b1, const float* __restrict__ b2,
    u16* __restrict__ qkv_out, float* __restrict__ flat_out,
    int K, int mode)
{
  __shared__ u16 As[128 * 32];
  __shared__ u16 Bs[128 * 32];

  const int tid = threadIdx.x;
  const int n0 = blockIdx.x * 128;
  const int m0 = blockIdx.y * 128;

  const int srow = tid >> 2;
  const int soff = (tid & 3) * 8;
  const u16* gA0 = A  + (size_t)(m0 + srow) * K + soff;
  const u16* gA1 = gA0 + (size_t)64 * K;
  const u16* gB0 = Bw + (size_t)(n0 + srow) * K + soff;
  const u16* gB1 = gB0 + (size_t)64 * K;
  u16* lA0 = As + tid * 8;
  u16* lA1 = As + 2048 + tid * 8;
  u16* lB0 = Bs + tid * 8;
  u16* lB1 = Bs + 2048 + tid * 8;

  const int lane = tid & 63;
  const int wave = tid >> 6;
  const int wm = (wave >> 1) * 64;
  const int wn = (wave & 1) * 64;
  const int fr = lane & 15;
  const int k8 = (lane >> 4) * 8;

  f32x4 zero = {0.f, 0.f, 0.f, 0.f};
  f32x4 acc[4][4];
#pragma unroll
  for (int i = 0; i < 4; i++)
#pragma unroll
    for (int j = 0; j < 4; j++) acc[i][j] = zero;

  for (int k0 = 0; k0 < K; k0 += 32) {
    llds16(gA0 + k0, lA0);
    llds16(gA1 + k0, lA1);
    llds16(gB0 + k0, lB0);
    llds16(gB1 + k0, lB1);
    __syncthreads();
    bf16x8 af[4], bfr[4];
#pragma unroll
    for (int i = 0; i < 4; i++)
      af[i] = *(const bf16x8*)(As + (wm + i * 16 + fr) * 32 + k8);
#pragma unroll
    for (int j = 0; j < 4; j++)
      bfr[j] = *(const bf16x8*)(Bs + (wn + j * 16 + fr) * 32 + k8);
#pragma unroll
    for (int i = 0; i < 4; i++)
#pragma unroll
      for (int j = 0; j < 4; j++)
        acc[i][j] = __builtin_amdgcn_mfma_f32_16x16x32_bf16(af[i], bfr[j], acc[i][j], 0, 0, 0);
    __syncthreads();
  }

  const int rbase = (lane >> 4) * 4;
  if (mode == 0) {
    const int which = n0 >> 10;
    const float* bias = (which == 0) ? b0 : ((which == 1) ? b1 : b2);
    const float post = (which == 0) ? 0.18033688011f : 1.0f;  // 0.125*log2(e)
    u16* outb = qkv_out + (size_t)which * 8388608;
#pragma unroll
    for (int j = 0; j < 4; j++) {
      const int nn = (n0 + wn + j * 16 + fr) & 1023;
      const float bb = bias[nn];
      const int h = nn >> 6, dh = nn & 63;
#pragma unroll
      for (int i = 0; i < 4; i++) {
#pragma unroll
        for (int r = 0; r < 4; r++) {
          const int m = m0 + wm + i * 16 + rbase + r;
          const int bI = m >> 11, s = m & 2047;
          outb[(((size_t)bI * 16 + h) * 2048 + s) * 64 + dh] = f2bf((acc[i][j][r] + bb) * post);
        }
      }
    }
  } else {
#pragma unroll
    for (int j = 0; j < 4; j++) {
      const int n = n0 + wn + j * 16 + fr;
      const float bb = b0[n];
#pragma unroll
      for (int i = 0; i < 4; i++) {
#pragma unroll
        for (int r = 0; r < 4; r++) {
          const int m = m0 + wm + i * 16 + rbase + r;
          flat_out[(size_t)m * 1024 + n] = acc[i][j][r] + bb;
        }
      }
    }
  }
}

// ---------------- V transpose: [BH][S][64] -> [BH][64][S] ----------------
__global__ __launch_bounds__(256) void transpose_v(const u16* __restrict__ V, u16* __restrict__ VT) {
  __shared__ u16 t_s[64 * 72];
  const int tid = threadIdx.x;
  const int st = blockIdx.x << 6;
  const int bh = blockIdx.y;
  const u16* src = V + ((size_t)bh * 2048 + st) * 64;
#pragma unroll
  for (int p = 0; p < 2; p++) {
    int i = p * 256 + tid;
    int row = i >> 3, ch = i & 7;
    bf16x8 v = *(const bf16x8*)(src + row * 64 + ch * 8);
    *(bf16x8*)(t_s + row * 72 + ch * 8) = v;
  }
  __syncthreads();
  u16* dst = VT + (size_t)bh * 131072 + st;
#pragma unroll
  for (int p = 0; p < 2; p++) {
    int i = p * 256 + tid;
    int dh = i >> 3, ch = i & 7;
    union { u16 s[8]; bf16x8 v; } u;
#pragma unroll
    for (int e = 0; e < 8; e++) u.s[e] = t_s[(ch * 8 + e) * 72 + dh];
    *(bf16x8*)(dst + (size_t)dh * 2048 + ch * 8) = u.v;
  }
}

// ---------------- MFMA flash attention: paired q-tiles, PV deferred ----------------
__global__ __launch_bounds__(256, 2) void attn_fa(
    const u16* __restrict__ Qb, const u16* __restrict__ Kb,
    const u16* __restrict__ VT, u16* __restrict__ Ob)
{
  __shared__ u16 k_s[2 * 4096];      // dbuf [kn][d], 16B-chunks XOR'd by row
  __shared__ u16 v_s[2 * 4096];      // dbuf [dn][k], same swizzle (lags K by 1 tile)
  __shared__ u16 p_s[2 * 9216];      // [tile][q(128)][key(72)] bf16 (wave-private rows)
  __shared__ float l_s[256];

  const int tid = threadIdx.x;
  const int lane = tid & 63;
  const int wave = tid >> 6;

  // decode: c = xcd + 8*(pair + 8*bh_hi); all 16 blocks of head bh share XCD bh%8
  const int c = (int)blockIdx.x;
  const int xcd = c & 7;
  const int rr_ = c >> 3;
  const int bh = xcd + ((rr_ >> 3) << 3);
  const int pr = rr_ & 7;
  const int qtA = pr;            // small tile (finishes early)
  const int qtB = 15 - pr;       // big tile (drives the K/V stream)

  const size_t head = (size_t)bh << 17;
  const int fr = lane & 15;
  const int g = lane >> 4;
  const int k8 = g << 3;
  const int q0A = qtA << 7;
  const int q0B = qtB << 7;
  const int wrow = wave << 5;

  bf16x8 aqA[2][2], aqB[2][2];
#pragma unroll
  for (int f = 0; f < 2; f++) {
    const u16* qpA = Qb + head + (size_t)(q0A + wrow + (f << 4) + fr) * 64;
    aqA[f][0] = *(const bf16x8*)(qpA + k8);
    aqA[f][1] = *(const bf16x8*)(qpA + 32 + k8);
    const u16* qpB = Qb + head + (size_t)(q0B + wrow + (f << 4) + fr) * 64;
    aqB[f][0] = *(const bf16x8*)(qpB + k8);
    aqB[f][1] = *(const bf16x8*)(qpB + 32 + k8);
  }

  const int r0 = tid >> 3, c0 = tid & 7;
  const int r1 = 32 + r0;
  const int koff0 = r0 * 64 + (((c0 ^ r0) & 7) << 3);
  const int koff1 = r1 * 64 + (((c0 ^ r1) & 7) << 3);
  const int voff0 = r0 * 2048 + (((c0 ^ r0) & 7) << 3);
  const int voff1 = r1 * 2048 + (((c0 ^ r1) & 7) << 3);
  int kaddr[4][2], vaddr[2][4];
#pragma unroll
  for (int j = 0; j < 4; j++) {
    const int kn = (j << 4) + fr;
    kaddr[j][0] = kn * 64 + (((g ^ kn) & 7) << 3);
    kaddr[j][1] = kn * 64 + ((((g + 4) ^ kn) & 7) << 3);
#pragma unroll
    for (int s2 = 0; s2 < 2; s2++)
      vaddr[s2][j] = kn * 64 + ((((s2 << 2) + g) ^ (kn & 7)) << 3);
  }
  u16* const prowA0 = p_s + (wrow + fr) * 72;
  u16* const prowA1 = p_s + (wrow + 16 + fr) * 72;
  u16* const prowB0 = p_s + 9216 + (wrow + fr) * 72;
  u16* const prowB1 = p_s + 9216 + (wrow + 16 + fr) * 72;
  const u16* Kbase = Kb + head;
  const u16* Vbase = VT + head;

  auto issueK = [&](int jt2, int buf) {
    const u16* Kt = Kbase + ((size_t)jt2 << 12);
    llds16(Kt + koff0, k_s + (buf << 12) + tid * 8);
    llds16(Kt + koff1, k_s + (buf << 12) + 2048 + tid * 8);
  };
  auto issueV = [&](int jt2, int buf) {
    const u16* Vt = Vbase + (jt2 << 6);
    llds16(Vt + voff0, v_s + (buf << 12) + tid * 8);
    llds16(Vt + voff1, v_s + (buf << 12) + 2048 + tid * 8);
  };

  f32x4 oA[2][4], oB[2][4];
  const f32x4 zero = {0.f, 0.f, 0.f, 0.f};
#pragma unroll
  for (int f = 0; f < 2; f++)
#pragma unroll
    for (int j = 0; j < 4; j++) { oA[f][j] = zero; oB[f][j] = zero; }
  float lA[2] = {0.f, 0.f}, lB[2] = {0.f, 0.f};

  const int jmax = 2 * qtB + 1;
  const int diagA = 2 * qtA + (wave >> 1);
  const int diagB = 2 * qtB + (wave >> 1);

  auto do_pv = [&](const u16* vs, f32x4 (&oacc)[2][4], const u16* p0r, const u16* p1r) {
#pragma unroll
    for (int s2 = 0; s2 < 2; s2++) {
      const bf16x8 ap0 = *(const bf16x8*)(p0r + (s2 << 5) + k8);
      const bf16x8 ap1 = *(const bf16x8*)(p1r + (s2 << 5) + k8);
#pragma unroll
      for (int j = 0; j < 4; j++) {
        const bf16x8 bv = *(const bf16x8*)(vs + vaddr[s2][j]);
        oacc[0][j] = __builtin_amdgcn_mfma_f32_16x16x32_bf16(ap0, bv, oacc[0][j], 0, 0, 0);
        oacc[1][j] = __builtin_amdgcn_mfma_f32_16x16x32_bf16(ap1, bv, oacc[1][j], 0, 0, 0);
      }
    }
  };

  auto do_s = [&](const u16* ks, int jt, bool dodiag, int q0t,
                  const bf16x8 (&aqt)[2][2], float (&lr)[2], u16* p0r, u16* p1r) {
    f32x4 s_acc[2][4];
#pragma unroll
    for (int f = 0; f < 2; f++)
#pragma unroll
      for (int j = 0; j < 4; j++) s_acc[f][j] = zero;
#pragma unroll
    for (int j = 0; j < 4; j++) {
      const bf16x8 ka0 = *(const bf16x8*)(ks + kaddr[j][0]);
      const bf16x8 ka1 = *(const bf16x8*)(ks + kaddr[j][1]);
      s_acc[0][j] = __builtin_amdgcn_mfma_f32_16x16x32_bf16(ka0, aqt[0][0], s_acc[0][j], 0, 0, 0);
      s_acc[0][j] = __builtin_amdgcn_mfma_f32_16x16x32_bf16(ka1, aqt[0][1], s_acc[0][j], 0, 0, 0);
      s_acc[1][j] = __builtin_amdgcn_mfma_f32_16x16x32_bf16(ka0, aqt[1][0], s_acc[1][j], 0, 0, 0);
      s_acc[1][j] = __builtin_amdgcn_mfma_f32_16x16x32_bf16(ka1, aqt[1][1], s_acc[1][j], 0, 0, 0);
    }
#pragma unroll
    for (int f = 0; f < 2; f++) {
      const int qa = q0t + wrow + (f << 4) + fr;
      u16* prow = (f == 0) ? p0r : p1r;
      if (dodiag) {
#pragma unroll
        for (int j = 0; j < 4; j++) {
          const int ka = (jt << 6) + (j << 4) + (g << 2);
          float p0 = (ka + 0 > qa) ? 0.f : __builtin_amdgcn_exp2f(s_acc[f][j][0]);
          float p1 = (ka + 1 > qa) ? 0.f : __builtin_amdgcn_exp2f(s_acc[f][j][1]);
          float p2 = (ka + 2 > qa) ? 0.f : __builtin_amdgcn_exp2f(s_acc[f][j][2]);
          float p3 = (ka + 3 > qa) ? 0.f : __builtin_amdgcn_exp2f(s_acc[f][j][3]);
          lr[f] += (p0 + p1) + (p2 + p3);
          union { __hip_bfloat162 h; unsigned u; } ca, cb;
          ca.h = __float22bfloat162_rn(make_float2(p0, p1));
          cb.h = __float22bfloat162_rn(make_float2(p2, p3));
          *(uint2*)(prow + (j << 4) + (g << 2)) = make_uint2(ca.u, cb.u);
        }
      } else {
#pragma unroll
        for (int j = 0; j < 4; j++) {
          float p0 = __builtin_amdgcn_exp2f(s_acc[f][j][0]);
          float p1 = __builtin_amdgcn_exp2f(s_acc[f][j][1]);
          float p2 = __builtin_amdgcn_exp2f(s_acc[f][j][2]);
          float p3 = __builtin_amdgcn_exp2f(s_acc[f][j][3]);
          lr[f] += (p0 + p1) + (p2 + p3);
          union { __hip_bfloat162 h; unsigned u; } ca, cb;
          ca.h = __float22bfloat162_rn(make_float2(p0, p1));
          cb.h = __float22bfloat162_rn(make_float2(p2, p3));
          *(uint2*)(prow + (j << 4) + (g << 2)) = make_uint2(ca.u, cb.u);
        }
      }
    }
  };

  issueK(0, 0);

  for (int jt = 0; jt <= jmax; jt++) {
    const int buf = jt & 1;
    __syncthreads();
    if (jt < jmax) issueK(jt + 1, buf ^ 1);
    issueV(jt, buf);
    if (jt > 0) {
      const u16* vprev = v_s + ((buf ^ 1) << 12);
      if (jt - 1 <= diagB) do_pv(vprev, oB, prowB0, prowB1);
      if (jt - 1 <= diagA) do_pv(vprev, oA, prowA0, prowA1);
    }
    if (jt <= diagB) do_s(k_s + (buf << 12), jt, jt == diagB, q0B, aqB, lB, prowB0, prowB1);
    if (jt <= diagA) do_s(k_s + (buf << 12), jt, jt == diagA, q0A, aqA, lA, prowA0, prowA1);
  }
  __syncthreads();
  if (diagB == jmax) do_pv(v_s + ((jmax & 1) << 12), oB, prowB0, prowB1);

#pragma unroll
  for (int f = 0; f < 2; f++) {
    float la = lA[f];
    la += __shfl_xor(la, 16);
    la += __shfl_xor(la, 32);
    if (g == 0) l_s[wrow + (f << 4) + fr] = la;
    float lb = lB[f];
    lb += __shfl_xor(lb, 16);
    lb += __shfl_xor(lb, 32);
    if (g == 0) l_s[128 + wrow + (f << 4) + fr] = lb;
  }
  const int b = bh >> 4, h = bh & 15;
#pragma unroll
  for (int f = 0; f < 2; f++) {
#pragma unroll
    for (int r = 0; r < 4; r++) {
      const int qloc = wrow + (f << 4) + (g << 2) + r;
      const float invA = 1.f / l_s[qloc];
      const float invB = 1.f / l_s[128 + qloc];
      const int qA_abs = q0A + qloc;
      const int qB_abs = q0B + qloc;
#pragma unroll
      for (int j = 0; j < 4; j++) {
        Ob[((size_t)b * 2048 + qA_abs) * 1024 + (h << 6) + (j << 4) + fr] =
            f2bf(oA[f][j][r] * invA);
        Ob[((size_t)b * 2048 + qB_abs) * 1024 + (h << 6) + (j << 4) + fr] =
            f2bf(oB[f][j][r] * invB);
      }
    }
  }
}

// ---------------- launch ----------------
extern "C" void kernel_launch(void* const* d_in, const int* in_sizes, int n_in,
                              void* d_out, int out_size, void* d_ws, size_t ws_size,
                              hipStream_t stream) {
  const float* x  = (const float*)d_in[0];
  const float* Wq = (const float*)d_in[1];
  const float* bq = (const float*)d_in[2];
  const float* Wk = (const float*)d_in[3];
  const float* bk = (const float*)d_in[4];
  const float* Wv = (const float*)d_in[5];
  const float* bv = (const float*)d_in[6];
  const float* Wo = (const float*)d_in[7];
  const float* bo = (const float*)d_in[8];
  float* out = (float*)d_out;

  char* ws = (char*)d_ws;
  u16* xb    = (u16*)(ws);                 // 16 MB; dead after QKV GEMM
  u16* vT    = (u16*)(ws);                 // aliases xb: V^T [BH][64][S]
  u16* wqkv  = (u16*)(ws + 16777216);      // 6 MB packed q|k|v weights
  u16* wo    = (u16*)(ws + 23068672);      // 2 MB
  u16* qkv   = (u16*)(ws + 25165824);      // 48 MB, [3][BH][S][DH]
  u16* attnb = (u16*)(ws + 75497472);      // 16 MB, [B,S,D]
  // total ws: 92,274,688 B

  cast_bf16_kernel<<<8192, 256, 0, stream>>>(x, xb, 2097152);
  cast4_kernel<<<dim3(1024, 4), 256, 0, stream>>>(
      Wq, Wk, Wv, Wo, wqkv, wqkv + 1048576, wqkv + 2097152, wo, 262144);

  // fused QKV projection: M=8192, N=3072, K=1024 (256^2 8-phase kernel)
  gemm_qkv_256<<<dim3(384), 512, 0, stream>>>(xb, wqkv, bq, bk, bv, qkv);

  // V [BH][S][64] -> V^T [BH][64][S]  (xb dead; vT aliases it)
  transpose_v<<<dim3(32, 64), 256, 0, stream>>>(qkv + 16777216, vT);

  // MFMA flash attention (paired q-tiles, 512 balanced blocks, XCD-grouped)
  attn_fa<<<dim3(512), 256, 0, stream>>>(qkv, qkv + 8388608, vT, attnb);

  // output projection: M=8192, N=1024, K=1024 -> fp32 d_out
  gemm_bt<<<dim3(8, 64), 256, 0, stream>>>(attnb, wo, bo, bo, bo, nullptr, out, 1024, 1);
}

// Round 3
// 256.347 us; speedup vs baseline: 1.2692x; 1.0500x over previous
//
#include <hip/hip_runtime.h>
#include <hip/hip_bf16.h>
#include <cstdint>
#include <cstddef>

// B=4, S=2048, D=1024, H=16, DH=64.  M = B*S = 8192.
// cast->bf16; fused QKV GEMM via 256x192-tile 8-phase pipelined MFMA kernel
// (T2 swizzle + counted-vmcnt + setprio, raw s_barrier; grid 512 = exactly
// 2 clean rounds on 256 CUs, A-panels XCD-grouped; LDS-staged coalesced
// epilogue); V transpose; MFMA flash attention with PAIRED q-tiles (constant
// work/block, 512 blocks, XCD-grouped); output GEMM on the 128^2 kernel.
// Workspace: 92,274,688 B (VT aliases xb's dead region).

typedef unsigned short u16;
typedef __bf16 bf16x8 __attribute__((ext_vector_type(8)));
typedef float  f32x4  __attribute__((ext_vector_type(4)));

__device__ __forceinline__ u16 f2bf(float f) {
  unsigned u = __float_as_uint(f);
  unsigned r = u + 0x7fffu + ((u >> 16) & 1u);   // RNE
  return (u16)(r >> 16);
}

// async global->LDS, 16B per lane (dest = wave-uniform base + lane*16)
__device__ __forceinline__ void llds16(const u16* g, u16* l) {
  __builtin_amdgcn_global_load_lds(
      (const __attribute__((address_space(1))) void*)g,
      (__attribute__((address_space(3))) void*)l, 16, 0, 0);
}

// ---------------- cast fp32 -> bf16 ----------------
__global__ void cast_bf16_kernel(const float* __restrict__ in, u16* __restrict__ out, int n4) {
  int i = blockIdx.x * blockDim.x + threadIdx.x;
  if (i >= n4) return;
  float4 f = ((const float4*)in)[i];
  ushort4 u;
  u.x = f2bf(f.x); u.y = f2bf(f.y); u.z = f2bf(f.z); u.w = f2bf(f.w);
  ((ushort4*)out)[i] = u;
}

// 4 weight matrices in one launch (grid.y selects)
__global__ void cast4_kernel(const float* __restrict__ a, const float* __restrict__ b,
                             const float* __restrict__ c, const float* __restrict__ d,
                             u16* __restrict__ oa, u16* __restrict__ ob,
                             u16* __restrict__ oc, u16* __restrict__ od, int n4) {
  const int w = blockIdx.y;
  const float* src = (w == 0) ? a : (w == 1) ? b : (w == 2) ? c : d;
  u16* dst = (w == 0) ? oa : (w == 1) ? ob : (w == 2) ? oc : od;
  int i = blockIdx.x * blockDim.x + threadIdx.x;
  if (i >= n4) return;
  float4 f = ((const float4*)src)[i];
  ushort4 u;
  u.x = f2bf(f.x); u.y = f2bf(f.y); u.z = f2bf(f.z); u.w = f2bf(f.w);
  ((ushort4*)dst)[i] = u;
}

// ---------------- 256x192 8-phase QKV GEMM: qkv = x * Wqkv^T + bias ----------------
// M=8192, N=3072, K=1024.  512 threads = 8 waves (2M x 4N); per-wave C = 128x48.
// Grid 512 = 32 mt x 16 nt = exactly 2 full rounds (1 block/CU, zero tail).
// LDS 112 KiB: buf{0,1} x [A(256x64) 16384 u16 | B(192x64) 12288 u16],
// 16B chunks XOR-swizzled by row&7.  K-tile kt lives in buf[kt&1].
// Staging units per K-tile (7 llds16/thread): A0(2) A1(2) B0(2) B1(1).
// Iteration t: phases 0-3 compute kt=2t from buf0, stage buf1{A1,B0,B1} (kt=2t+1)
// + buf0.A0 (kt=2t+2), vmcnt(2); phases 4-7 mirror.  Counted vmcnt ledger:
// at p3's vmcnt(2) the 7 oldest of 9 outstanding retire = everything the next
// 4 phases read; only the newest A0 stage (2 loads) stays in flight.
__global__ __launch_bounds__(512) void gemm_qkv_256(
    const u16* __restrict__ A, const u16* __restrict__ Bw,
    const float* __restrict__ b0, const float* __restrict__ b1, const float* __restrict__ b2,
    u16* __restrict__ qkv_out)
{
  __shared__ u16 lds[57344];   // 112 KiB (reused as epilogue staging [256][200])

  const int tid = threadIdx.x;
  const int lane = tid & 63;
  const int wave = tid >> 6;

  // XCD-grouped decode: xcd = bid&7; each XCD owns 4 m-panels x all 16 n-tiles.
  const int bid = (int)blockIdx.x;
  const int xcd = bid & 7;
  const int idx = bid >> 3;                 // 0..63
  const int mt = (xcd << 2) | (idx & 3);    // 0..31
  const int nt = idx >> 2;                  // 0..15
  const int m0 = mt << 8;
  const int n0 = nt * 192;

  const int warp_m = wave >> 2;       // 0..1
  const int warp_n = wave & 3;        // 0..3
  const int wm = warp_m << 7;         // 0,128
  const int wn = warp_n * 48;         // 0,48,96,144
  const int fr = lane & 15;
  const int g  = lane >> 4;           // 0..3

  // staging source (pre-swizzled global addr so linear LDS dest lands swizzled)
  const int srow = tid >> 3;                       // 0..63
  const int schk = ((tid & 7) ^ (srow & 7)) << 3;  // stored chunk -> logical col
  const u16* pA = A  + (size_t)(m0 + srow) * 1024 + schk;
  const u16* pB = Bw + (size_t)(n0 + srow) * 1024 + schk;

  // fragment-read swizzled chunk offsets (chunk = s*4+g, stored = chunk^(row&7))
  const int rsw0 = ((g    ) ^ (fr & 7)) << 3;
  const int rsw1 = ((g ^ 4) ^ (fr & 7)) << 3;

  // read bases (include fr*64 row offset); buf stride 28672 u16
  const u16* Ab0 = lds + (size_t)(wm + fr) * 64;
  const u16* Bb0 = lds + 16384 + (size_t)(wn + fr) * 64;
  const u16* Ab1 = Ab0 + 28672;
  const u16* Bb1 = Bb0 + 28672;

  f32x4 acc[8][3];
  const f32x4 zero = {0.f, 0.f, 0.f, 0.f};
#pragma unroll
  for (int i = 0; i < 8; i++)
#pragma unroll
    for (int j = 0; j < 3; j++) acc[i][j] = zero;

  bf16x8 a_[4][2];
  bf16x8 b_[3][2];

  auto stageA = [&](int kt, int buf, int half) {   // 2 loads (128 rows)
    const u16* src = pA + (size_t)half * 131072 + (kt << 6);
    u16* dst = lds + buf * 28672 + half * 8192 + tid * 8;
    llds16(src, dst);
    llds16(src + 65536, dst + 4096);
  };
  auto stageB0 = [&](int kt, int buf) {            // 2 loads (rows 0-127)
    const u16* src = pB + (kt << 6);
    u16* dst = lds + buf * 28672 + 16384 + tid * 8;
    llds16(src, dst);
    llds16(src + 65536, dst + 4096);
  };
  auto stageB1 = [&](int kt, int buf) {            // 1 load (rows 128-191)
    const u16* src = pB + 131072 + (kt << 6);
    u16* dst = lds + buf * 28672 + 24576 + tid * 8;
    llds16(src, dst);
  };
  auto loadA4 = [&](const u16* Ab, int ib) {
#pragma unroll
    for (int ii = 0; ii < 4; ii++) {
      const u16* r = Ab + (ib + ii) * 1024;
      a_[ii][0] = *(const bf16x8*)(r + rsw0);
      a_[ii][1] = *(const bf16x8*)(r + rsw1);
    }
  };
  auto loadB = [&](const u16* Bb, int j0, int nj) {
#pragma unroll
    for (int jj = 0; jj < 3; jj++) {
      if (jj < nj) {
        const u16* r = Bb + (j0 + jj) * 1024;
        b_[j0 + jj][0] = *(const bf16x8*)(r + rsw0);
        b_[j0 + jj][1] = *(const bf16x8*)(r + rsw1);
      }
    }
  };
  auto mfmaQ = [&](int ib, int j0, int nj) {
    __builtin_amdgcn_s_setprio(1);
#pragma unroll
    for (int jj = 0; jj < 3; jj++) {
      if (jj < nj) {
#pragma unroll
        for (int ii = 0; ii < 4; ii++) {
          acc[ib+ii][j0+jj] = __builtin_amdgcn_mfma_f32_16x16x32_bf16(
              a_[ii][0], b_[j0+jj][0], acc[ib+ii][j0+jj], 0, 0, 0);
          acc[ib+ii][j0+jj] = __builtin_amdgcn_mfma_f32_16x16x32_bf16(
              a_[ii][1], b_[j0+jj][1], acc[ib+ii][j0+jj], 0, 0, 0);
        }
      }
    }
    __builtin_amdgcn_s_setprio(0);
  };

  // prologue: buf0 <- K-tile 0 (A0,A1,B0,B1 = 7 loads), buf1.A0 <- K-tile 1 (2)
  stageA(0, 0, 0);
  stageA(0, 0, 1);
  stageB0(0, 0);
  stageB1(0, 0);
  stageA(1, 1, 0);
  asm volatile("s_waitcnt vmcnt(2)" ::: "memory");  // tile0 landed; tile1.A0 in flight
  __builtin_amdgcn_s_barrier();

  const int NTI = 8;   // K / 128
  for (int t = 0; t < NTI; ++t) {
    const bool st = (t < NTI - 1);
    const int ka = 2 * t + 1;
    const int kb = 2 * t + 2;
    const int kc = 2 * t + 3;

    // ---- K-tile 2t from buf0 ----
    // p0
    loadA4(Ab0, 0); loadB(Bb0, 0, 2);
    stageA(ka, 1, 1);
    __builtin_amdgcn_s_barrier();
    mfmaQ(0, 0, 2);
    __builtin_amdgcn_s_barrier();
    // p1
    loadB(Bb0, 2, 1);
    stageB0(ka, 1);
    __builtin_amdgcn_s_barrier();
    mfmaQ(0, 2, 1);
    __builtin_amdgcn_s_barrier();
    // p2
    loadA4(Ab0, 4);
    stageB1(ka, 1);
    __builtin_amdgcn_s_barrier();
    mfmaQ(4, 2, 1);
    __builtin_amdgcn_s_barrier();
    // p3
    if (st) stageA(kb, 0, 0);
    __builtin_amdgcn_s_barrier();
    mfmaQ(4, 0, 2);
    if (st) { asm volatile("s_waitcnt vmcnt(2)" ::: "memory"); }
    else    { asm volatile("s_waitcnt vmcnt(0)" ::: "memory"); }
    __builtin_amdgcn_s_barrier();

    // ---- K-tile 2t+1 from buf1 ----
    // p4
    loadA4(Ab1, 0); loadB(Bb1, 0, 2);
    if (st) stageA(kb, 0, 1);
    __builtin_amdgcn_s_barrier();
    mfmaQ(0, 0, 2);
    __builtin_amdgcn_s_barrier();
    // p5
    loadB(Bb1, 2, 1);
    if (st) stageB0(kb, 0);
    __builtin_amdgcn_s_barrier();
    mfmaQ(0, 2, 1);
    __builtin_amdgcn_s_barrier();
    // p6
    loadA4(Ab1, 4);
    if (st) stageB1(kb, 0);
    __builtin_amdgcn_s_barrier();
    mfmaQ(4, 2, 1);
    __builtin_amdgcn_s_barrier();
    // p7
    if (st) stageA(kc, 1, 0);
    __builtin_amdgcn_s_barrier();
    mfmaQ(4, 0, 2);
    if (st) { asm volatile("s_waitcnt vmcnt(2)" ::: "memory"); }
    __builtin_amdgcn_s_barrier();
  }

  // ---- epilogue: bias+post -> LDS [256][200] -> coalesced 16B stores ----
  __syncthreads();
  const int bI  = m0 >> 11;
  const int s0m = m0 & 2047;
#pragma unroll
  for (int j = 0; j < 3; j++) {
    const int ncol = n0 + wn + j * 16 + fr;
    const int which = ncol >> 10;
    const float bb = ((which == 0) ? b0 : (which == 1) ? b1 : b2)[ncol & 1023];
    const float post = (which == 0) ? 0.18033688011f : 1.0f;  // 0.125*log2(e)
    const int cl = wn + j * 16 + fr;
#pragma unroll
    for (int i = 0; i < 8; i++) {
#pragma unroll
      for (int r = 0; r < 4; r++) {
        const int row = wm + i * 16 + g * 4 + r;
        lds[row * 200 + cl] = f2bf((acc[i][j][r] + bb) * post);
      }
    }
  }
  __syncthreads();
  const int part = tid & 7;
#pragma unroll
  for (int p = 0; p < 12; p++) {
    const int hc = p >> 2;
    const int ml = ((p & 3) << 6) + (tid >> 3);
    const int ncol0 = n0 + hc * 64;
    const int which = ncol0 >> 10;
    const int h = (ncol0 >> 6) & 15;
    const bf16x8 v = *(const bf16x8*)(lds + ml * 200 + hc * 64 + part * 8);
    *(bf16x8*)(qkv_out + (size_t)which * 8388608 +
               ((size_t)(bI * 16 + h) * 2048 + s0m + ml) * 64 + part * 8) = v;
  }
}

// ---------------- bf16 MFMA GEMM (m97-style), C = A*Bw^T + bias ----------------
__global__ __launch_bounds__(256) void gemm_bt(
    const u16* __restrict__ A, const u16* __restrict__ Bw,
    const float* __restrict__ b0, const float* __restrict__ b1, const float* __restrict__ b2,
    u16* __restrict__ qkv_out, float* __restrict__ flat_out,
    int K, int mode)
{
  __shared__ u16 As[128 * 32];
  __shared__ u16 Bs[128 * 32];

  const int tid = threadIdx.x;
  const int n0 = blockIdx.x * 128;
  const int m0 = blockIdx.y * 128;

  const int srow = tid >> 2;
  const int soff = (tid & 3) * 8;
  const u16* gA0 = A  + (size_t)(m0 + srow) * K + soff;
  const u16* gA1 = gA0 + (size_t)64 * K;
  const u16* gB0 = Bw + (size_t)(n0 + srow) * K + soff;
  const u16* gB1 = gB0 + (size_t)64 * K;
  u16* lA0 = As + tid * 8;
  u16* lA1 = As + 2048 + tid * 8;
  u16* lB0 = Bs + tid * 8;
  u16* lB1 = Bs + 2048 + tid * 8;

  const int lane = tid & 63;
  const int wave = tid >> 6;
  const int wm = (wave >> 1) * 64;
  const int wn = (wave & 1) * 64;
  const int fr = lane & 15;
  const int k8 = (lane >> 4) * 8;

  f32x4 zero = {0.f, 0.f, 0.f, 0.f};
  f32x4 acc[4][4];
#pragma unroll
  for (int i = 0; i < 4; i++)
#pragma unroll
    for (int j = 0; j < 4; j++) acc[i][j] = zero;

  for (int k0 = 0; k0 < K; k0 += 32) {
    llds16(gA0 + k0, lA0);
    llds16(gA1 + k0, lA1);
    llds16(gB0 + k0, lB0);
    llds16(gB1 + k0, lB1);
    __syncthreads();
    bf16x8 af[4], bfr[4];
#pragma unroll
    for (int i = 0; i < 4; i++)
      af[i] = *(const bf16x8*)(As + (wm + i * 16 + fr) * 32 + k8);
#pragma unroll
    for (int j = 0; j < 4; j++)
      bfr[j] = *(const bf16x8*)(Bs + (wn + j * 16 + fr) * 32 + k8);
#pragma unroll
    for (int i = 0; i < 4; i++)
#pragma unroll
      for (int j = 0; j < 4; j++)
        acc[i][j] = __builtin_amdgcn_mfma_f32_16x16x32_bf16(af[i], bfr[j], acc[i][j], 0, 0, 0);
    __syncthreads();
  }

  const int rbase = (lane >> 4) * 4;
  if (mode == 0) {
    const int which = n0 >> 10;
    const float* bias = (which == 0) ? b0 : ((which == 1) ? b1 : b2);
    const float post = (which == 0) ? 0.18033688011f : 1.0f;  // 0.125*log2(e)
    u16* outb = qkv_out + (size_t)which * 8388608;
#pragma unroll
    for (int j = 0; j < 4; j++) {
      const int nn = (n0 + wn + j * 16 + fr) & 1023;
      const float bb = bias[nn];
      const int h = nn >> 6, dh = nn & 63;
#pragma unroll
      for (int i = 0; i < 4; i++) {
#pragma unroll
        for (int r = 0; r < 4; r++) {
          const int m = m0 + wm + i * 16 + rbase + r;
          const int bI = m >> 11, s = m & 2047;
          outb[(((size_t)bI * 16 + h) * 2048 + s) * 64 + dh] = f2bf((acc[i][j][r] + bb) * post);
        }
      }
    }
  } else {
#pragma unroll
    for (int j = 0; j < 4; j++) {
      const int n = n0 + wn + j * 16 + fr;
      const float bb = b0[n];
#pragma unroll
      for (int i = 0; i < 4; i++) {
#pragma unroll
        for (int r = 0; r < 4; r++) {
          const int m = m0 + wm + i * 16 + rbase + r;
          flat_out[(size_t)m * 1024 + n] = acc[i][j][r] + bb;
        }
      }
    }
  }
}

// ---------------- V transpose: [BH][S][64] -> [BH][64][S] ----------------
__global__ __launch_bounds__(256) void transpose_v(const u16* __restrict__ V, u16* __restrict__ VT) {
  __shared__ u16 t_s[64 * 72];
  const int tid = threadIdx.x;
  const int st = blockIdx.x << 6;
  const int bh = blockIdx.y;
  const u16* src = V + ((size_t)bh * 2048 + st) * 64;
#pragma unroll
  for (int p = 0; p < 2; p++) {
    int i = p * 256 + tid;
    int row = i >> 3, ch = i & 7;
    bf16x8 v = *(const bf16x8*)(src + row * 64 + ch * 8);
    *(bf16x8*)(t_s + row * 72 + ch * 8) = v;
  }
  __syncthreads();
  u16* dst = VT + (size_t)bh * 131072 + st;
#pragma unroll
  for (int p = 0; p < 2; p++) {
    int i = p * 256 + tid;
    int dh = i >> 3, ch = i & 7;
    union { u16 s[8]; bf16x8 v; } u;
#pragma unroll
    for (int e = 0; e < 8; e++) u.s[e] = t_s[(ch * 8 + e) * 72 + dh];
    *(bf16x8*)(dst + (size_t)dh * 2048 + ch * 8) = u.v;
  }
}

// ---------------- MFMA flash attention: paired q-tiles, PV deferred ----------------
__global__ __launch_bounds__(256, 2) void attn_fa(
    const u16* __restrict__ Qb, const u16* __restrict__ Kb,
    const u16* __restrict__ VT, u16* __restrict__ Ob)
{
  __shared__ u16 k_s[2 * 4096];      // dbuf [kn][d], 16B-chunks XOR'd by row
  __shared__ u16 v_s[2 * 4096];      // dbuf [dn][k], same swizzle (lags K by 1 tile)
  __shared__ u16 p_s[2 * 9216];      // [tile][q(128)][key(72)] bf16 (wave-private rows)
  __shared__ float l_s[256];

  const int tid = threadIdx.x;
  const int lane = tid & 63;
  const int wave = tid >> 6;

  // decode: c = xcd + 8*(pair + 8*bh_hi); all 16 blocks of head bh share XCD bh%8
  const int c = (int)blockIdx.x;
  const int xcd = c & 7;
  const int rr_ = c >> 3;
  const int bh = xcd + ((rr_ >> 3) << 3);
  const int pr = rr_ & 7;
  const int qtA = pr;            // small tile (finishes early)
  const int qtB = 15 - pr;       // big tile (drives the K/V stream)

  const size_t head = (size_t)bh << 17;
  const int fr = lane & 15;
  const int g = lane >> 4;
  const int k8 = g << 3;
  const int q0A = qtA << 7;
  const int q0B = qtB << 7;
  const int wrow = wave << 5;

  bf16x8 aqA[2][2], aqB[2][2];
#pragma unroll
  for (int f = 0; f < 2; f++) {
    const u16* qpA = Qb + head + (size_t)(q0A + wrow + (f << 4) + fr) * 64;
    aqA[f][0] = *(const bf16x8*)(qpA + k8);
    aqA[f][1] = *(const bf16x8*)(qpA + 32 + k8);
    const u16* qpB = Qb + head + (size_t)(q0B + wrow + (f << 4) + fr) * 64;
    aqB[f][0] = *(const bf16x8*)(qpB + k8);
    aqB[f][1] = *(const bf16x8*)(qpB + 32 + k8);
  }

  const int r0 = tid >> 3, c0 = tid & 7;
  const int r1 = 32 + r0;
  const int koff0 = r0 * 64 + (((c0 ^ r0) & 7) << 3);
  const int koff1 = r1 * 64 + (((c0 ^ r1) & 7) << 3);
  const int voff0 = r0 * 2048 + (((c0 ^ r0) & 7) << 3);
  const int voff1 = r1 * 2048 + (((c0 ^ r1) & 7) << 3);
  int kaddr[4][2], vaddr[2][4];
#pragma unroll
  for (int j = 0; j < 4; j++) {
    const int kn = (j << 4) + fr;
    kaddr[j][0] = kn * 64 + (((g ^ kn) & 7) << 3);
    kaddr[j][1] = kn * 64 + ((((g + 4) ^ kn) & 7) << 3);
#pragma unroll
    for (int s2 = 0; s2 < 2; s2++)
      vaddr[s2][j] = kn * 64 + ((((s2 << 2) + g) ^ (kn & 7)) << 3);
  }
  u16* const prowA0 = p_s + (wrow + fr) * 72;
  u16* const prowA1 = p_s + (wrow + 16 + fr) * 72;
  u16* const prowB0 = p_s + 9216 + (wrow + fr) * 72;
  u16* const prowB1 = p_s + 9216 + (wrow + 16 + fr) * 72;
  const u16* Kbase = Kb + head;
  const u16* Vbase = VT + head;

  auto issueK = [&](int jt2, int buf) {
    const u16* Kt = Kbase + ((size_t)jt2 << 12);
    llds16(Kt + koff0, k_s + (buf << 12) + tid * 8);
    llds16(Kt + koff1, k_s + (buf << 12) + 2048 + tid * 8);
  };
  auto issueV = [&](int jt2, int buf) {
    const u16* Vt = Vbase + (jt2 << 6);
    llds16(Vt + voff0, v_s + (buf << 12) + tid * 8);
    llds16(Vt + voff1, v_s + (buf << 12) + 2048 + tid * 8);
  };

  f32x4 oA[2][4], oB[2][4];
  const f32x4 zero = {0.f, 0.f, 0.f, 0.f};
#pragma unroll
  for (int f = 0; f < 2; f++)
#pragma unroll
    for (int j = 0; j < 4; j++) { oA[f][j] = zero; oB[f][j] = zero; }
  float lA[2] = {0.f, 0.f}, lB[2] = {0.f, 0.f};

  const int jmax = 2 * qtB + 1;
  const int diagA = 2 * qtA + (wave >> 1);
  const int diagB = 2 * qtB + (wave >> 1);

  auto do_pv = [&](const u16* vs, f32x4 (&oacc)[2][4], const u16* p0r, const u16* p1r) {
#pragma unroll
    for (int s2 = 0; s2 < 2; s2++) {
      const bf16x8 ap0 = *(const bf16x8*)(p0r + (s2 << 5) + k8);
      const bf16x8 ap1 = *(const bf16x8*)(p1r + (s2 << 5) + k8);
#pragma unroll
      for (int j = 0; j < 4; j++) {
        const bf16x8 bv = *(const bf16x8*)(vs + vaddr[s2][j]);
        oacc[0][j] = __builtin_amdgcn_mfma_f32_16x16x32_bf16(ap0, bv, oacc[0][j], 0, 0, 0);
        oacc[1][j] = __builtin_amdgcn_mfma_f32_16x16x32_bf16(ap1, bv, oacc[1][j], 0, 0, 0);
      }
    }
  };

  auto do_s = [&](const u16* ks, int jt, bool dodiag, int q0t,
                  const bf16x8 (&aqt)[2][2], float (&lr)[2], u16* p0r, u16* p1r) {
    f32x4 s_acc[2][4];
#pragma unroll
    for (int f = 0; f < 2; f++)
#pragma unroll
      for (int j = 0; j < 4; j++) s_acc[f][j] = zero;
#pragma unroll
    for (int j = 0; j < 4; j++) {
      const bf16x8 ka0 = *(const bf16x8*)(ks + kaddr[j][0]);
      const bf16x8 ka1 = *(const bf16x8*)(ks + kaddr[j][1]);
      s_acc[0][j] = __builtin_amdgcn_mfma_f32_16x16x32_bf16(ka0, aqt[0][0], s_acc[0][j], 0, 0, 0);
      s_acc[0][j] = __builtin_amdgcn_mfma_f32_16x16x32_bf16(ka1, aqt[0][1], s_acc[0][j], 0, 0, 0);
      s_acc[1][j] = __builtin_amdgcn_mfma_f32_16x16x32_bf16(ka0, aqt[1][0], s_acc[1][j], 0, 0, 0);
      s_acc[1][j] = __builtin_amdgcn_mfma_f32_16x16x32_bf16(ka1, aqt[1][1], s_acc[1][j], 0, 0, 0);
    }
#pragma unroll
    for (int f = 0; f < 2; f++) {
      const int qa = q0t + wrow + (f << 4) + fr;
      u16* prow = (f == 0) ? p0r : p1r;
      if (dodiag) {
#pragma unroll
        for (int j = 0; j < 4; j++) {
          const int ka = (jt << 6) + (j << 4) + (g << 2);
          float p0 = (ka + 0 > qa) ? 0.f : __builtin_amdgcn_exp2f(s_acc[f][j][0]);
          float p1 = (ka + 1 > qa) ? 0.f : __builtin_amdgcn_exp2f(s_acc[f][j][1]);
          float p2 = (ka + 2 > qa) ? 0.f : __builtin_amdgcn_exp2f(s_acc[f][j][2]);
          float p3 = (ka + 3 > qa) ? 0.f : __builtin_amdgcn_exp2f(s_acc[f][j][3]);
          lr[f] += (p0 + p1) + (p2 + p3);
          union { __hip_bfloat162 h; unsigned u; } ca, cb;
          ca.h = __float22bfloat162_rn(make_float2(p0, p1));
          cb.h = __float22bfloat162_rn(make_float2(p2, p3));
          *(uint2*)(prow + (j << 4) + (g << 2)) = make_uint2(ca.u, cb.u);
        }
      } else {
#pragma unroll
        for (int j = 0; j < 4; j++) {
          float p0 = __builtin_amdgcn_exp2f(s_acc[f][j][0]);
          float p1 = __builtin_amdgcn_exp2f(s_acc[f][j][1]);
          float p2 = __builtin_amdgcn_exp2f(s_acc[f][j][2]);
          float p3 = __builtin_amdgcn_exp2f(s_acc[f][j][3]);
          lr[f] += (p0 + p1) + (p2 + p3);
          union { __hip_bfloat162 h; unsigned u; } ca, cb;
          ca.h = __float22bfloat162_rn(make_float2(p0, p1));
          cb.h = __float22bfloat162_rn(make_float2(p2, p3));
          *(uint2*)(prow + (j << 4) + (g << 2)) = make_uint2(ca.u, cb.u);
        }
      }
    }
  };

  issueK(0, 0);

  for (int jt = 0; jt <= jmax; jt++) {
    const int buf = jt & 1;
    __syncthreads();
    if (jt < jmax) issueK(jt + 1, buf ^ 1);
    issueV(jt, buf);
    if (jt > 0) {
      const u16* vprev = v_s + ((buf ^ 1) << 12);
      if (jt - 1 <= diagB) do_pv(vprev, oB, prowB0, prowB1);
      if (jt - 1 <= diagA) do_pv(vprev, oA, prowA0, prowA1);
    }
    if (jt <= diagB) do_s(k_s + (buf << 12), jt, jt == diagB, q0B, aqB, lB, prowB0, prowB1);
    if (jt <= diagA) do_s(k_s + (buf << 12), jt, jt == diagA, q0A, aqA, lA, prowA0, prowA1);
  }
  __syncthreads();
  if (diagB == jmax) do_pv(v_s + ((jmax & 1) << 12), oB, prowB0, prowB1);

#pragma unroll
  for (int f = 0; f < 2; f++) {
    float la = lA[f];
    la += __shfl_xor(la, 16);
    la += __shfl_xor(la, 32);
    if (g == 0) l_s[wrow + (f << 4) + fr] = la;
    float lb = lB[f];
    lb += __shfl_xor(lb, 16);
    lb += __shfl_xor(lb, 32);
    if (g == 0) l_s[128 + wrow + (f << 4) + fr] = lb;
  }
  const int b = bh >> 4, h = bh & 15;
#pragma unroll
  for (int f = 0; f < 2; f++) {
#pragma unroll
    for (int r = 0; r < 4; r++) {
      const int qloc = wrow + (f << 4) + (g << 2) + r;
      const float invA = 1.f / l_s[qloc];
      const float invB = 1.f / l_s[128 + qloc];
      const int qA_abs = q0A + qloc;
      const int qB_abs = q0B + qloc;
#pragma unroll
      for (int j = 0; j < 4; j++) {
        Ob[((size_t)b * 2048 + qA_abs) * 1024 + (h << 6) + (j << 4) + fr] =
            f2bf(oA[f][j][r] * invA);
        Ob[((size_t)b * 2048 + qB_abs) * 1024 + (h << 6) + (j << 4) + fr] =
            f2bf(oB[f][j][r] * invB);
      }
    }
  }
}

// ---------------- launch ----------------
extern "C" void kernel_launch(void* const* d_in, const int* in_sizes, int n_in,
                              void* d_out, int out_size, void* d_ws, size_t ws_size,
                              hipStream_t stream) {
  const float* x  = (const float*)d_in[0];
  const float* Wq = (const float*)d_in[1];
  const float* bq = (const float*)d_in[2];
  const float* Wk = (const float*)d_in[3];
  const float* bk = (const float*)d_in[4];
  const float* Wv = (const float*)d_in[5];
  const float* bv = (const float*)d_in[6];
  const float* Wo = (const float*)d_in[7];
  const float* bo = (const float*)d_in[8];
  float* out = (float*)d_out;

  char* ws = (char*)d_ws;
  u16* xb    = (u16*)(ws);                 // 16 MB; dead after QKV GEMM
  u16* vT    = (u16*)(ws);                 // aliases xb: V^T [BH][64][S]
  u16* wqkv  = (u16*)(ws + 16777216);      // 6 MB packed q|k|v weights
  u16* wo    = (u16*)(ws + 23068672);      // 2 MB
  u16* qkv   = (u16*)(ws + 25165824);      // 48 MB, [3][BH][S][DH]
  u16* attnb = (u16*)(ws + 75497472);      // 16 MB, [B,S,D]
  // total ws: 92,274,688 B

  cast_bf16_kernel<<<8192, 256, 0, stream>>>(x, xb, 2097152);
  cast4_kernel<<<dim3(1024, 4), 256, 0, stream>>>(
      Wq, Wk, Wv, Wo, wqkv, wqkv + 1048576, wqkv + 2097152, wo, 262144);

  // fused QKV projection: M=8192, N=3072, K=1024 (256x192 8-phase, 2 clean rounds)
  gemm_qkv_256<<<dim3(512), 512, 0, stream>>>(xb, wqkv, bq, bk, bv, qkv);

  // V [BH][S][64] -> V^T [BH][64][S]  (xb dead; vT aliases it)
  transpose_v<<<dim3(32, 64), 256, 0, stream>>>(qkv + 16777216, vT);

  // MFMA flash attention (paired q-tiles, 512 balanced blocks, XCD-grouped)
  attn_fa<<<dim3(512), 256, 0, stream>>>(qkv, qkv + 8388608, vT, attnb);

  // output projection: M=8192, N=1024, K=1024 -> fp32 d_out
  gemm_bt<<<dim3(8, 64), 256, 0, stream>>>(attnb, wo, bo, bo, bo, nullptr, out, 1024, 1);
}

// Round 4
// 247.708 us; speedup vs baseline: 1.3135x; 1.0349x over previous
//
#include <hip/hip_runtime.h>
#include <hip/hip_bf16.h>
#include <cstdint>
#include <cstddef>

// B=4, S=2048, D=1024, H=16, DH=64.  M = B*S = 8192.
// cast->bf16; fused QKV GEMM via 256x192-tile 8-phase pipelined MFMA kernel
// (T2 swizzle + counted-vmcnt + setprio, raw s_barrier; grid 512 = exactly
// 2 clean rounds on 256 CUs, A-panels XCD-grouped; LDS-staged coalesced
// epilogue); V transpose; MFMA flash attention: SINGLE q-tile per block,
// 51.7 KB LDS -> 3 blocks/CU, flat 1024-block grid with big-tiles-first
// dispatch (qt = 15 - bid>>6) and XCD-grouped bh (bh%8 == bid%8) so long
// blocks start at t=0 and short ones backfill; output GEMM on 128^2 kernel.
// Workspace: 92,274,688 B (VT aliases xb's dead region).

typedef unsigned short u16;
typedef __bf16 bf16x8 __attribute__((ext_vector_type(8)));
typedef float  f32x4  __attribute__((ext_vector_type(4)));

__device__ __forceinline__ u16 f2bf(float f) {
  unsigned u = __float_as_uint(f);
  unsigned r = u + 0x7fffu + ((u >> 16) & 1u);   // RNE
  return (u16)(r >> 16);
}

// async global->LDS, 16B per lane (dest = wave-uniform base + lane*16)
__device__ __forceinline__ void llds16(const u16* g, u16* l) {
  __builtin_amdgcn_global_load_lds(
      (const __attribute__((address_space(1))) void*)g,
      (__attribute__((address_space(3))) void*)l, 16, 0, 0);
}

// ---------------- cast fp32 -> bf16 ----------------
__global__ void cast_bf16_kernel(const float* __restrict__ in, u16* __restrict__ out, int n4) {
  int i = blockIdx.x * blockDim.x + threadIdx.x;
  if (i >= n4) return;
  float4 f = ((const float4*)in)[i];
  ushort4 u;
  u.x = f2bf(f.x); u.y = f2bf(f.y); u.z = f2bf(f.z); u.w = f2bf(f.w);
  ((ushort4*)out)[i] = u;
}

// 4 weight matrices in one launch (grid.y selects)
__global__ void cast4_kernel(const float* __restrict__ a, const float* __restrict__ b,
                             const float* __restrict__ c, const float* __restrict__ d,
                             u16* __restrict__ oa, u16* __restrict__ ob,
                             u16* __restrict__ oc, u16* __restrict__ od, int n4) {
  const int w = blockIdx.y;
  const float* src = (w == 0) ? a : (w == 1) ? b : (w == 2) ? c : d;
  u16* dst = (w == 0) ? oa : (w == 1) ? ob : (w == 2) ? oc : od;
  int i = blockIdx.x * blockDim.x + threadIdx.x;
  if (i >= n4) return;
  float4 f = ((const float4*)src)[i];
  ushort4 u;
  u.x = f2bf(f.x); u.y = f2bf(f.y); u.z = f2bf(f.z); u.w = f2bf(f.w);
  ((ushort4*)dst)[i] = u;
}

// ---------------- 256x192 8-phase QKV GEMM: qkv = x * Wqkv^T + bias ----------------
// M=8192, N=3072, K=1024.  512 threads = 8 waves (2M x 4N); per-wave C = 128x48.
// Grid 512 = 32 mt x 16 nt = exactly 2 full rounds (1 block/CU, zero tail).
// LDS 112 KiB: buf{0,1} x [A(256x64) 16384 u16 | B(192x64) 12288 u16],
// 16B chunks XOR-swizzled by row&7.  K-tile kt lives in buf[kt&1].
// Staging units per K-tile (7 llds16/thread): A0(2) A1(2) B0(2) B1(1).
// Counted vmcnt ledger: at p3/p7's vmcnt(2) the older 7 of 9 outstanding
// retire = everything the next 4 phases read.
__global__ __launch_bounds__(512) void gemm_qkv_256(
    const u16* __restrict__ A, const u16* __restrict__ Bw,
    const float* __restrict__ b0, const float* __restrict__ b1, const float* __restrict__ b2,
    u16* __restrict__ qkv_out)
{
  __shared__ u16 lds[57344];   // 112 KiB (reused as epilogue staging [256][200])

  const int tid = threadIdx.x;
  const int lane = tid & 63;
  const int wave = tid >> 6;

  // XCD-grouped decode: xcd = bid&7; each XCD owns 4 m-panels x all 16 n-tiles.
  const int bid = (int)blockIdx.x;
  const int xcd = bid & 7;
  const int idx = bid >> 3;                 // 0..63
  const int mt = (xcd << 2) | (idx & 3);    // 0..31
  const int nt = idx >> 2;                  // 0..15
  const int m0 = mt << 8;
  const int n0 = nt * 192;

  const int warp_m = wave >> 2;       // 0..1
  const int warp_n = wave & 3;        // 0..3
  const int wm = warp_m << 7;         // 0,128
  const int wn = warp_n * 48;         // 0,48,96,144
  const int fr = lane & 15;
  const int g  = lane >> 4;           // 0..3

  // staging source (pre-swizzled global addr so linear LDS dest lands swizzled)
  const int srow = tid >> 3;                       // 0..63
  const int schk = ((tid & 7) ^ (srow & 7)) << 3;  // stored chunk -> logical col
  const u16* pA = A  + (size_t)(m0 + srow) * 1024 + schk;
  const u16* pB = Bw + (size_t)(n0 + srow) * 1024 + schk;

  // fragment-read swizzled chunk offsets (chunk = s*4+g, stored = chunk^(row&7))
  const int rsw0 = ((g    ) ^ (fr & 7)) << 3;
  const int rsw1 = ((g ^ 4) ^ (fr & 7)) << 3;

  // read bases (include fr*64 row offset); buf stride 28672 u16
  const u16* Ab0 = lds + (size_t)(wm + fr) * 64;
  const u16* Bb0 = lds + 16384 + (size_t)(wn + fr) * 64;
  const u16* Ab1 = Ab0 + 28672;
  const u16* Bb1 = Bb0 + 28672;

  f32x4 acc[8][3];
  const f32x4 zero = {0.f, 0.f, 0.f, 0.f};
#pragma unroll
  for (int i = 0; i < 8; i++)
#pragma unroll
    for (int j = 0; j < 3; j++) acc[i][j] = zero;

  bf16x8 a_[4][2];
  bf16x8 b_[3][2];

  auto stageA = [&](int kt, int buf, int half) {   // 2 loads (128 rows)
    const u16* src = pA + (size_t)half * 131072 + (kt << 6);
    u16* dst = lds + buf * 28672 + half * 8192 + tid * 8;
    llds16(src, dst);
    llds16(src + 65536, dst + 4096);
  };
  auto stageB0 = [&](int kt, int buf) {            // 2 loads (rows 0-127)
    const u16* src = pB + (kt << 6);
    u16* dst = lds + buf * 28672 + 16384 + tid * 8;
    llds16(src, dst);
    llds16(src + 65536, dst + 4096);
  };
  auto stageB1 = [&](int kt, int buf) {            // 1 load (rows 128-191)
    const u16* src = pB + 131072 + (kt << 6);
    u16* dst = lds + buf * 28672 + 24576 + tid * 8;
    llds16(src, dst);
  };
  auto loadA4 = [&](const u16* Ab, int ib) {
#pragma unroll
    for (int ii = 0; ii < 4; ii++) {
      const u16* r = Ab + (ib + ii) * 1024;
      a_[ii][0] = *(const bf16x8*)(r + rsw0);
      a_[ii][1] = *(const bf16x8*)(r + rsw1);
    }
  };
  auto loadB = [&](const u16* Bb, int j0, int nj) {
#pragma unroll
    for (int jj = 0; jj < 3; jj++) {
      if (jj < nj) {
        const u16* r = Bb + (j0 + jj) * 1024;
        b_[j0 + jj][0] = *(const bf16x8*)(r + rsw0);
        b_[j0 + jj][1] = *(const bf16x8*)(r + rsw1);
      }
    }
  };
  auto mfmaQ = [&](int ib, int j0, int nj) {
    __builtin_amdgcn_s_setprio(1);
#pragma unroll
    for (int jj = 0; jj < 3; jj++) {
      if (jj < nj) {
#pragma unroll
        for (int ii = 0; ii < 4; ii++) {
          acc[ib+ii][j0+jj] = __builtin_amdgcn_mfma_f32_16x16x32_bf16(
              a_[ii][0], b_[j0+jj][0], acc[ib+ii][j0+jj], 0, 0, 0);
          acc[ib+ii][j0+jj] = __builtin_amdgcn_mfma_f32_16x16x32_bf16(
              a_[ii][1], b_[j0+jj][1], acc[ib+ii][j0+jj], 0, 0, 0);
        }
      }
    }
    __builtin_amdgcn_s_setprio(0);
  };

  // prologue: buf0 <- K-tile 0 (A0,A1,B0,B1 = 7 loads), buf1.A0 <- K-tile 1 (2)
  stageA(0, 0, 0);
  stageA(0, 0, 1);
  stageB0(0, 0);
  stageB1(0, 0);
  stageA(1, 1, 0);
  asm volatile("s_waitcnt vmcnt(2)" ::: "memory");  // tile0 landed; tile1.A0 in flight
  __builtin_amdgcn_s_barrier();

  const int NTI = 8;   // K / 128
  for (int t = 0; t < NTI; ++t) {
    const bool st = (t < NTI - 1);
    const int ka = 2 * t + 1;
    const int kb = 2 * t + 2;
    const int kc = 2 * t + 3;

    // ---- K-tile 2t from buf0 ----
    // p0
    loadA4(Ab0, 0); loadB(Bb0, 0, 2);
    stageA(ka, 1, 1);
    __builtin_amdgcn_s_barrier();
    mfmaQ(0, 0, 2);
    __builtin_amdgcn_s_barrier();
    // p1
    loadB(Bb0, 2, 1);
    stageB0(ka, 1);
    __builtin_amdgcn_s_barrier();
    mfmaQ(0, 2, 1);
    __builtin_amdgcn_s_barrier();
    // p2
    loadA4(Ab0, 4);
    stageB1(ka, 1);
    __builtin_amdgcn_s_barrier();
    mfmaQ(4, 2, 1);
    __builtin_amdgcn_s_barrier();
    // p3
    if (st) stageA(kb, 0, 0);
    __builtin_amdgcn_s_barrier();
    mfmaQ(4, 0, 2);
    if (st) { asm volatile("s_waitcnt vmcnt(2)" ::: "memory"); }
    else    { asm volatile("s_waitcnt vmcnt(0)" ::: "memory"); }
    __builtin_amdgcn_s_barrier();

    // ---- K-tile 2t+1 from buf1 ----
    // p4
    loadA4(Ab1, 0); loadB(Bb1, 0, 2);
    if (st) stageA(kb, 0, 1);
    __builtin_amdgcn_s_barrier();
    mfmaQ(0, 0, 2);
    __builtin_amdgcn_s_barrier();
    // p5
    loadB(Bb1, 2, 1);
    if (st) stageB0(kb, 0);
    __builtin_amdgcn_s_barrier();
    mfmaQ(0, 2, 1);
    __builtin_amdgcn_s_barrier();
    // p6
    loadA4(Ab1, 4);
    if (st) stageB1(kb, 0);
    __builtin_amdgcn_s_barrier();
    mfmaQ(4, 2, 1);
    __builtin_amdgcn_s_barrier();
    // p7
    if (st) stageA(kc, 1, 0);
    __builtin_amdgcn_s_barrier();
    mfmaQ(4, 0, 2);
    if (st) { asm volatile("s_waitcnt vmcnt(2)" ::: "memory"); }
    __builtin_amdgcn_s_barrier();
  }

  // ---- epilogue: bias+post -> LDS [256][200] -> coalesced 16B stores ----
  __syncthreads();
  const int bI  = m0 >> 11;
  const int s0m = m0 & 2047;
#pragma unroll
  for (int j = 0; j < 3; j++) {
    const int ncol = n0 + wn + j * 16 + fr;
    const int which = ncol >> 10;
    const float bb = ((which == 0) ? b0 : (which == 1) ? b1 : b2)[ncol & 1023];
    const float post = (which == 0) ? 0.18033688011f : 1.0f;  // 0.125*log2(e)
    const int cl = wn + j * 16 + fr;
#pragma unroll
    for (int i = 0; i < 8; i++) {
#pragma unroll
      for (int r = 0; r < 4; r++) {
        const int row = wm + i * 16 + g * 4 + r;
        lds[row * 200 + cl] = f2bf((acc[i][j][r] + bb) * post);
      }
    }
  }
  __syncthreads();
  const int part = tid & 7;
#pragma unroll
  for (int p = 0; p < 12; p++) {
    const int hc = p >> 2;
    const int ml = ((p & 3) << 6) + (tid >> 3);
    const int ncol0 = n0 + hc * 64;
    const int which = ncol0 >> 10;
    const int h = (ncol0 >> 6) & 15;
    const bf16x8 v = *(const bf16x8*)(lds + ml * 200 + hc * 64 + part * 8);
    *(bf16x8*)(qkv_out + (size_t)which * 8388608 +
               ((size_t)(bI * 16 + h) * 2048 + s0m + ml) * 64 + part * 8) = v;
  }
}

// ---------------- bf16 MFMA GEMM (m97-style), C = A*Bw^T + bias ----------------
__global__ __launch_bounds__(256) void gemm_bt(
    const u16* __restrict__ A, const u16* __restrict__ Bw,
    const float* __restrict__ b0, const float* __restrict__ b1, const float* __restrict__ b2,
    u16* __restrict__ qkv_out, float* __restrict__ flat_out,
    int K, int mode)
{
  __shared__ u16 As[128 * 32];
  __shared__ u16 Bs[128 * 32];

  const int tid = threadIdx.x;
  const int n0 = blockIdx.x * 128;
  const int m0 = blockIdx.y * 128;

  const int srow = tid >> 2;
  const int soff = (tid & 3) * 8;
  const u16* gA0 = A  + (size_t)(m0 + srow) * K + soff;
  const u16* gA1 = gA0 + (size_t)64 * K;
  const u16* gB0 = Bw + (size_t)(n0 + srow) * K + soff;
  const u16* gB1 = gB0 + (size_t)64 * K;
  u16* lA0 = As + tid * 8;
  u16* lA1 = As + 2048 + tid * 8;
  u16* lB0 = Bs + tid * 8;
  u16* lB1 = Bs + 2048 + tid * 8;

  const int lane = tid & 63;
  const int wave = tid >> 6;
  const int wm = (wave >> 1) * 64;
  const int wn = (wave & 1) * 64;
  const int fr = lane & 15;
  const int k8 = (lane >> 4) * 8;

  f32x4 zero = {0.f, 0.f, 0.f, 0.f};
  f32x4 acc[4][4];
#pragma unroll
  for (int i = 0; i < 4; i++)
#pragma unroll
    for (int j = 0; j < 4; j++) acc[i][j] = zero;

  for (int k0 = 0; k0 < K; k0 += 32) {
    llds16(gA0 + k0, lA0);
    llds16(gA1 + k0, lA1);
    llds16(gB0 + k0, lB0);
    llds16(gB1 + k0, lB1);
    __syncthreads();
    bf16x8 af[4], bfr[4];
#pragma unroll
    for (int i = 0; i < 4; i++)
      af[i] = *(const bf16x8*)(As + (wm + i * 16 + fr) * 32 + k8);
#pragma unroll
    for (int j = 0; j < 4; j++)
      bfr[j] = *(const bf16x8*)(Bs + (wn + j * 16 + fr) * 32 + k8);
#pragma unroll
    for (int i = 0; i < 4; i++)
#pragma unroll
      for (int j = 0; j < 4; j++)
        acc[i][j] = __builtin_amdgcn_mfma_f32_16x16x32_bf16(af[i], bfr[j], acc[i][j], 0, 0, 0);
    __syncthreads();
  }

  const int rbase = (lane >> 4) * 4;
  if (mode == 0) {
    const int which = n0 >> 10;
    const float* bias = (which == 0) ? b0 : ((which == 1) ? b1 : b2);
    const float post = (which == 0) ? 0.18033688011f : 1.0f;  // 0.125*log2(e)
    u16* outb = qkv_out + (size_t)which * 8388608;
#pragma unroll
    for (int j = 0; j < 4; j++) {
      const int nn = (n0 + wn + j * 16 + fr) & 1023;
      const float bb = bias[nn];
      const int h = nn >> 6, dh = nn & 63;
#pragma unroll
      for (int i = 0; i < 4; i++) {
#pragma unroll
        for (int r = 0; r < 4; r++) {
          const int m = m0 + wm + i * 16 + rbase + r;
          const int bI = m >> 11, s = m & 2047;
          outb[(((size_t)bI * 16 + h) * 2048 + s) * 64 + dh] = f2bf((acc[i][j][r] + bb) * post);
        }
      }
    }
  } else {
#pragma unroll
    for (int j = 0; j < 4; j++) {
      const int n = n0 + wn + j * 16 + fr;
      const float bb = b0[n];
#pragma unroll
      for (int i = 0; i < 4; i++) {
#pragma unroll
        for (int r = 0; r < 4; r++) {
          const int m = m0 + wm + i * 16 + rbase + r;
          flat_out[(size_t)m * 1024 + n] = acc[i][j][r] + bb;
        }
      }
    }
  }
}

// ---------------- V transpose: [BH][S][64] -> [BH][64][S] ----------------
__global__ __launch_bounds__(256) void transpose_v(const u16* __restrict__ V, u16* __restrict__ VT) {
  __shared__ u16 t_s[64 * 72];
  const int tid = threadIdx.x;
  const int st = blockIdx.x << 6;
  const int bh = blockIdx.y;
  const u16* src = V + ((size_t)bh * 2048 + st) * 64;
#pragma unroll
  for (int p = 0; p < 2; p++) {
    int i = p * 256 + tid;
    int row = i >> 3, ch = i & 7;
    bf16x8 v = *(const bf16x8*)(src + row * 64 + ch * 8);
    *(bf16x8*)(t_s + row * 72 + ch * 8) = v;
  }
  __syncthreads();
  u16* dst = VT + (size_t)bh * 131072 + st;
#pragma unroll
  for (int p = 0; p < 2; p++) {
    int i = p * 256 + tid;
    int dh = i >> 3, ch = i & 7;
    union { u16 s[8]; bf16x8 v; } u;
#pragma unroll
    for (int e = 0; e < 8; e++) u.s[e] = t_s[(ch * 8 + e) * 72 + dh];
    *(bf16x8*)(dst + (size_t)dh * 2048 + ch * 8) = u.v;
  }
}

// ---------------- MFMA flash attention: single q-tile, PV deferred, 3 blocks/CU ----------------
// Flat grid 1024; decode: qt = 15 - (bid>>6) (big tiles dispatched FIRST so the
// 32-iteration blocks start at t=0 and short ones backfill), bh%8 == bid%8
// (XCD-grouped K/V in L2).  LDS 51.7 KB -> 3 blocks/CU (12 waves).  Per
// iteration: barrier; issue DMA K(jt+1),V(jt); PV(jt-1) from resident P/V
// (deferred one tile); S(jt); softmax; write P(jt).  P rows wave-private;
// per-wave in-order LDS makes read-old-P-then-overwrite safe with ONE buffer.
__global__ __launch_bounds__(256, 3) void attn_fa(
    const u16* __restrict__ Qb, const u16* __restrict__ Kb,
    const u16* __restrict__ VT, u16* __restrict__ Ob)
{
  __shared__ u16 k_s[2 * 4096];      // dbuf [kn][d], 16B-chunks XOR'd by row
  __shared__ u16 v_s[2 * 4096];      // dbuf [dn][k], same swizzle (lags K by 1 tile)
  __shared__ u16 p_s[128 * 72];      // [q][key] bf16, stride 72 (wave-private rows)
  __shared__ float l_s[128];

  const int tid = threadIdx.x;
  const int lane = tid & 63;
  const int wave = tid >> 6;
  const int bid = (int)blockIdx.x;
  const int qt = 15 - (bid >> 6);               // big tiles first
  const int bh = (((bid >> 3) & 7) << 3) | (bid & 7);   // bh % 8 == bid % 8 (XCD)
  const size_t head = (size_t)bh << 17;
  const int fr = lane & 15;
  const int g = lane >> 4;
  const int k8 = g << 3;
  const int q0 = qt << 7;
  const int wrow = wave << 5;

  // Q fragments (pre-scaled); loop-invariant B-operands
  bf16x8 aq[2][2];
#pragma unroll
  for (int f = 0; f < 2; f++) {
    const u16* qp = Qb + head + (size_t)(q0 + wrow + (f << 4) + fr) * 64;
    aq[f][0] = *(const bf16x8*)(qp + k8);
    aq[f][1] = *(const bf16x8*)(qp + 32 + k8);
  }

  // ---- hoisted lane-constant offsets ----
  const int r0 = tid >> 3, c0 = tid & 7;
  const int r1 = 32 + r0;
  const int koff0 = r0 * 64 + (((c0 ^ r0) & 7) << 3);     // K staging src offsets
  const int koff1 = r1 * 64 + (((c0 ^ r1) & 7) << 3);
  const int voff0 = r0 * 2048 + (((c0 ^ r0) & 7) << 3);   // V^T staging src offsets
  const int voff1 = r1 * 2048 + (((c0 ^ r1) & 7) << 3);
  int kaddr[4][2], vaddr[2][4];                           // fragment-read offsets
#pragma unroll
  for (int j = 0; j < 4; j++) {
    const int kn = (j << 4) + fr;
    kaddr[j][0] = kn * 64 + (((g ^ kn) & 7) << 3);
    kaddr[j][1] = kn * 64 + ((((g + 4) ^ kn) & 7) << 3);
#pragma unroll
    for (int s2 = 0; s2 < 2; s2++)
      vaddr[s2][j] = kn * 64 + ((((s2 << 2) + g) ^ (kn & 7)) << 3);
  }
  u16* const prow0 = p_s + (wrow + fr) * 72;        // q row f=0 (write cols & read k8)
  u16* const prow1 = p_s + (wrow + 16 + fr) * 72;   // q row f=1
  const u16* Kbase = Kb + head;
  const u16* Vbase = VT + head;

  auto issueK = [&](int jt2, int buf) {
    const u16* Kt = Kbase + ((size_t)jt2 << 12);
    llds16(Kt + koff0, k_s + (buf << 12) + tid * 8);
    llds16(Kt + koff1, k_s + (buf << 12) + 2048 + tid * 8);
  };
  auto issueV = [&](int jt2, int buf) {
    const u16* Vt = Vbase + (jt2 << 6);
    llds16(Vt + voff0, v_s + (buf << 12) + tid * 8);
    llds16(Vt + voff1, v_s + (buf << 12) + 2048 + tid * 8);
  };

  f32x4 o_acc[2][4];
  const f32x4 zero = {0.f, 0.f, 0.f, 0.f};
#pragma unroll
  for (int f = 0; f < 2; f++)
#pragma unroll
    for (int j = 0; j < 4; j++) o_acc[f][j] = zero;
  float l_run[2] = {0.f, 0.f};

  const int jmax = 2 * qt + 1;                 // jmax+1 iterations (even count)
  const int jt_diag = 2 * qt + (wave >> 1);    // per-wave diagonal tile

  auto do_pv = [&](const u16* vs) {
#pragma unroll
    for (int s2 = 0; s2 < 2; s2++) {
      const bf16x8 ap0 = *(const bf16x8*)(prow0 + (s2 << 5) + k8);
      const bf16x8 ap1 = *(const bf16x8*)(prow1 + (s2 << 5) + k8);
#pragma unroll
      for (int j = 0; j < 4; j++) {
        const bf16x8 bv = *(const bf16x8*)(vs + vaddr[s2][j]);
        o_acc[0][j] = __builtin_amdgcn_mfma_f32_16x16x32_bf16(ap0, bv, o_acc[0][j], 0, 0, 0);
        o_acc[1][j] = __builtin_amdgcn_mfma_f32_16x16x32_bf16(ap1, bv, o_acc[1][j], 0, 0, 0);
      }
    }
  };

  auto do_s = [&](const u16* ks, bool dodiag, int jt) {
    f32x4 s_acc[2][4];
#pragma unroll
    for (int f = 0; f < 2; f++)
#pragma unroll
      for (int j = 0; j < 4; j++) s_acc[f][j] = zero;
#pragma unroll
    for (int j = 0; j < 4; j++) {
      const bf16x8 ka0 = *(const bf16x8*)(ks + kaddr[j][0]);
      const bf16x8 ka1 = *(const bf16x8*)(ks + kaddr[j][1]);
      s_acc[0][j] = __builtin_amdgcn_mfma_f32_16x16x32_bf16(ka0, aq[0][0], s_acc[0][j], 0, 0, 0);
      s_acc[0][j] = __builtin_amdgcn_mfma_f32_16x16x32_bf16(ka1, aq[0][1], s_acc[0][j], 0, 0, 0);
      s_acc[1][j] = __builtin_amdgcn_mfma_f32_16x16x32_bf16(ka0, aq[1][0], s_acc[1][j], 0, 0, 0);
      s_acc[1][j] = __builtin_amdgcn_mfma_f32_16x16x32_bf16(ka1, aq[1][1], s_acc[1][j], 0, 0, 0);
    }
#pragma unroll
    for (int f = 0; f < 2; f++) {
      const int qa = q0 + wrow + (f << 4) + fr;
      u16* prow = (f == 0) ? prow0 : prow1;
      if (dodiag) {
#pragma unroll
        for (int j = 0; j < 4; j++) {
          const int kb = (jt << 6) + (j << 4) + (g << 2);
          float p0 = (kb + 0 > qa) ? 0.f : __builtin_amdgcn_exp2f(s_acc[f][j][0]);
          float p1 = (kb + 1 > qa) ? 0.f : __builtin_amdgcn_exp2f(s_acc[f][j][1]);
          float p2 = (kb + 2 > qa) ? 0.f : __builtin_amdgcn_exp2f(s_acc[f][j][2]);
          float p3 = (kb + 3 > qa) ? 0.f : __builtin_amdgcn_exp2f(s_acc[f][j][3]);
          l_run[f] += (p0 + p1) + (p2 + p3);
          union { __hip_bfloat162 h; unsigned u; } ca, cb;
          ca.h = __float22bfloat162_rn(make_float2(p0, p1));
          cb.h = __float22bfloat162_rn(make_float2(p2, p3));
          *(uint2*)(prow + (j << 4) + (g << 2)) = make_uint2(ca.u, cb.u);
        }
      } else {
#pragma unroll
        for (int j = 0; j < 4; j++) {
          float p0 = __builtin_amdgcn_exp2f(s_acc[f][j][0]);
          float p1 = __builtin_amdgcn_exp2f(s_acc[f][j][1]);
          float p2 = __builtin_amdgcn_exp2f(s_acc[f][j][2]);
          float p3 = __builtin_amdgcn_exp2f(s_acc[f][j][3]);
          l_run[f] += (p0 + p1) + (p2 + p3);
          union { __hip_bfloat162 h; unsigned u; } ca, cb;
          ca.h = __float22bfloat162_rn(make_float2(p0, p1));
          cb.h = __float22bfloat162_rn(make_float2(p2, p3));
          *(uint2*)(prow + (j << 4) + (g << 2)) = make_uint2(ca.u, cb.u);
        }
      }
    }
  };

  issueK(0, 0);   // prime K pipeline (V(0) issued inside iteration 0)

  for (int jt = 0; jt <= jmax; jt++) {
    const int kb = jt & 1;
    __syncthreads();                       // K(jt) + V(jt-1) landed; LDS reads drained
    if (jt < jmax) issueK(jt + 1, kb ^ 1);
    issueV(jt, kb);
    if (jt > 0 && jt - 1 <= jt_diag) do_pv(v_s + ((kb ^ 1) << 12));   // deferred PV
    if (jt <= jt_diag) do_s(k_s + (kb << 12), jt == jt_diag, jt);
  }
  __syncthreads();                         // V(jmax) landed
  if (jt_diag == jmax) do_pv(v_s + ((jmax & 1) << 12));   // waves 2,3 final PV

  // epilogue: reduce l (q-col lives in lanes fr, fr+16, fr+32, fr+48)
#pragma unroll
  for (int f = 0; f < 2; f++) {
    float l = l_run[f];
    l += __shfl_xor(l, 16);
    l += __shfl_xor(l, 32);
    if (g == 0) l_s[wrow + (f << 4) + fr] = l;   // wave-private slot
  }
  const int b = bh >> 4, h = bh & 15;
#pragma unroll
  for (int f = 0; f < 2; f++) {
#pragma unroll
    for (int r = 0; r < 4; r++) {
      const int qloc = wrow + (f << 4) + (g << 2) + r;
      const float inv = 1.f / l_s[qloc];
      const int q_abs = q0 + qloc;
#pragma unroll
      for (int j = 0; j < 4; j++)
        Ob[((size_t)b * 2048 + q_abs) * 1024 + (h << 6) + (j << 4) + fr] =
            f2bf(o_acc[f][j][r] * inv);
    }
  }
}

// ---------------- launch ----------------
extern "C" void kernel_launch(void* const* d_in, const int* in_sizes, int n_in,
                              void* d_out, int out_size, void* d_ws, size_t ws_size,
                              hipStream_t stream) {
  const float* x  = (const float*)d_in[0];
  const float* Wq = (const float*)d_in[1];
  const float* bq = (const float*)d_in[2];
  const float* Wk = (const float*)d_in[3];
  const float* bk = (const float*)d_in[4];
  const float* Wv = (const float*)d_in[5];
  const float* bv = (const float*)d_in[6];
  const float* Wo = (const float*)d_in[7];
  const float* bo = (const float*)d_in[8];
  float* out = (float*)d_out;

  char* ws = (char*)d_ws;
  u16* xb    = (u16*)(ws);                 // 16 MB; dead after QKV GEMM
  u16* vT    = (u16*)(ws);                 // aliases xb: V^T [BH][64][S]
  u16* wqkv  = (u16*)(ws + 16777216);      // 6 MB packed q|k|v weights
  u16* wo    = (u16*)(ws + 23068672);      // 2 MB
  u16* qkv   = (u16*)(ws + 25165824);      // 48 MB, [3][BH][S][DH]
  u16* attnb = (u16*)(ws + 75497472);      // 16 MB, [B,S,D]
  // total ws: 92,274,688 B

  cast_bf16_kernel<<<8192, 256, 0, stream>>>(x, xb, 2097152);
  cast4_kernel<<<dim3(1024, 4), 256, 0, stream>>>(
      Wq, Wk, Wv, Wo, wqkv, wqkv + 1048576, wqkv + 2097152, wo, 262144);

  // fused QKV projection: M=8192, N=3072, K=1024 (256x192 8-phase, 2 clean rounds)
  gemm_qkv_256<<<dim3(512), 512, 0, stream>>>(xb, wqkv, bq, bk, bv, qkv);

  // V [BH][S][64] -> V^T [BH][64][S]  (xb dead; vT aliases it)
  transpose_v<<<dim3(32, 64), 256, 0, stream>>>(qkv + 16777216, vT);

  // MFMA flash attention (single q-tile/block, big-first dispatch, 3 blocks/CU)
  attn_fa<<<dim3(1024), 256, 0, stream>>>(qkv, qkv + 8388608, vT, attnb);

  // output projection: M=8192, N=1024, K=1024 -> fp32 d_out
  gemm_bt<<<dim3(8, 64), 256, 0, stream>>>(attnb, wo, bo, bo, bo, nullptr, out, 1024, 1);
}

// Round 6
// 241.969 us; speedup vs baseline: 1.3447x; 1.0237x over previous
//
#include <hip/hip_runtime.h>
#include <hip/hip_bf16.h>
#include <cstdint>
#include <cstddef>

// B=4, S=2048, D=1024, H=16, DH=64.  M = B*S = 8192.
// cast->bf16; fused QKV GEMM via 256x192-tile 6-phase pipelined MFMA kernel
// (T2 swizzle + counted-vmcnt + setprio, raw s_barrier; 16-MFMA balanced
// phases; grid 512 = 2 clean rounds, A-panels XCD-grouped; LDS-staged
// coalesced epilogue); V transpose; MFMA flash attention (single q-tile,
// big-first dispatch, 3 blocks/CU); output GEMM via 256x128-tile 6-phase
// kernel (grid 256 = 1 clean round).  Workspace: 92,274,688 B.
// (Round 5 failed on container acquire, not kernel: resubmitted unchanged
// after re-verifying barrier uniformity, stage/read hazards, vmcnt ledger.)

typedef unsigned short u16;
typedef __bf16 bf16x8 __attribute__((ext_vector_type(8)));
typedef float  f32x4  __attribute__((ext_vector_type(4)));

__device__ __forceinline__ u16 f2bf(float f) {
  unsigned u = __float_as_uint(f);
  unsigned r = u + 0x7fffu + ((u >> 16) & 1u);   // RNE
  return (u16)(r >> 16);
}

// async global->LDS, 16B per lane (dest = wave-uniform base + lane*16)
__device__ __forceinline__ void llds16(const u16* g, u16* l) {
  __builtin_amdgcn_global_load_lds(
      (const __attribute__((address_space(1))) void*)g,
      (__attribute__((address_space(3))) void*)l, 16, 0, 0);
}

// ---------------- cast fp32 -> bf16 ----------------
__global__ void cast_bf16_kernel(const float* __restrict__ in, u16* __restrict__ out, int n4) {
  int i = blockIdx.x * blockDim.x + threadIdx.x;
  if (i >= n4) return;
  float4 f = ((const float4*)in)[i];
  ushort4 u;
  u.x = f2bf(f.x); u.y = f2bf(f.y); u.z = f2bf(f.z); u.w = f2bf(f.w);
  ((ushort4*)out)[i] = u;
}

// 4 weight matrices in one launch (grid.y selects)
__global__ void cast4_kernel(const float* __restrict__ a, const float* __restrict__ b,
                             const float* __restrict__ c, const float* __restrict__ d,
                             u16* __restrict__ oa, u16* __restrict__ ob,
                             u16* __restrict__ oc, u16* __restrict__ od, int n4) {
  const int w = blockIdx.y;
  const float* src = (w == 0) ? a : (w == 1) ? b : (w == 2) ? c : d;
  u16* dst = (w == 0) ? oa : (w == 1) ? ob : (w == 2) ? oc : od;
  int i = blockIdx.x * blockDim.x + threadIdx.x;
  if (i >= n4) return;
  float4 f = ((const float4*)src)[i];
  ushort4 u;
  u.x = f2bf(f.x); u.y = f2bf(f.y); u.z = f2bf(f.z); u.w = f2bf(f.w);
  ((ushort4*)dst)[i] = u;
}

// ---------------- 256x192 6-phase QKV GEMM: qkv = x * Wqkv^T + bias ----------------
// M=8192, N=3072, K=1024.  512 threads = 8 waves (2M x 4N); per-wave C = 128x48.
// Grid 512 = 32 mt x 16 nt = exactly 2 full rounds (1 block/CU, zero tail).
// LDS 112 KiB: buf{0,1} x [A(256x64) | B(192x64)] u16, 16B chunks XOR-swizzled.
// 3 phases per K-tile, 16 MFMA each (i0-7 x j0-1 split 2 ways, then i0-7 x j2).
// Stage windows: into buf1 during buf0 phases and vice versa; A0-of-next-next
// staged only in the j2 phase (no A readers there).  vmcnt ledger: 9
// outstanding at each wait, vmcnt(2) retires the 7 the next K-tile reads.
__global__ __launch_bounds__(512) void gemm_qkv_256(
    const u16* __restrict__ A, const u16* __restrict__ Bw,
    const float* __restrict__ b0, const float* __restrict__ b1, const float* __restrict__ b2,
    u16* __restrict__ qkv_out)
{
  __shared__ u16 lds[57344];   // 112 KiB (reused as epilogue staging [256][200])

  const int tid = threadIdx.x;
  const int lane = tid & 63;
  const int wave = tid >> 6;

  // XCD-grouped decode: xcd = bid&7; each XCD owns 4 m-panels x all 16 n-tiles.
  const int bid = (int)blockIdx.x;
  const int xcd = bid & 7;
  const int idx = bid >> 3;                 // 0..63
  const int mt = (xcd << 2) | (idx & 3);    // 0..31
  const int nt = idx >> 2;                  // 0..15
  const int m0 = mt << 8;
  const int n0 = nt * 192;

  const int warp_m = wave >> 2;       // 0..1
  const int warp_n = wave & 3;        // 0..3
  const int wm = warp_m << 7;         // 0,128
  const int wn = warp_n * 48;         // 0,48,96,144
  const int fr = lane & 15;
  const int g  = lane >> 4;           // 0..3

  // staging source (pre-swizzled global addr so linear LDS dest lands swizzled)
  const int srow = tid >> 3;                       // 0..63
  const int schk = ((tid & 7) ^ (srow & 7)) << 3;  // stored chunk -> logical col
  const u16* pA = A  + (size_t)(m0 + srow) * 1024 + schk;
  const u16* pB = Bw + (size_t)(n0 + srow) * 1024 + schk;

  // fragment-read swizzled chunk offsets (chunk = s*4+g, stored = chunk^(row&7))
  const int rsw0 = ((g    ) ^ (fr & 7)) << 3;
  const int rsw1 = ((g ^ 4) ^ (fr & 7)) << 3;

  // read bases (include fr*64 row offset); buf stride 28672 u16
  const u16* Ab0 = lds + (size_t)(wm + fr) * 64;
  const u16* Bb0 = lds + 16384 + (size_t)(wn + fr) * 64;
  const u16* Ab1 = Ab0 + 28672;
  const u16* Bb1 = Bb0 + 28672;

  f32x4 acc[8][3];
  const f32x4 zero = {0.f, 0.f, 0.f, 0.f};
#pragma unroll
  for (int i = 0; i < 8; i++)
#pragma unroll
    for (int j = 0; j < 3; j++) acc[i][j] = zero;

  bf16x8 a_[8][2];
  bf16x8 b_[3][2];

  auto stageA = [&](int kt, int buf, int half) {   // 2 loads (128 rows)
    const u16* src = pA + (size_t)half * 131072 + (kt << 6);
    u16* dst = lds + buf * 28672 + half * 8192 + tid * 8;
    llds16(src, dst);
    llds16(src + 65536, dst + 4096);
  };
  auto stageB0 = [&](int kt, int buf) {            // 2 loads (rows 0-127)
    const u16* src = pB + (kt << 6);
    u16* dst = lds + buf * 28672 + 16384 + tid * 8;
    llds16(src, dst);
    llds16(src + 65536, dst + 4096);
  };
  auto stageB1 = [&](int kt, int buf) {            // 1 load (rows 128-191)
    const u16* src = pB + 131072 + (kt << 6);
    u16* dst = lds + buf * 28672 + 24576 + tid * 8;
    llds16(src, dst);
  };
  auto loadA4 = [&](const u16* Ab, int ib) {
#pragma unroll
    for (int ii = 0; ii < 4; ii++) {
      const u16* r = Ab + (ib + ii) * 1024;
      a_[ib + ii][0] = *(const bf16x8*)(r + rsw0);
      a_[ib + ii][1] = *(const bf16x8*)(r + rsw1);
    }
  };
  auto loadB = [&](const u16* Bb, int j0, int nj) {
#pragma unroll
    for (int jj = 0; jj < 3; jj++) {
      if (jj < nj) {
        const u16* r = Bb + (j0 + jj) * 1024;
        b_[j0 + jj][0] = *(const bf16x8*)(r + rsw0);
        b_[j0 + jj][1] = *(const bf16x8*)(r + rsw1);
      }
    }
  };
  auto mfmaJ01 = [&](int ib) {   // 16 MFMA: i ib..ib+3 x j0,j1 x 2 k-halves
    __builtin_amdgcn_s_setprio(1);
#pragma unroll
    for (int jj = 0; jj < 2; jj++)
#pragma unroll
      for (int ii = 0; ii < 4; ii++) {
        acc[ib+ii][jj] = __builtin_amdgcn_mfma_f32_16x16x32_bf16(
            a_[ib+ii][0], b_[jj][0], acc[ib+ii][jj], 0, 0, 0);
        acc[ib+ii][jj] = __builtin_amdgcn_mfma_f32_16x16x32_bf16(
            a_[ib+ii][1], b_[jj][1], acc[ib+ii][jj], 0, 0, 0);
      }
    __builtin_amdgcn_s_setprio(0);
  };
  auto mfmaJ2 = [&]() {          // 16 MFMA: i0-7 x j2 x 2 k-halves
    __builtin_amdgcn_s_setprio(1);
#pragma unroll
    for (int ii = 0; ii < 8; ii++) {
      acc[ii][2] = __builtin_amdgcn_mfma_f32_16x16x32_bf16(
          a_[ii][0], b_[2][0], acc[ii][2], 0, 0, 0);
      acc[ii][2] = __builtin_amdgcn_mfma_f32_16x16x32_bf16(
          a_[ii][1], b_[2][1], acc[ii][2], 0, 0, 0);
    }
    __builtin_amdgcn_s_setprio(0);
  };

  // prologue: buf0 <- K-tile 0 (A0,A1,B0,B1 = 7 loads), buf1.A0 <- K-tile 1 (2)
  stageA(0, 0, 0);
  stageA(0, 0, 1);
  stageB0(0, 0);
  stageB1(0, 0);
  stageA(1, 1, 0);
  asm volatile("s_waitcnt vmcnt(2)" ::: "memory");  // tile0 landed; tile1.A0 in flight
  __builtin_amdgcn_s_barrier();

  const int NTI = 8;   // K / 128
  for (int t = 0; t < NTI; ++t) {
    const bool st = (t < NTI - 1);
    const int ka = 2 * t + 1;
    const int kb = 2 * t + 2;
    const int kc = 2 * t + 3;

    // ---- K-tile 2t from buf0 ----
    // q0: A reads i0-3 + B j0-1; stage next.A1
    loadA4(Ab0, 0); loadB(Bb0, 0, 2);
    stageA(ka, 1, 1);
    __builtin_amdgcn_s_barrier();
    mfmaJ01(0);
    __builtin_amdgcn_s_barrier();
    // q1: A reads i4-7; stage next.B0
    loadA4(Ab0, 4);
    stageB0(ka, 1);
    __builtin_amdgcn_s_barrier();
    mfmaJ01(4);
    __builtin_amdgcn_s_barrier();
    // q2: B j2 read only (no A readers); stage next.B1 + next2.A0
    loadB(Bb0, 2, 1);
    stageB1(ka, 1);
    if (st) stageA(kb, 0, 0);
    __builtin_amdgcn_s_barrier();
    mfmaJ2();
    if (st) { asm volatile("s_waitcnt vmcnt(2)" ::: "memory"); }
    else    { asm volatile("s_waitcnt vmcnt(0)" ::: "memory"); }
    __builtin_amdgcn_s_barrier();

    // ---- K-tile 2t+1 from buf1 ----
    // q3
    loadA4(Ab1, 0); loadB(Bb1, 0, 2);
    if (st) stageA(kb, 0, 1);
    __builtin_amdgcn_s_barrier();
    mfmaJ01(0);
    __builtin_amdgcn_s_barrier();
    // q4
    loadA4(Ab1, 4);
    if (st) stageB0(kb, 0);
    __builtin_amdgcn_s_barrier();
    mfmaJ01(4);
    __builtin_amdgcn_s_barrier();
    // q5
    loadB(Bb1, 2, 1);
    if (st) { stageB1(kb, 0); stageA(kc, 1, 0); }
    __builtin_amdgcn_s_barrier();
    mfmaJ2();
    if (st) { asm volatile("s_waitcnt vmcnt(2)" ::: "memory"); }
    __builtin_amdgcn_s_barrier();
  }

  // ---- epilogue: bias+post -> LDS [256][200] -> coalesced 16B stores ----
  __syncthreads();
  const int bI  = m0 >> 11;
  const int s0m = m0 & 2047;
#pragma unroll
  for (int j = 0; j < 3; j++) {
    const int ncol = n0 + wn + j * 16 + fr;
    const int which = ncol >> 10;
    const float bb = ((which == 0) ? b0 : (which == 1) ? b1 : b2)[ncol & 1023];
    const float post = (which == 0) ? 0.18033688011f : 1.0f;  // 0.125*log2(e)
    const int cl = wn + j * 16 + fr;
#pragma unroll
    for (int i = 0; i < 8; i++) {
#pragma unroll
      for (int r = 0; r < 4; r++) {
        const int row = wm + i * 16 + g * 4 + r;
        lds[row * 200 + cl] = f2bf((acc[i][j][r] + bb) * post);
      }
    }
  }
  __syncthreads();
  const int part = tid & 7;
#pragma unroll
  for (int p = 0; p < 12; p++) {
    const int hc = p >> 2;
    const int ml = ((p & 3) << 6) + (tid >> 3);
    const int ncol0 = n0 + hc * 64;
    const int which = ncol0 >> 10;
    const int h = (ncol0 >> 6) & 15;
    const bf16x8 v = *(const bf16x8*)(lds + ml * 200 + hc * 64 + part * 8);
    *(bf16x8*)(qkv_out + (size_t)which * 8388608 +
               ((size_t)(bI * 16 + h) * 2048 + s0m + ml) * 64 + part * 8) = v;
  }
}

// ---------------- 256x128 6-phase output GEMM: out = attn * Wo^T + bo (fp32) ----------------
// M=8192, N=1024, K=1024.  Grid 256 = 32 mt x 8 nt = exactly 1 round, 1 block/CU.
// 8 waves (2M x 4N); per-wave C = 128x32 (acc[8][2]).  LDS 96 KiB:
// buf{0,1} x [A(256x64) 16384 | B(128x64) 8192] u16, XOR-swizzled chunks.
// 3 phases per K-tile (16/8/8 MFMA); A0-of-next-next staged in the j1 phase
// (no A readers).  vmcnt ledger: 8 outstanding at each wait, vmcnt(2)
// retires the 6 the next K-tile reads.
__global__ __launch_bounds__(512) void gemm_o_256(
    const u16* __restrict__ A, const u16* __restrict__ Bw,
    const float* __restrict__ bo, float* __restrict__ out)
{
  __shared__ u16 lds[49152];   // 96 KiB

  const int tid = threadIdx.x;
  const int lane = tid & 63;
  const int wave = tid >> 6;

  const int bid = (int)blockIdx.x;
  const int xcd = bid & 7;
  const int idx = bid >> 3;                 // 0..31
  const int mt = (xcd << 2) | (idx & 3);    // 0..31
  const int nt = idx >> 2;                  // 0..7
  const int m0 = mt << 8;
  const int n0 = nt << 7;

  const int warp_m = wave >> 2;
  const int warp_n = wave & 3;
  const int wm = warp_m << 7;
  const int wn = warp_n << 5;               // 0,32,64,96
  const int fr = lane & 15;
  const int g  = lane >> 4;

  const int srow = tid >> 3;
  const int schk = ((tid & 7) ^ (srow & 7)) << 3;
  const u16* pA = A  + (size_t)(m0 + srow) * 1024 + schk;
  const u16* pB = Bw + (size_t)(n0 + srow) * 1024 + schk;

  const int rsw0 = ((g    ) ^ (fr & 7)) << 3;
  const int rsw1 = ((g ^ 4) ^ (fr & 7)) << 3;

  const u16* Ab0 = lds + (size_t)(wm + fr) * 64;
  const u16* Bb0 = lds + 16384 + (size_t)(wn + fr) * 64;
  const u16* Ab1 = Ab0 + 24576;
  const u16* Bb1 = Bb0 + 24576;

  f32x4 acc[8][2];
  const f32x4 zero = {0.f, 0.f, 0.f, 0.f};
#pragma unroll
  for (int i = 0; i < 8; i++)
#pragma unroll
    for (int j = 0; j < 2; j++) acc[i][j] = zero;

  bf16x8 a_[8][2];
  bf16x8 b_[2][2];

  auto stageA = [&](int kt, int buf, int half) {   // 2 loads (128 rows)
    const u16* src = pA + (size_t)half * 131072 + (kt << 6);
    u16* dst = lds + buf * 24576 + half * 8192 + tid * 8;
    llds16(src, dst);
    llds16(src + 65536, dst + 4096);
  };
  auto stageB = [&](int kt, int buf) {             // 2 loads (128 rows)
    const u16* src = pB + (kt << 6);
    u16* dst = lds + buf * 24576 + 16384 + tid * 8;
    llds16(src, dst);
    llds16(src + 65536, dst + 4096);
  };
  auto loadA4 = [&](const u16* Ab, int ib) {
#pragma unroll
    for (int ii = 0; ii < 4; ii++) {
      const u16* r = Ab + (ib + ii) * 1024;
      a_[ib + ii][0] = *(const bf16x8*)(r + rsw0);
      a_[ib + ii][1] = *(const bf16x8*)(r + rsw1);
    }
  };
  auto loadB2 = [&](const u16* Bb) {
#pragma unroll
    for (int jj = 0; jj < 2; jj++) {
      const u16* r = Bb + jj * 1024;
      b_[jj][0] = *(const bf16x8*)(r + rsw0);
      b_[jj][1] = *(const bf16x8*)(r + rsw1);
    }
  };
  auto mfma16 = [&](int ib) {
    __builtin_amdgcn_s_setprio(1);
#pragma unroll
    for (int jj = 0; jj < 2; jj++)
#pragma unroll
      for (int ii = 0; ii < 4; ii++) {
        acc[ib+ii][jj] = __builtin_amdgcn_mfma_f32_16x16x32_bf16(
            a_[ib+ii][0], b_[jj][0], acc[ib+ii][jj], 0, 0, 0);
        acc[ib+ii][jj] = __builtin_amdgcn_mfma_f32_16x16x32_bf16(
            a_[ib+ii][1], b_[jj][1], acc[ib+ii][jj], 0, 0, 0);
      }
    __builtin_amdgcn_s_setprio(0);
  };
  auto mfma8 = [&](int ib, int jj) {
    __builtin_amdgcn_s_setprio(1);
#pragma unroll
    for (int ii = 0; ii < 4; ii++) {
      acc[ib+ii][jj] = __builtin_amdgcn_mfma_f32_16x16x32_bf16(
          a_[ib+ii][0], b_[jj][0], acc[ib+ii][jj], 0, 0, 0);
      acc[ib+ii][jj] = __builtin_amdgcn_mfma_f32_16x16x32_bf16(
          a_[ib+ii][1], b_[jj][1], acc[ib+ii][jj], 0, 0, 0);
    }
    __builtin_amdgcn_s_setprio(0);
  };

  // prologue: buf0 <- K-tile 0 (A0,A1,B = 6 loads), buf1.A0 <- K-tile 1 (2)
  stageA(0, 0, 0);
  stageA(0, 0, 1);
  stageB(0, 0);
  stageA(1, 1, 0);
  asm volatile("s_waitcnt vmcnt(2)" ::: "memory");
  __builtin_amdgcn_s_barrier();

  const int NTI = 8;   // K / 128
  for (int t = 0; t < NTI; ++t) {
    const bool st = (t < NTI - 1);
    const int ka = 2 * t + 1;
    const int kb = 2 * t + 2;
    const int kc = 2 * t + 3;

    // ---- K-tile 2t from buf0 ----
    // q0: A i0-3 + B; stage next.A1
    loadA4(Ab0, 0); loadB2(Bb0);
    stageA(ka, 1, 1);
    __builtin_amdgcn_s_barrier();
    mfma16(0);
    __builtin_amdgcn_s_barrier();
    // q1: A i4-7; stage next.B
    loadA4(Ab0, 4);
    stageB(ka, 1);
    __builtin_amdgcn_s_barrier();
    mfma8(4, 0);
    __builtin_amdgcn_s_barrier();
    // q2: no reads; stage next2.A0
    if (st) stageA(kb, 0, 0);
    __builtin_amdgcn_s_barrier();
    mfma8(4, 1);
    if (st) { asm volatile("s_waitcnt vmcnt(2)" ::: "memory"); }
    else    { asm volatile("s_waitcnt vmcnt(0)" ::: "memory"); }
    __builtin_amdgcn_s_barrier();

    // ---- K-tile 2t+1 from buf1 ----
    // q3
    loadA4(Ab1, 0); loadB2(Bb1);
    if (st) stageA(kb, 0, 1);
    __builtin_amdgcn_s_barrier();
    mfma16(0);
    __builtin_amdgcn_s_barrier();
    // q4
    loadA4(Ab1, 4);
    if (st) stageB(kb, 0);
    __builtin_amdgcn_s_barrier();
    mfma8(4, 0);
    __builtin_amdgcn_s_barrier();
    // q5
    if (st) stageA(kc, 1, 0);
    __builtin_amdgcn_s_barrier();
    mfma8(4, 1);
    if (st) { asm volatile("s_waitcnt vmcnt(2)" ::: "memory"); }
    __builtin_amdgcn_s_barrier();
  }

  // epilogue: fp32 direct stores with bias
#pragma unroll
  for (int j = 0; j < 2; j++) {
    const int n = n0 + wn + j * 16 + fr;
    const float bb = bo[n];
#pragma unroll
    for (int i = 0; i < 8; i++) {
#pragma unroll
      for (int r = 0; r < 4; r++) {
        const int m = m0 + wm + i * 16 + g * 4 + r;
        out[(size_t)m * 1024 + n] = acc[i][j][r] + bb;
      }
    }
  }
}

// ---------------- V transpose: [BH][S][64] -> [BH][64][S] ----------------
__global__ __launch_bounds__(256) void transpose_v(const u16* __restrict__ V, u16* __restrict__ VT) {
  __shared__ u16 t_s[64 * 72];
  const int tid = threadIdx.x;
  const int st = blockIdx.x << 6;
  const int bh = blockIdx.y;
  const u16* src = V + ((size_t)bh * 2048 + st) * 64;
#pragma unroll
  for (int p = 0; p < 2; p++) {
    int i = p * 256 + tid;
    int row = i >> 3, ch = i & 7;
    bf16x8 v = *(const bf16x8*)(src + row * 64 + ch * 8);
    *(bf16x8*)(t_s + row * 72 + ch * 8) = v;
  }
  __syncthreads();
  u16* dst = VT + (size_t)bh * 131072 + st;
#pragma unroll
  for (int p = 0; p < 2; p++) {
    int i = p * 256 + tid;
    int dh = i >> 3, ch = i & 7;
    union { u16 s[8]; bf16x8 v; } u;
#pragma unroll
    for (int e = 0; e < 8; e++) u.s[e] = t_s[(ch * 8 + e) * 72 + dh];
    *(bf16x8*)(dst + (size_t)dh * 2048 + ch * 8) = u.v;
  }
}

// ---------------- MFMA flash attention: single q-tile, PV deferred, 3 blocks/CU ----------------
__global__ __launch_bounds__(256, 3) void attn_fa(
    const u16* __restrict__ Qb, const u16* __restrict__ Kb,
    const u16* __restrict__ VT, u16* __restrict__ Ob)
{
  __shared__ u16 k_s[2 * 4096];      // dbuf [kn][d], 16B-chunks XOR'd by row
  __shared__ u16 v_s[2 * 4096];      // dbuf [dn][k], same swizzle (lags K by 1 tile)
  __shared__ u16 p_s[128 * 72];      // [q][key] bf16, stride 72 (wave-private rows)
  __shared__ float l_s[128];

  const int tid = threadIdx.x;
  const int lane = tid & 63;
  const int wave = tid >> 6;
  const int bid = (int)blockIdx.x;
  const int qt = 15 - (bid >> 6);               // big tiles first
  const int bh = (((bid >> 3) & 7) << 3) | (bid & 7);   // bh % 8 == bid % 8 (XCD)
  const size_t head = (size_t)bh << 17;
  const int fr = lane & 15;
  const int g = lane >> 4;
  const int k8 = g << 3;
  const int q0 = qt << 7;
  const int wrow = wave << 5;

  // Q fragments (pre-scaled); loop-invariant B-operands
  bf16x8 aq[2][2];
#pragma unroll
  for (int f = 0; f < 2; f++) {
    const u16* qp = Qb + head + (size_t)(q0 + wrow + (f << 4) + fr) * 64;
    aq[f][0] = *(const bf16x8*)(qp + k8);
    aq[f][1] = *(const bf16x8*)(qp + 32 + k8);
  }

  // ---- hoisted lane-constant offsets ----
  const int r0 = tid >> 3, c0 = tid & 7;
  const int r1 = 32 + r0;
  const int koff0 = r0 * 64 + (((c0 ^ r0) & 7) << 3);     // K staging src offsets
  const int koff1 = r1 * 64 + (((c0 ^ r1) & 7) << 3);
  const int voff0 = r0 * 2048 + (((c0 ^ r0) & 7) << 3);   // V^T staging src offsets
  const int voff1 = r1 * 2048 + (((c0 ^ r1) & 7) << 3);
  int kaddr[4][2], vaddr[2][4];                           // fragment-read offsets
#pragma unroll
  for (int j = 0; j < 4; j++) {
    const int kn = (j << 4) + fr;
    kaddr[j][0] = kn * 64 + (((g ^ kn) & 7) << 3);
    kaddr[j][1] = kn * 64 + ((((g + 4) ^ kn) & 7) << 3);
#pragma unroll
    for (int s2 = 0; s2 < 2; s2++)
      vaddr[s2][j] = kn * 64 + ((((s2 << 2) + g) ^ (kn & 7)) << 3);
  }
  u16* const prow0 = p_s + (wrow + fr) * 72;        // q row f=0 (write cols & read k8)
  u16* const prow1 = p_s + (wrow + 16 + fr) * 72;   // q row f=1
  const u16* Kbase = Kb + head;
  const u16* Vbase = VT + head;

  auto issueK = [&](int jt2, int buf) {
    const u16* Kt = Kbase + ((size_t)jt2 << 12);
    llds16(Kt + koff0, k_s + (buf << 12) + tid * 8);
    llds16(Kt + koff1, k_s + (buf << 12) + 2048 + tid * 8);
  };
  auto issueV = [&](int jt2, int buf) {
    const u16* Vt = Vbase + (jt2 << 6);
    llds16(Vt + voff0, v_s + (buf << 12) + tid * 8);
    llds16(Vt + voff1, v_s + (buf << 12) + 2048 + tid * 8);
  };

  f32x4 o_acc[2][4];
  const f32x4 zero = {0.f, 0.f, 0.f, 0.f};
#pragma unroll
  for (int f = 0; f < 2; f++)
#pragma unroll
    for (int j = 0; j < 4; j++) o_acc[f][j] = zero;
  float l_run[2] = {0.f, 0.f};

  const int jmax = 2 * qt + 1;                 // jmax+1 iterations (even count)
  const int jt_diag = 2 * qt + (wave >> 1);    // per-wave diagonal tile

  auto do_pv = [&](const u16* vs) {
#pragma unroll
    for (int s2 = 0; s2 < 2; s2++) {
      const bf16x8 ap0 = *(const bf16x8*)(prow0 + (s2 << 5) + k8);
      const bf16x8 ap1 = *(const bf16x8*)(prow1 + (s2 << 5) + k8);
#pragma unroll
      for (int j = 0; j < 4; j++) {
        const bf16x8 bv = *(const bf16x8*)(vs + vaddr[s2][j]);
        o_acc[0][j] = __builtin_amdgcn_mfma_f32_16x16x32_bf16(ap0, bv, o_acc[0][j], 0, 0, 0);
        o_acc[1][j] = __builtin_amdgcn_mfma_f32_16x16x32_bf16(ap1, bv, o_acc[1][j], 0, 0, 0);
      }
    }
  };

  auto do_s = [&](const u16* ks, bool dodiag, int jt) {
    f32x4 s_acc[2][4];
#pragma unroll
    for (int f = 0; f < 2; f++)
#pragma unroll
      for (int j = 0; j < 4; j++) s_acc[f][j] = zero;
#pragma unroll
    for (int j = 0; j < 4; j++) {
      const bf16x8 ka0 = *(const bf16x8*)(ks + kaddr[j][0]);
      const bf16x8 ka1 = *(const bf16x8*)(ks + kaddr[j][1]);
      s_acc[0][j] = __builtin_amdgcn_mfma_f32_16x16x32_bf16(ka0, aq[0][0], s_acc[0][j], 0, 0, 0);
      s_acc[0][j] = __builtin_amdgcn_mfma_f32_16x16x32_bf16(ka1, aq[0][1], s_acc[0][j], 0, 0, 0);
      s_acc[1][j] = __builtin_amdgcn_mfma_f32_16x16x32_bf16(ka0, aq[1][0], s_acc[1][j], 0, 0, 0);
      s_acc[1][j] = __builtin_amdgcn_mfma_f32_16x16x32_bf16(ka1, aq[1][1], s_acc[1][j], 0, 0, 0);
    }
#pragma unroll
    for (int f = 0; f < 2; f++) {
      const int qa = q0 + wrow + (f << 4) + fr;
      u16* prow = (f == 0) ? prow0 : prow1;
      if (dodiag) {
#pragma unroll
        for (int j = 0; j < 4; j++) {
          const int kb = (jt << 6) + (j << 4) + (g << 2);
          float p0 = (kb + 0 > qa) ? 0.f : __builtin_amdgcn_exp2f(s_acc[f][j][0]);
          float p1 = (kb + 1 > qa) ? 0.f : __builtin_amdgcn_exp2f(s_acc[f][j][1]);
          float p2 = (kb + 2 > qa) ? 0.f : __builtin_amdgcn_exp2f(s_acc[f][j][2]);
          float p3 = (kb + 3 > qa) ? 0.f : __builtin_amdgcn_exp2f(s_acc[f][j][3]);
          l_run[f] += (p0 + p1) + (p2 + p3);
          union { __hip_bfloat162 h; unsigned u; } ca, cb;
          ca.h = __float22bfloat162_rn(make_float2(p0, p1));
          cb.h = __float22bfloat162_rn(make_float2(p2, p3));
          *(uint2*)(prow + (j << 4) + (g << 2)) = make_uint2(ca.u, cb.u);
        }
      } else {
#pragma unroll
        for (int j = 0; j < 4; j++) {
          float p0 = __builtin_amdgcn_exp2f(s_acc[f][j][0]);
          float p1 = __builtin_amdgcn_exp2f(s_acc[f][j][1]);
          float p2 = __builtin_amdgcn_exp2f(s_acc[f][j][2]);
          float p3 = __builtin_amdgcn_exp2f(s_acc[f][j][3]);
          l_run[f] += (p0 + p1) + (p2 + p3);
          union { __hip_bfloat162 h; unsigned u; } ca, cb;
          ca.h = __float22bfloat162_rn(make_float2(p0, p1));
          cb.h = __float22bfloat162_rn(make_float2(p2, p3));
          *(uint2*)(prow + (j << 4) + (g << 2)) = make_uint2(ca.u, cb.u);
        }
      }
    }
  };

  issueK(0, 0);   // prime K pipeline (V(0) issued inside iteration 0)

  for (int jt = 0; jt <= jmax; jt++) {
    const int kb = jt & 1;
    __syncthreads();                       // K(jt) + V(jt-1) landed; LDS reads drained
    if (jt < jmax) issueK(jt + 1, kb ^ 1);
    issueV(jt, kb);
    if (jt > 0 && jt - 1 <= jt_diag) do_pv(v_s + ((kb ^ 1) << 12));   // deferred PV
    if (jt <= jt_diag) do_s(k_s + (kb << 12), jt == jt_diag, jt);
  }
  __syncthreads();                         // V(jmax) landed
  if (jt_diag == jmax) do_pv(v_s + ((jmax & 1) << 12));   // waves 2,3 final PV

  // epilogue: reduce l (q-col lives in lanes fr, fr+16, fr+32, fr+48)
#pragma unroll
  for (int f = 0; f < 2; f++) {
    float l = l_run[f];
    l += __shfl_xor(l, 16);
    l += __shfl_xor(l, 32);
    if (g == 0) l_s[wrow + (f << 4) + fr] = l;   // wave-private slot
  }
  const int b = bh >> 4, h = bh & 15;
#pragma unroll
  for (int f = 0; f < 2; f++) {
#pragma unroll
    for (int r = 0; r < 4; r++) {
      const int qloc = wrow + (f << 4) + (g << 2) + r;
      const float inv = 1.f / l_s[qloc];
      const int q_abs = q0 + qloc;
#pragma unroll
      for (int j = 0; j < 4; j++)
        Ob[((size_t)b * 2048 + q_abs) * 1024 + (h << 6) + (j << 4) + fr] =
            f2bf(o_acc[f][j][r] * inv);
    }
  }
}

// ---------------- launch ----------------
extern "C" void kernel_launch(void* const* d_in, const int* in_sizes, int n_in,
                              void* d_out, int out_size, void* d_ws, size_t ws_size,
                              hipStream_t stream) {
  const float* x  = (const float*)d_in[0];
  const float* Wq = (const float*)d_in[1];
  const float* bq = (const float*)d_in[2];
  const float* Wk = (const float*)d_in[3];
  const float* bk = (const float*)d_in[4];
  const float* Wv = (const float*)d_in[5];
  const float* bv = (const float*)d_in[6];
  const float* Wo = (const float*)d_in[7];
  const float* bo = (const float*)d_in[8];
  float* out = (float*)d_out;

  char* ws = (char*)d_ws;
  u16* xb    = (u16*)(ws);                 // 16 MB; dead after QKV GEMM
  u16* vT    = (u16*)(ws);                 // aliases xb: V^T [BH][64][S]
  u16* wqkv  = (u16*)(ws + 16777216);      // 6 MB packed q|k|v weights
  u16* wo    = (u16*)(ws + 23068672);      // 2 MB
  u16* qkv   = (u16*)(ws + 25165824);      // 48 MB, [3][BH][S][DH]
  u16* attnb = (u16*)(ws + 75497472);      // 16 MB, [B,S,D]
  // total ws: 92,274,688 B

  cast_bf16_kernel<<<8192, 256, 0, stream>>>(x, xb, 2097152);
  cast4_kernel<<<dim3(1024, 4), 256, 0, stream>>>(
      Wq, Wk, Wv, Wo, wqkv, wqkv + 1048576, wqkv + 2097152, wo, 262144);

  // fused QKV projection: M=8192, N=3072, K=1024 (256x192 6-phase, 2 clean rounds)
  gemm_qkv_256<<<dim3(512), 512, 0, stream>>>(xb, wqkv, bq, bk, bv, qkv);

  // V [BH][S][64] -> V^T [BH][64][S]  (xb dead; vT aliases it)
  transpose_v<<<dim3(32, 64), 256, 0, stream>>>(qkv + 16777216, vT);

  // MFMA flash attention (single q-tile/block, big-first dispatch, 3 blocks/CU)
  attn_fa<<<dim3(1024), 256, 0, stream>>>(qkv, qkv + 8388608, vT, attnb);

  // output projection: M=8192, N=1024, K=1024 (256x128 6-phase, 1 clean round)
  gemm_o_256<<<dim3(256), 512, 0, stream>>>(attnb, wo, bo, out);
}

// Round 7
// 238.684 us; speedup vs baseline: 1.3632x; 1.0138x over previous
//
#include <hip/hip_runtime.h>
#include <hip/hip_bf16.h>
#include <cstdint>
#include <cstddef>

// B=4, S=2048, D=1024, H=16, DH=64.  M = B*S = 8192.
// fused cast (x + 4 weights, one launch); fused QKV GEMM via 256x192-tile
// 8-phase pipelined MFMA kernel (T2 swizzle + counted-vmcnt + setprio, raw
// s_barrier; p3/p7 are ds_read-free MFMA phases -- proven 60.4us schedule);
// V transpose; MFMA flash attention (single q-tile, big-first dispatch,
// 3 blocks/CU); output GEMM via 256x128-tile 6-phase kernel (1 clean round).
// attnb aliases the dead V-original region: workspace 75,497,472 B.

typedef unsigned short u16;
typedef __bf16 bf16x8 __attribute__((ext_vector_type(8)));
typedef float  f32x4  __attribute__((ext_vector_type(4)));

__device__ __forceinline__ u16 f2bf(float f) {
  unsigned u = __float_as_uint(f);
  unsigned r = u + 0x7fffu + ((u >> 16) & 1u);   // RNE
  return (u16)(r >> 16);
}

// async global->LDS, 16B per lane (dest = wave-uniform base + lane*16)
__device__ __forceinline__ void llds16(const u16* g, u16* l) {
  __builtin_amdgcn_global_load_lds(
      (const __attribute__((address_space(1))) void*)g,
      (__attribute__((address_space(3))) void*)l, 16, 0, 0);
}

// ---------------- fused cast fp32 -> bf16 (x + Wq,Wk,Wv,Wo) ----------------
// blocks [0,8192): x (2097152 float4); blocks [8192,12288): weights
// (4 x 262144 float4 -> wqkv packed q|k|v and wo).
__global__ void cast_all_kernel(const float* __restrict__ x,
                                const float* __restrict__ Wq, const float* __restrict__ Wk,
                                const float* __restrict__ Wv, const float* __restrict__ Wo,
                                u16* __restrict__ xb, u16* __restrict__ wqkv,
                                u16* __restrict__ wo) {
  const int bid = (int)blockIdx.x;
  const int tid = threadIdx.x;
  if (bid < 8192) {
    const int i = (bid << 8) + tid;
    float4 f = ((const float4*)x)[i];
    ushort4 u;
    u.x = f2bf(f.x); u.y = f2bf(f.y); u.z = f2bf(f.z); u.w = f2bf(f.w);
    ((ushort4*)xb)[i] = u;
  } else {
    const int j = ((bid - 8192) << 8) + tid;   // 0..1048575
    const int w = j >> 18;                     // 0..3
    const int idx = j & 262143;
    const float* src = (w == 0) ? Wq : (w == 1) ? Wk : (w == 2) ? Wv : Wo;
    u16* dst = (w == 3) ? wo : (wqkv + (w << 20));
    float4 f = ((const float4*)src)[idx];
    ushort4 u;
    u.x = f2bf(f.x); u.y = f2bf(f.y); u.z = f2bf(f.z); u.w = f2bf(f.w);
    ((ushort4*)dst)[idx] = u;
  }
}

// ---------------- 256x192 8-phase QKV GEMM: qkv = x * Wqkv^T + bias ----------------
// M=8192, N=3072, K=1024.  512 threads = 8 waves (2M x 4N); per-wave C = 128x48.
// Grid 512 = 32 mt x 16 nt = exactly 2 full rounds (1 block/CU, zero tail).
// LDS 112 KiB: buf{0,1} x [A(256x64) | B(192x64)] u16, 16B chunks XOR-swizzled.
// 4 phases per K-tile: p0 {ldA0-3,ldB0-1 -> 16 MFMA}, p1 {ldB2 -> 8}, p2
// {ldA4-7 -> 8}, p3 {NO ds_reads -> 16 MFMA} -- the read-free p3/p7 phases
// start MFMA with zero lgkm drain (this beat the 6-phase variant by 11%).
// Staging units per K-tile (7 llds16/thread): A0(2) A1(2) B0(2) B1(1);
// vmcnt(2) at p3/p7 retires the 7 loads the next K-tile reads.
__global__ __launch_bounds__(512) void gemm_qkv_256(
    const u16* __restrict__ A, const u16* __restrict__ Bw,
    const float* __restrict__ b0, const float* __restrict__ b1, const float* __restrict__ b2,
    u16* __restrict__ qkv_out)
{
  __shared__ u16 lds[57344];   // 112 KiB (reused as epilogue staging [256][200])

  const int tid = threadIdx.x;
  const int lane = tid & 63;
  const int wave = tid >> 6;

  // XCD-grouped decode: xcd = bid&7; each XCD owns 4 m-panels x all 16 n-tiles.
  const int bid = (int)blockIdx.x;
  const int xcd = bid & 7;
  const int idx = bid >> 3;                 // 0..63
  const int mt = (xcd << 2) | (idx & 3);    // 0..31
  const int nt = idx >> 2;                  // 0..15
  const int m0 = mt << 8;
  const int n0 = nt * 192;

  const int warp_m = wave >> 2;       // 0..1
  const int warp_n = wave & 3;        // 0..3
  const int wm = warp_m << 7;         // 0,128
  const int wn = warp_n * 48;         // 0,48,96,144
  const int fr = lane & 15;
  const int g  = lane >> 4;           // 0..3

  // staging source (pre-swizzled global addr so linear LDS dest lands swizzled)
  const int srow = tid >> 3;                       // 0..63
  const int schk = ((tid & 7) ^ (srow & 7)) << 3;  // stored chunk -> logical col
  const u16* pA = A  + (size_t)(m0 + srow) * 1024 + schk;
  const u16* pB = Bw + (size_t)(n0 + srow) * 1024 + schk;

  // fragment-read swizzled chunk offsets (chunk = s*4+g, stored = chunk^(row&7))
  const int rsw0 = ((g    ) ^ (fr & 7)) << 3;
  const int rsw1 = ((g ^ 4) ^ (fr & 7)) << 3;

  // read bases (include fr*64 row offset); buf stride 28672 u16
  const u16* Ab0 = lds + (size_t)(wm + fr) * 64;
  const u16* Bb0 = lds + 16384 + (size_t)(wn + fr) * 64;
  const u16* Ab1 = Ab0 + 28672;
  const u16* Bb1 = Bb0 + 28672;

  f32x4 acc[8][3];
  const f32x4 zero = {0.f, 0.f, 0.f, 0.f};
#pragma unroll
  for (int i = 0; i < 8; i++)
#pragma unroll
    for (int j = 0; j < 3; j++) acc[i][j] = zero;

  bf16x8 a_[4][2];
  bf16x8 b_[3][2];

  auto stageA = [&](int kt, int buf, int half) {   // 2 loads (128 rows)
    const u16* src = pA + (size_t)half * 131072 + (kt << 6);
    u16* dst = lds + buf * 28672 + half * 8192 + tid * 8;
    llds16(src, dst);
    llds16(src + 65536, dst + 4096);
  };
  auto stageB0 = [&](int kt, int buf) {            // 2 loads (rows 0-127)
    const u16* src = pB + (kt << 6);
    u16* dst = lds + buf * 28672 + 16384 + tid * 8;
    llds16(src, dst);
    llds16(src + 65536, dst + 4096);
  };
  auto stageB1 = [&](int kt, int buf) {            // 1 load (rows 128-191)
    const u16* src = pB + 131072 + (kt << 6);
    u16* dst = lds + buf * 28672 + 24576 + tid * 8;
    llds16(src, dst);
  };
  auto loadA4 = [&](const u16* Ab, int ib) {
#pragma unroll
    for (int ii = 0; ii < 4; ii++) {
      const u16* r = Ab + (ib + ii) * 1024;
      a_[ii][0] = *(const bf16x8*)(r + rsw0);
      a_[ii][1] = *(const bf16x8*)(r + rsw1);
    }
  };
  auto loadB = [&](const u16* Bb, int j0, int nj) {
#pragma unroll
    for (int jj = 0; jj < 3; jj++) {
      if (jj < nj) {
        const u16* r = Bb + (j0 + jj) * 1024;
        b_[j0 + jj][0] = *(const bf16x8*)(r + rsw0);
        b_[j0 + jj][1] = *(const bf16x8*)(r + rsw1);
      }
    }
  };
  auto mfmaQ = [&](int ib, int j0, int nj) {
    __builtin_amdgcn_s_setprio(1);
#pragma unroll
    for (int jj = 0; jj < 3; jj++) {
      if (jj < nj) {
#pragma unroll
        for (int ii = 0; ii < 4; ii++) {
          acc[ib+ii][j0+jj] = __builtin_amdgcn_mfma_f32_16x16x32_bf16(
              a_[ii][0], b_[j0+jj][0], acc[ib+ii][j0+jj], 0, 0, 0);
          acc[ib+ii][j0+jj] = __builtin_amdgcn_mfma_f32_16x16x32_bf16(
              a_[ii][1], b_[j0+jj][1], acc[ib+ii][j0+jj], 0, 0, 0);
        }
      }
    }
    __builtin_amdgcn_s_setprio(0);
  };

  // prologue: buf0 <- K-tile 0 (A0,A1,B0,B1 = 7 loads), buf1.A0 <- K-tile 1 (2)
  stageA(0, 0, 0);
  stageA(0, 0, 1);
  stageB0(0, 0);
  stageB1(0, 0);
  stageA(1, 1, 0);
  asm volatile("s_waitcnt vmcnt(2)" ::: "memory");  // tile0 landed; tile1.A0 in flight
  __builtin_amdgcn_s_barrier();

  const int NTI = 8;   // K / 128
  for (int t = 0; t < NTI; ++t) {
    const bool st = (t < NTI - 1);
    const int ka = 2 * t + 1;
    const int kb = 2 * t + 2;
    const int kc = 2 * t + 3;

    // ---- K-tile 2t from buf0 ----
    // p0
    loadA4(Ab0, 0); loadB(Bb0, 0, 2);
    stageA(ka, 1, 1);
    __builtin_amdgcn_s_barrier();
    mfmaQ(0, 0, 2);
    __builtin_amdgcn_s_barrier();
    // p1
    loadB(Bb0, 2, 1);
    stageB0(ka, 1);
    __builtin_amdgcn_s_barrier();
    mfmaQ(0, 2, 1);
    __builtin_amdgcn_s_barrier();
    // p2
    loadA4(Ab0, 4);
    stageB1(ka, 1);
    __builtin_amdgcn_s_barrier();
    mfmaQ(4, 2, 1);
    __builtin_amdgcn_s_barrier();
    // p3 (no ds_reads -> MFMA starts with zero lgkm drain)
    if (st) stageA(kb, 0, 0);
    __builtin_amdgcn_s_barrier();
    mfmaQ(4, 0, 2);
    if (st) { asm volatile("s_waitcnt vmcnt(2)" ::: "memory"); }
    else    { asm volatile("s_waitcnt vmcnt(0)" ::: "memory"); }
    __builtin_amdgcn_s_barrier();

    // ---- K-tile 2t+1 from buf1 ----
    // p4
    loadA4(Ab1, 0); loadB(Bb1, 0, 2);
    if (st) stageA(kb, 0, 1);
    __builtin_amdgcn_s_barrier();
    mfmaQ(0, 0, 2);
    __builtin_amdgcn_s_barrier();
    // p5
    loadB(Bb1, 2, 1);
    if (st) stageB0(kb, 0);
    __builtin_amdgcn_s_barrier();
    mfmaQ(0, 2, 1);
    __builtin_amdgcn_s_barrier();
    // p6
    loadA4(Ab1, 4);
    if (st) stageB1(kb, 0);
    __builtin_amdgcn_s_barrier();
    mfmaQ(4, 2, 1);
    __builtin_amdgcn_s_barrier();
    // p7 (no ds_reads)
    if (st) stageA(kc, 1, 0);
    __builtin_amdgcn_s_barrier();
    mfmaQ(4, 0, 2);
    if (st) { asm volatile("s_waitcnt vmcnt(2)" ::: "memory"); }
    __builtin_amdgcn_s_barrier();
  }

  // ---- epilogue: bias+post -> LDS [256][200] -> coalesced 16B stores ----
  __syncthreads();
  const int bI  = m0 >> 11;
  const int s0m = m0 & 2047;
#pragma unroll
  for (int j = 0; j < 3; j++) {
    const int ncol = n0 + wn + j * 16 + fr;
    const int which = ncol >> 10;
    const float bb = ((which == 0) ? b0 : (which == 1) ? b1 : b2)[ncol & 1023];
    const float post = (which == 0) ? 0.18033688011f : 1.0f;  // 0.125*log2(e)
    const int cl = wn + j * 16 + fr;
#pragma unroll
    for (int i = 0; i < 8; i++) {
#pragma unroll
      for (int r = 0; r < 4; r++) {
        const int row = wm + i * 16 + g * 4 + r;
        lds[row * 200 + cl] = f2bf((acc[i][j][r] + bb) * post);
      }
    }
  }
  __syncthreads();
  const int part = tid & 7;
#pragma unroll
  for (int p = 0; p < 12; p++) {
    const int hc = p >> 2;
    const int ml = ((p & 3) << 6) + (tid >> 3);
    const int ncol0 = n0 + hc * 64;
    const int which = ncol0 >> 10;
    const int h = (ncol0 >> 6) & 15;
    const bf16x8 v = *(const bf16x8*)(lds + ml * 200 + hc * 64 + part * 8);
    *(bf16x8*)(qkv_out + (size_t)which * 8388608 +
               ((size_t)(bI * 16 + h) * 2048 + s0m + ml) * 64 + part * 8) = v;
  }
}

// ---------------- 256x128 6-phase output GEMM: out = attn * Wo^T + bo (fp32) ----------------
// M=8192, N=1024, K=1024.  Grid 256 = 32 mt x 8 nt = exactly 1 round, 1 block/CU.
// 8 waves (2M x 4N); per-wave C = 128x32 (acc[8][2]).  LDS 96 KiB.
__global__ __launch_bounds__(512) void gemm_o_256(
    const u16* __restrict__ A, const u16* __restrict__ Bw,
    const float* __restrict__ bo, float* __restrict__ out)
{
  __shared__ u16 lds[49152];   // 96 KiB

  const int tid = threadIdx.x;
  const int lane = tid & 63;
  const int wave = tid >> 6;

  const int bid = (int)blockIdx.x;
  const int xcd = bid & 7;
  const int idx = bid >> 3;                 // 0..31
  const int mt = (xcd << 2) | (idx & 3);    // 0..31
  const int nt = idx >> 2;                  // 0..7
  const int m0 = mt << 8;
  const int n0 = nt << 7;

  const int warp_m = wave >> 2;
  const int warp_n = wave & 3;
  const int wm = warp_m << 7;
  const int wn = warp_n << 5;               // 0,32,64,96
  const int fr = lane & 15;
  const int g  = lane >> 4;

  const int srow = tid >> 3;
  const int schk = ((tid & 7) ^ (srow & 7)) << 3;
  const u16* pA = A  + (size_t)(m0 + srow) * 1024 + schk;
  const u16* pB = Bw + (size_t)(n0 + srow) * 1024 + schk;

  const int rsw0 = ((g    ) ^ (fr & 7)) << 3;
  const int rsw1 = ((g ^ 4) ^ (fr & 7)) << 3;

  const u16* Ab0 = lds + (size_t)(wm + fr) * 64;
  const u16* Bb0 = lds + 16384 + (size_t)(wn + fr) * 64;
  const u16* Ab1 = Ab0 + 24576;
  const u16* Bb1 = Bb0 + 24576;

  f32x4 acc[8][2];
  const f32x4 zero = {0.f, 0.f, 0.f, 0.f};
#pragma unroll
  for (int i = 0; i < 8; i++)
#pragma unroll
    for (int j = 0; j < 2; j++) acc[i][j] = zero;

  bf16x8 a_[8][2];
  bf16x8 b_[2][2];

  auto stageA = [&](int kt, int buf, int half) {   // 2 loads (128 rows)
    const u16* src = pA + (size_t)half * 131072 + (kt << 6);
    u16* dst = lds + buf * 24576 + half * 8192 + tid * 8;
    llds16(src, dst);
    llds16(src + 65536, dst + 4096);
  };
  auto stageB = [&](int kt, int buf) {             // 2 loads (128 rows)
    const u16* src = pB + (kt << 6);
    u16* dst = lds + buf * 24576 + 16384 + tid * 8;
    llds16(src, dst);
    llds16(src + 65536, dst + 4096);
  };
  auto loadA4 = [&](const u16* Ab, int ib) {
#pragma unroll
    for (int ii = 0; ii < 4; ii++) {
      const u16* r = Ab + (ib + ii) * 1024;
      a_[ib + ii][0] = *(const bf16x8*)(r + rsw0);
      a_[ib + ii][1] = *(const bf16x8*)(r + rsw1);
    }
  };
  auto loadB2 = [&](const u16* Bb) {
#pragma unroll
    for (int jj = 0; jj < 2; jj++) {
      const u16* r = Bb + jj * 1024;
      b_[jj][0] = *(const bf16x8*)(r + rsw0);
      b_[jj][1] = *(const bf16x8*)(r + rsw1);
    }
  };
  auto mfma16 = [&](int ib) {
    __builtin_amdgcn_s_setprio(1);
#pragma unroll
    for (int jj = 0; jj < 2; jj++)
#pragma unroll
      for (int ii = 0; ii < 4; ii++) {
        acc[ib+ii][jj] = __builtin_amdgcn_mfma_f32_16x16x32_bf16(
            a_[ib+ii][0], b_[jj][0], acc[ib+ii][jj], 0, 0, 0);
        acc[ib+ii][jj] = __builtin_amdgcn_mfma_f32_16x16x32_bf16(
            a_[ib+ii][1], b_[jj][1], acc[ib+ii][jj], 0, 0, 0);
      }
    __builtin_amdgcn_s_setprio(0);
  };
  auto mfma8 = [&](int ib, int jj) {
    __builtin_amdgcn_s_setprio(1);
#pragma unroll
    for (int ii = 0; ii < 4; ii++) {
      acc[ib+ii][jj] = __builtin_amdgcn_mfma_f32_16x16x32_bf16(
          a_[ib+ii][0], b_[jj][0], acc[ib+ii][jj], 0, 0, 0);
      acc[ib+ii][jj] = __builtin_amdgcn_mfma_f32_16x16x32_bf16(
          a_[ib+ii][1], b_[jj][1], acc[ib+ii][jj], 0, 0, 0);
    }
    __builtin_amdgcn_s_setprio(0);
  };

  // prologue: buf0 <- K-tile 0 (A0,A1,B = 6 loads), buf1.A0 <- K-tile 1 (2)
  stageA(0, 0, 0);
  stageA(0, 0, 1);
  stageB(0, 0);
  stageA(1, 1, 0);
  asm volatile("s_waitcnt vmcnt(2)" ::: "memory");
  __builtin_amdgcn_s_barrier();

  const int NTI = 8;   // K / 128
  for (int t = 0; t < NTI; ++t) {
    const bool st = (t < NTI - 1);
    const int ka = 2 * t + 1;
    const int kb = 2 * t + 2;
    const int kc = 2 * t + 3;

    // ---- K-tile 2t from buf0 ----
    loadA4(Ab0, 0); loadB2(Bb0);
    stageA(ka, 1, 1);
    __builtin_amdgcn_s_barrier();
    mfma16(0);
    __builtin_amdgcn_s_barrier();
    loadA4(Ab0, 4);
    stageB(ka, 1);
    __builtin_amdgcn_s_barrier();
    mfma8(4, 0);
    __builtin_amdgcn_s_barrier();
    if (st) stageA(kb, 0, 0);
    __builtin_amdgcn_s_barrier();
    mfma8(4, 1);
    if (st) { asm volatile("s_waitcnt vmcnt(2)" ::: "memory"); }
    else    { asm volatile("s_waitcnt vmcnt(0)" ::: "memory"); }
    __builtin_amdgcn_s_barrier();

    // ---- K-tile 2t+1 from buf1 ----
    loadA4(Ab1, 0); loadB2(Bb1);
    if (st) stageA(kb, 0, 1);
    __builtin_amdgcn_s_barrier();
    mfma16(0);
    __builtin_amdgcn_s_barrier();
    loadA4(Ab1, 4);
    if (st) stageB(kb, 0);
    __builtin_amdgcn_s_barrier();
    mfma8(4, 0);
    __builtin_amdgcn_s_barrier();
    if (st) stageA(kc, 1, 0);
    __builtin_amdgcn_s_barrier();
    mfma8(4, 1);
    if (st) { asm volatile("s_waitcnt vmcnt(2)" ::: "memory"); }
    __builtin_amdgcn_s_barrier();
  }

  // epilogue: fp32 direct stores with bias
#pragma unroll
  for (int j = 0; j < 2; j++) {
    const int n = n0 + wn + j * 16 + fr;
    const float bb = bo[n];
#pragma unroll
    for (int i = 0; i < 8; i++) {
#pragma unroll
      for (int r = 0; r < 4; r++) {
        const int m = m0 + wm + i * 16 + g * 4 + r;
        out[(size_t)m * 1024 + n] = acc[i][j][r] + bb;
      }
    }
  }
}

// ---------------- V transpose: [BH][S][64] -> [BH][64][S] ----------------
__global__ __launch_bounds__(256) void transpose_v(const u16* __restrict__ V, u16* __restrict__ VT) {
  __shared__ u16 t_s[64 * 72];
  const int tid = threadIdx.x;
  const int st = blockIdx.x << 6;
  const int bh = blockIdx.y;
  const u16* src = V + ((size_t)bh * 2048 + st) * 64;
#pragma unroll
  for (int p = 0; p < 2; p++) {
    int i = p * 256 + tid;
    int row = i >> 3, ch = i & 7;
    bf16x8 v = *(const bf16x8*)(src + row * 64 + ch * 8);
    *(bf16x8*)(t_s + row * 72 + ch * 8) = v;
  }
  __syncthreads();
  u16* dst = VT + (size_t)bh * 131072 + st;
#pragma unroll
  for (int p = 0; p < 2; p++) {
    int i = p * 256 + tid;
    int dh = i >> 3, ch = i & 7;
    union { u16 s[8]; bf16x8 v; } u;
#pragma unroll
    for (int e = 0; e < 8; e++) u.s[e] = t_s[(ch * 8 + e) * 72 + dh];
    *(bf16x8*)(dst + (size_t)dh * 2048 + ch * 8) = u.v;
  }
}

// ---------------- MFMA flash attention: single q-tile, PV deferred, 3 blocks/CU ----------------
__global__ __launch_bounds__(256, 3) void attn_fa(
    const u16* __restrict__ Qb, const u16* __restrict__ Kb,
    const u16* __restrict__ VT, u16* __restrict__ Ob)
{
  __shared__ u16 k_s[2 * 4096];      // dbuf [kn][d], 16B-chunks XOR'd by row
  __shared__ u16 v_s[2 * 4096];      // dbuf [dn][k], same swizzle (lags K by 1 tile)
  __shared__ u16 p_s[128 * 72];      // [q][key] bf16, stride 72 (wave-private rows)
  __shared__ float l_s[128];

  const int tid = threadIdx.x;
  const int lane = tid & 63;
  const int wave = tid >> 6;
  const int bid = (int)blockIdx.x;
  const int qt = 15 - (bid >> 6);               // big tiles first
  const int bh = (((bid >> 3) & 7) << 3) | (bid & 7);   // bh % 8 == bid % 8 (XCD)
  const size_t head = (size_t)bh << 17;
  const int fr = lane & 15;
  const int g = lane >> 4;
  const int k8 = g << 3;
  const int q0 = qt << 7;
  const int wrow = wave << 5;

  // Q fragments (pre-scaled); loop-invariant B-operands
  bf16x8 aq[2][2];
#pragma unroll
  for (int f = 0; f < 2; f++) {
    const u16* qp = Qb + head + (size_t)(q0 + wrow + (f << 4) + fr) * 64;
    aq[f][0] = *(const bf16x8*)(qp + k8);
    aq[f][1] = *(const bf16x8*)(qp + 32 + k8);
  }

  // ---- hoisted lane-constant offsets ----
  const int r0 = tid >> 3, c0 = tid & 7;
  const int r1 = 32 + r0;
  const int koff0 = r0 * 64 + (((c0 ^ r0) & 7) << 3);     // K staging src offsets
  const int koff1 = r1 * 64 + (((c0 ^ r1) & 7) << 3);
  const int voff0 = r0 * 2048 + (((c0 ^ r0) & 7) << 3);   // V^T staging src offsets
  const int voff1 = r1 * 2048 + (((c0 ^ r1) & 7) << 3);
  int kaddr[4][2], vaddr[2][4];                           // fragment-read offsets
#pragma unroll
  for (int j = 0; j < 4; j++) {
    const int kn = (j << 4) + fr;
    kaddr[j][0] = kn * 64 + (((g ^ kn) & 7) << 3);
    kaddr[j][1] = kn * 64 + ((((g + 4) ^ kn) & 7) << 3);
#pragma unroll
    for (int s2 = 0; s2 < 2; s2++)
      vaddr[s2][j] = kn * 64 + ((((s2 << 2) + g) ^ (kn & 7)) << 3);
  }
  u16* const prow0 = p_s + (wrow + fr) * 72;        // q row f=0 (write cols & read k8)
  u16* const prow1 = p_s + (wrow + 16 + fr) * 72;   // q row f=1
  const u16* Kbase = Kb + head;
  const u16* Vbase = VT + head;

  auto issueK = [&](int jt2, int buf) {
    const u16* Kt = Kbase + ((size_t)jt2 << 12);
    llds16(Kt + koff0, k_s + (buf << 12) + tid * 8);
    llds16(Kt + koff1, k_s + (buf << 12) + 2048 + tid * 8);
  };
  auto issueV = [&](int jt2, int buf) {
    const u16* Vt = Vbase + (jt2 << 6);
    llds16(Vt + voff0, v_s + (buf << 12) + tid * 8);
    llds16(Vt + voff1, v_s + (buf << 12) + 2048 + tid * 8);
  };

  f32x4 o_acc[2][4];
  const f32x4 zero = {0.f, 0.f, 0.f, 0.f};
#pragma unroll
  for (int f = 0; f < 2; f++)
#pragma unroll
    for (int j = 0; j < 4; j++) o_acc[f][j] = zero;
  float l_run[2] = {0.f, 0.f};

  const int jmax = 2 * qt + 1;                 // jmax+1 iterations (even count)
  const int jt_diag = 2 * qt + (wave >> 1);    // per-wave diagonal tile

  auto do_pv = [&](const u16* vs) {
#pragma unroll
    for (int s2 = 0; s2 < 2; s2++) {
      const bf16x8 ap0 = *(const bf16x8*)(prow0 + (s2 << 5) + k8);
      const bf16x8 ap1 = *(const bf16x8*)(prow1 + (s2 << 5) + k8);
#pragma unroll
      for (int j = 0; j < 4; j++) {
        const bf16x8 bv = *(const bf16x8*)(vs + vaddr[s2][j]);
        o_acc[0][j] = __builtin_amdgcn_mfma_f32_16x16x32_bf16(ap0, bv, o_acc[0][j], 0, 0, 0);
        o_acc[1][j] = __builtin_amdgcn_mfma_f32_16x16x32_bf16(ap1, bv, o_acc[1][j], 0, 0, 0);
      }
    }
  };

  auto do_s = [&](const u16* ks, bool dodiag, int jt) {
    f32x4 s_acc[2][4];
#pragma unroll
    for (int f = 0; f < 2; f++)
#pragma unroll
      for (int j = 0; j < 4; j++) s_acc[f][j] = zero;
#pragma unroll
    for (int j = 0; j < 4; j++) {
      const bf16x8 ka0 = *(const bf16x8*)(ks + kaddr[j][0]);
      const bf16x8 ka1 = *(const bf16x8*)(ks + kaddr[j][1]);
      s_acc[0][j] = __builtin_amdgcn_mfma_f32_16x16x32_bf16(ka0, aq[0][0], s_acc[0][j], 0, 0, 0);
      s_acc[0][j] = __builtin_amdgcn_mfma_f32_16x16x32_bf16(ka1, aq[0][1], s_acc[0][j], 0, 0, 0);
      s_acc[1][j] = __builtin_amdgcn_mfma_f32_16x16x32_bf16(ka0, aq[1][0], s_acc[1][j], 0, 0, 0);
      s_acc[1][j] = __builtin_amdgcn_mfma_f32_16x16x32_bf16(ka1, aq[1][1], s_acc[1][j], 0, 0, 0);
    }
#pragma unroll
    for (int f = 0; f < 2; f++) {
      const int qa = q0 + wrow + (f << 4) + fr;
      u16* prow = (f == 0) ? prow0 : prow1;
      if (dodiag) {
#pragma unroll
        for (int j = 0; j < 4; j++) {
          const int kb = (jt << 6) + (j << 4) + (g << 2);
          float p0 = (kb + 0 > qa) ? 0.f : __builtin_amdgcn_exp2f(s_acc[f][j][0]);
          float p1 = (kb + 1 > qa) ? 0.f : __builtin_amdgcn_exp2f(s_acc[f][j][1]);
          float p2 = (kb + 2 > qa) ? 0.f : __builtin_amdgcn_exp2f(s_acc[f][j][2]);
          float p3 = (kb + 3 > qa) ? 0.f : __builtin_amdgcn_exp2f(s_acc[f][j][3]);
          l_run[f] += (p0 + p1) + (p2 + p3);
          union { __hip_bfloat162 h; unsigned u; } ca, cb;
          ca.h = __float22bfloat162_rn(make_float2(p0, p1));
          cb.h = __float22bfloat162_rn(make_float2(p2, p3));
          *(uint2*)(prow + (j << 4) + (g << 2)) = make_uint2(ca.u, cb.u);
        }
      } else {
#pragma unroll
        for (int j = 0; j < 4; j++) {
          float p0 = __builtin_amdgcn_exp2f(s_acc[f][j][0]);
          float p1 = __builtin_amdgcn_exp2f(s_acc[f][j][1]);
          float p2 = __builtin_amdgcn_exp2f(s_acc[f][j][2]);
          float p3 = __builtin_amdgcn_exp2f(s_acc[f][j][3]);
          l_run[f] += (p0 + p1) + (p2 + p3);
          union { __hip_bfloat162 h; unsigned u; } ca, cb;
          ca.h = __float22bfloat162_rn(make_float2(p0, p1));
          cb.h = __float22bfloat162_rn(make_float2(p2, p3));
          *(uint2*)(prow + (j << 4) + (g << 2)) = make_uint2(ca.u, cb.u);
        }
      }
    }
  };

  issueK(0, 0);   // prime K pipeline (V(0) issued inside iteration 0)

  for (int jt = 0; jt <= jmax; jt++) {
    const int kb = jt & 1;
    __syncthreads();                       // K(jt) + V(jt-1) landed; LDS reads drained
    if (jt < jmax) issueK(jt + 1, kb ^ 1);
    issueV(jt, kb);
    if (jt > 0 && jt - 1 <= jt_diag) do_pv(v_s + ((kb ^ 1) << 12));   // deferred PV
    if (jt <= jt_diag) do_s(k_s + (kb << 12), jt == jt_diag, jt);
  }
  __syncthreads();                         // V(jmax) landed
  if (jt_diag == jmax) do_pv(v_s + ((jmax & 1) << 12));   // waves 2,3 final PV

  // epilogue: reduce l (q-col lives in lanes fr, fr+16, fr+32, fr+48)
#pragma unroll
  for (int f = 0; f < 2; f++) {
    float l = l_run[f];
    l += __shfl_xor(l, 16);
    l += __shfl_xor(l, 32);
    if (g == 0) l_s[wrow + (f << 4) + fr] = l;   // wave-private slot
  }
  const int b = bh >> 4, h = bh & 15;
#pragma unroll
  for (int f = 0; f < 2; f++) {
#pragma unroll
    for (int r = 0; r < 4; r++) {
      const int qloc = wrow + (f << 4) + (g << 2) + r;
      const float inv = 1.f / l_s[qloc];
      const int q_abs = q0 + qloc;
#pragma unroll
      for (int j = 0; j < 4; j++)
        Ob[((size_t)b * 2048 + q_abs) * 1024 + (h << 6) + (j << 4) + fr] =
            f2bf(o_acc[f][j][r] * inv);
    }
  }
}

// ---------------- launch ----------------
extern "C" void kernel_launch(void* const* d_in, const int* in_sizes, int n_in,
                              void* d_out, int out_size, void* d_ws, size_t ws_size,
                              hipStream_t stream) {
  const float* x  = (const float*)d_in[0];
  const float* Wq = (const float*)d_in[1];
  const float* bq = (const float*)d_in[2];
  const float* Wk = (const float*)d_in[3];
  const float* bk = (const float*)d_in[4];
  const float* Wv = (const float*)d_in[5];
  const float* bv = (const float*)d_in[6];
  const float* Wo = (const float*)d_in[7];
  const float* bo = (const float*)d_in[8];
  float* out = (float*)d_out;

  char* ws = (char*)d_ws;
  u16* xb    = (u16*)(ws);                 // 16 MB; dead after QKV GEMM
  u16* vT    = (u16*)(ws);                 // aliases xb: V^T [BH][64][S]
  u16* wqkv  = (u16*)(ws + 16777216);      // 6 MB packed q|k|v weights
  u16* wo    = (u16*)(ws + 23068672);      // 2 MB
  u16* qkv   = (u16*)(ws + 25165824);      // 48 MB, [3][BH][S][DH]
  u16* attnb = qkv + 16777216;             // aliases V-original (dead after transpose)
  // total ws: 75,497,472 B

  // fused cast: x + all 4 weight matrices, one launch
  cast_all_kernel<<<12288, 256, 0, stream>>>(x, Wq, Wk, Wv, Wo, xb, wqkv, wo);

  // fused QKV projection: M=8192, N=3072, K=1024 (256x192 8-phase, 2 clean rounds)
  gemm_qkv_256<<<dim3(512), 512, 0, stream>>>(xb, wqkv, bq, bk, bv, qkv);

  // V [BH][S][64] -> V^T [BH][64][S]  (xb dead; vT aliases it)
  transpose_v<<<dim3(32, 64), 256, 0, stream>>>(qkv + 16777216, vT);

  // MFMA flash attention (single q-tile/block, big-first dispatch, 3 blocks/CU)
  // writes attnb over the now-dead V-original region
  attn_fa<<<dim3(1024), 256, 0, stream>>>(qkv, qkv + 8388608, vT, attnb);

  // output projection: M=8192, N=1024, K=1024 (256x128 6-phase, 1 clean round)
  gemm_o_256<<<dim3(256), 512, 0, stream>>>(attnb, wo, bo, out);
}

// Round 8
// 238.507 us; speedup vs baseline: 1.3642x; 1.0007x over previous
//
#include <hip/hip_runtime.h>
#include <hip/hip_bf16.h>
#include <cstdint>
#include <cstddef>

// B=4, S=2048, D=1024, H=16, DH=64.  M = B*S = 8192.
// fused cast (x + 4 weights, one launch); fused QKV GEMM via 256x192-tile
// 8-phase pipelined MFMA kernel (T2 swizzle + counted-vmcnt + setprio, raw
// s_barrier; p3/p7 are ds_read-free MFMA phases) WITH FUSED V-TRANSPOSE
// EPILOGUE: Q/K stored [BH][S][DH], V stored directly as V^T [BH][DH][S]
// via column-major LDS restage + coalesced 16B stores (transpose_v kernel
// eliminated, -32MB HBM traffic, -1 launch); MFMA flash attention (single
// q-tile, big-first dispatch, 3 blocks/CU); output GEMM via 256x128-tile
// 6-phase kernel (1 clean round).
// Workspace 75,497,472 B: xb/attnb 16M | wqkv 6M | wo 2M | Q,K 32M | vT 16M.

typedef unsigned short u16;
typedef __bf16 bf16x8 __attribute__((ext_vector_type(8)));
typedef float  f32x4  __attribute__((ext_vector_type(4)));

__device__ __forceinline__ u16 f2bf(float f) {
  unsigned u = __float_as_uint(f);
  unsigned r = u + 0x7fffu + ((u >> 16) & 1u);   // RNE
  return (u16)(r >> 16);
}

// async global->LDS, 16B per lane (dest = wave-uniform base + lane*16)
__device__ __forceinline__ void llds16(const u16* g, u16* l) {
  __builtin_amdgcn_global_load_lds(
      (const __attribute__((address_space(1))) void*)g,
      (__attribute__((address_space(3))) void*)l, 16, 0, 0);
}

// ---------------- fused cast fp32 -> bf16 (x + Wq,Wk,Wv,Wo) ----------------
__global__ void cast_all_kernel(const float* __restrict__ x,
                                const float* __restrict__ Wq, const float* __restrict__ Wk,
                                const float* __restrict__ Wv, const float* __restrict__ Wo,
                                u16* __restrict__ xb, u16* __restrict__ wqkv,
                                u16* __restrict__ wo) {
  const int bid = (int)blockIdx.x;
  const int tid = threadIdx.x;
  if (bid < 8192) {
    const int i = (bid << 8) + tid;
    float4 f = ((const float4*)x)[i];
    ushort4 u;
    u.x = f2bf(f.x); u.y = f2bf(f.y); u.z = f2bf(f.z); u.w = f2bf(f.w);
    ((ushort4*)xb)[i] = u;
  } else {
    const int j = ((bid - 8192) << 8) + tid;   // 0..1048575
    const int w = j >> 18;                     // 0..3
    const int idx = j & 262143;
    const float* src = (w == 0) ? Wq : (w == 1) ? Wk : (w == 2) ? Wv : Wo;
    u16* dst = (w == 3) ? wo : (wqkv + (w << 20));
    float4 f = ((const float4*)src)[idx];
    ushort4 u;
    u.x = f2bf(f.x); u.y = f2bf(f.y); u.z = f2bf(f.z); u.w = f2bf(f.w);
    ((ushort4*)dst)[idx] = u;
  }
}

// ---------------- 256x192 8-phase QKV GEMM + fused V-transpose ----------------
// M=8192, N=3072, K=1024.  512 threads = 8 waves (2M x 4N); per-wave C = 128x48.
// Grid 512 = 32 mt x 16 nt = exactly 2 full rounds (1 block/CU, zero tail).
// LDS 112 KiB: buf{0,1} x [A(256x64) | B(192x64)] u16, 16B chunks XOR-swizzled.
// Hot loop identical to the proven 8-phase schedule (p3/p7 ds_read-free).
// Epilogue: cols <2048 (Q/K) -> row-major LDS [256][200] -> [BH][S][DH] stores;
// cols >=2048 (V) -> col-major LDS [clv][264] -> coalesced V^T [BH][DH][S]
// stores (lane = s-group: 512B contiguous per wave).  64-col chunks never
// straddle the Q/K/V boundary (1024 % 64 == 0).
__global__ __launch_bounds__(512) void gemm_qkv_256(
    const u16* __restrict__ A, const u16* __restrict__ Bw,
    const float* __restrict__ b0, const float* __restrict__ b1, const float* __restrict__ b2,
    u16* __restrict__ qkv_out, u16* __restrict__ vT_out)
{
  __shared__ u16 lds[57344];   // 112 KiB (reused as epilogue staging)

  const int tid = threadIdx.x;
  const int lane = tid & 63;
  const int wave = tid >> 6;

  // XCD-grouped decode: xcd = bid&7; each XCD owns 4 m-panels x all 16 n-tiles.
  const int bid = (int)blockIdx.x;
  const int xcd = bid & 7;
  const int idx = bid >> 3;                 // 0..63
  const int mt = (xcd << 2) | (idx & 3);    // 0..31
  const int nt = idx >> 2;                  // 0..15
  const int m0 = mt << 8;
  const int n0 = nt * 192;

  const int warp_m = wave >> 2;       // 0..1
  const int warp_n = wave & 3;        // 0..3
  const int wm = warp_m << 7;         // 0,128
  const int wn = warp_n * 48;         // 0,48,96,144
  const int fr = lane & 15;
  const int g  = lane >> 4;           // 0..3

  // staging source (pre-swizzled global addr so linear LDS dest lands swizzled)
  const int srow = tid >> 3;                       // 0..63
  const int schk = ((tid & 7) ^ (srow & 7)) << 3;  // stored chunk -> logical col
  const u16* pA = A  + (size_t)(m0 + srow) * 1024 + schk;
  const u16* pB = Bw + (size_t)(n0 + srow) * 1024 + schk;

  // fragment-read swizzled chunk offsets (chunk = s*4+g, stored = chunk^(row&7))
  const int rsw0 = ((g    ) ^ (fr & 7)) << 3;
  const int rsw1 = ((g ^ 4) ^ (fr & 7)) << 3;

  // read bases (include fr*64 row offset); buf stride 28672 u16
  const u16* Ab0 = lds + (size_t)(wm + fr) * 64;
  const u16* Bb0 = lds + 16384 + (size_t)(wn + fr) * 64;
  const u16* Ab1 = Ab0 + 28672;
  const u16* Bb1 = Bb0 + 28672;

  f32x4 acc[8][3];
  const f32x4 zero = {0.f, 0.f, 0.f, 0.f};
#pragma unroll
  for (int i = 0; i < 8; i++)
#pragma unroll
    for (int j = 0; j < 3; j++) acc[i][j] = zero;

  bf16x8 a_[4][2];
  bf16x8 b_[3][2];

  auto stageA = [&](int kt, int buf, int half) {   // 2 loads (128 rows)
    const u16* src = pA + (size_t)half * 131072 + (kt << 6);
    u16* dst = lds + buf * 28672 + half * 8192 + tid * 8;
    llds16(src, dst);
    llds16(src + 65536, dst + 4096);
  };
  auto stageB0 = [&](int kt, int buf) {            // 2 loads (rows 0-127)
    const u16* src = pB + (kt << 6);
    u16* dst = lds + buf * 28672 + 16384 + tid * 8;
    llds16(src, dst);
    llds16(src + 65536, dst + 4096);
  };
  auto stageB1 = [&](int kt, int buf) {            // 1 load (rows 128-191)
    const u16* src = pB + 131072 + (kt << 6);
    u16* dst = lds + buf * 28672 + 24576 + tid * 8;
    llds16(src, dst);
  };
  auto loadA4 = [&](const u16* Ab, int ib) {
#pragma unroll
    for (int ii = 0; ii < 4; ii++) {
      const u16* r = Ab + (ib + ii) * 1024;
      a_[ii][0] = *(const bf16x8*)(r + rsw0);
      a_[ii][1] = *(const bf16x8*)(r + rsw1);
    }
  };
  auto loadB = [&](const u16* Bb, int j0, int nj) {
#pragma unroll
    for (int jj = 0; jj < 3; jj++) {
      if (jj < nj) {
        const u16* r = Bb + (j0 + jj) * 1024;
        b_[j0 + jj][0] = *(const bf16x8*)(r + rsw0);
        b_[j0 + jj][1] = *(const bf16x8*)(r + rsw1);
      }
    }
  };
  auto mfmaQ = [&](int ib, int j0, int nj) {
    __builtin_amdgcn_s_setprio(1);
#pragma unroll
    for (int jj = 0; jj < 3; jj++) {
      if (jj < nj) {
#pragma unroll
        for (int ii = 0; ii < 4; ii++) {
          acc[ib+ii][j0+jj] = __builtin_amdgcn_mfma_f32_16x16x32_bf16(
              a_[ii][0], b_[j0+jj][0], acc[ib+ii][j0+jj], 0, 0, 0);
          acc[ib+ii][j0+jj] = __builtin_amdgcn_mfma_f32_16x16x32_bf16(
              a_[ii][1], b_[j0+jj][1], acc[ib+ii][j0+jj], 0, 0, 0);
        }
      }
    }
    __builtin_amdgcn_s_setprio(0);
  };

  // prologue: buf0 <- K-tile 0 (A0,A1,B0,B1 = 7 loads), buf1.A0 <- K-tile 1 (2)
  stageA(0, 0, 0);
  stageA(0, 0, 1);
  stageB0(0, 0);
  stageB1(0, 0);
  stageA(1, 1, 0);
  asm volatile("s_waitcnt vmcnt(2)" ::: "memory");  // tile0 landed; tile1.A0 in flight
  __builtin_amdgcn_s_barrier();

  const int NTI = 8;   // K / 128
  for (int t = 0; t < NTI; ++t) {
    const bool st = (t < NTI - 1);
    const int ka = 2 * t + 1;
    const int kb = 2 * t + 2;
    const int kc = 2 * t + 3;

    // ---- K-tile 2t from buf0 ----
    // p0
    loadA4(Ab0, 0); loadB(Bb0, 0, 2);
    stageA(ka, 1, 1);
    __builtin_amdgcn_s_barrier();
    mfmaQ(0, 0, 2);
    __builtin_amdgcn_s_barrier();
    // p1
    loadB(Bb0, 2, 1);
    stageB0(ka, 1);
    __builtin_amdgcn_s_barrier();
    mfmaQ(0, 2, 1);
    __builtin_amdgcn_s_barrier();
    // p2
    loadA4(Ab0, 4);
    stageB1(ka, 1);
    __builtin_amdgcn_s_barrier();
    mfmaQ(4, 2, 1);
    __builtin_amdgcn_s_barrier();
    // p3 (no ds_reads -> MFMA starts with zero lgkm drain)
    if (st) stageA(kb, 0, 0);
    __builtin_amdgcn_s_barrier();
    mfmaQ(4, 0, 2);
    if (st) { asm volatile("s_waitcnt vmcnt(2)" ::: "memory"); }
    else    { asm volatile("s_waitcnt vmcnt(0)" ::: "memory"); }
    __builtin_amdgcn_s_barrier();

    // ---- K-tile 2t+1 from buf1 ----
    // p4
    loadA4(Ab1, 0); loadB(Bb1, 0, 2);
    if (st) stageA(kb, 0, 1);
    __builtin_amdgcn_s_barrier();
    mfmaQ(0, 0, 2);
    __builtin_amdgcn_s_barrier();
    // p5
    loadB(Bb1, 2, 1);
    if (st) stageB0(kb, 0);
    __builtin_amdgcn_s_barrier();
    mfmaQ(0, 2, 1);
    __builtin_amdgcn_s_barrier();
    // p6
    loadA4(Ab1, 4);
    if (st) stageB1(kb, 0);
    __builtin_amdgcn_s_barrier();
    mfmaQ(4, 2, 1);
    __builtin_amdgcn_s_barrier();
    // p7 (no ds_reads)
    if (st) stageA(kc, 1, 0);
    __builtin_amdgcn_s_barrier();
    mfmaQ(4, 0, 2);
    if (st) { asm volatile("s_waitcnt vmcnt(2)" ::: "memory"); }
    __builtin_amdgcn_s_barrier();
  }

  // ---- epilogue ----
  __syncthreads();
  const int bI  = m0 >> 11;
  const int s0m = m0 & 2047;
  // vs0 = first V-range local column (192 = none, 0 = all V; multiple of 64)
  const int vs0 = (n0 >= 2048) ? 0 : ((n0 + 192 <= 2048) ? 192 : (2048 - n0));

  // pass 1: Q/K columns -> row-major LDS [256][200] -> [BH][S][DH] stores
  if (vs0 > 0) {
#pragma unroll
    for (int j = 0; j < 3; j++) {
      const int cl = wn + j * 16 + fr;
      if (cl < vs0) {
        const int ncol = n0 + cl;
        const int which = ncol >> 10;             // 0 or 1 here
        const float bb = ((which == 0) ? b0 : b1)[ncol & 1023];
        const float post = (which == 0) ? 0.18033688011f : 1.0f;  // 0.125*log2(e)
#pragma unroll
        for (int i = 0; i < 8; i++) {
#pragma unroll
          for (int r = 0; r < 4; r++) {
            const int row = wm + i * 16 + g * 4 + r;
            lds[row * 200 + cl] = f2bf((acc[i][j][r] + bb) * post);
          }
        }
      }
    }
    __syncthreads();
    const int part = tid & 7;
#pragma unroll
    for (int p = 0; p < 12; p++) {
      const int hc = p >> 2;
      if (hc * 64 < vs0) {                        // chunk fully Q/K
        const int ml = ((p & 3) << 6) + (tid >> 3);
        const int ncol0 = n0 + hc * 64;
        const int which = ncol0 >> 10;
        const int h = (ncol0 >> 6) & 15;
        const bf16x8 v = *(const bf16x8*)(lds + ml * 200 + hc * 64 + part * 8);
        *(bf16x8*)(qkv_out + (size_t)which * 8388608 +
                   ((size_t)(bI * 16 + h) * 2048 + s0m + ml) * 64 + part * 8) = v;
      }
    }
  }

  // pass 2: V columns -> col-major LDS [clv][264] -> coalesced V^T [BH][DH][S]
  if (vs0 < 192) {
    __syncthreads();                              // pass-1 LDS reads drained
#pragma unroll
    for (int j = 0; j < 3; j++) {
      const int cl = wn + j * 16 + fr;
      const int clv = cl - vs0;
      if (clv >= 0) {
        const int ncol = n0 + cl;
        const float bb = b2[ncol & 1023];
#pragma unroll
        for (int i = 0; i < 8; i++) {
#pragma unroll
          for (int r = 0; r < 4; r++) {
            const int row = wm + i * 16 + g * 4 + r;
            lds[clv * 264 + row] = f2bf(acc[i][j][r] + bb);
          }
        }
      }
    }
    __syncthreads();
    const int vcols = 192 - vs0;
    const int mg = tid & 31;                      // s-group: lanes contiguous in s
    const int cidx = tid >> 5;                    // 0..15
    for (int cc = cidx; cc < vcols; cc += 16) {
      const int ncol = n0 + vs0 + cc;
      const int h = (ncol >> 6) & 15;
      const int dh = ncol & 63;
      const bf16x8 v = *(const bf16x8*)(lds + cc * 264 + mg * 8);
      *(bf16x8*)(vT_out + ((size_t)(bI * 16 + h) * 64 + dh) * 2048 + s0m + mg * 8) = v;
    }
  }
}

// ---------------- 256x128 6-phase output GEMM: out = attn * Wo^T + bo (fp32) ----------------
__global__ __launch_bounds__(512) void gemm_o_256(
    const u16* __restrict__ A, const u16* __restrict__ Bw,
    const float* __restrict__ bo, float* __restrict__ out)
{
  __shared__ u16 lds[49152];   // 96 KiB

  const int tid = threadIdx.x;
  const int lane = tid & 63;
  const int wave = tid >> 6;

  const int bid = (int)blockIdx.x;
  const int xcd = bid & 7;
  const int idx = bid >> 3;                 // 0..31
  const int mt = (xcd << 2) | (idx & 3);    // 0..31
  const int nt = idx >> 2;                  // 0..7
  const int m0 = mt << 8;
  const int n0 = nt << 7;

  const int warp_m = wave >> 2;
  const int warp_n = wave & 3;
  const int wm = warp_m << 7;
  const int wn = warp_n << 5;               // 0,32,64,96
  const int fr = lane & 15;
  const int g  = lane >> 4;

  const int srow = tid >> 3;
  const int schk = ((tid & 7) ^ (srow & 7)) << 3;
  const u16* pA = A  + (size_t)(m0 + srow) * 1024 + schk;
  const u16* pB = Bw + (size_t)(n0 + srow) * 1024 + schk;

  const int rsw0 = ((g    ) ^ (fr & 7)) << 3;
  const int rsw1 = ((g ^ 4) ^ (fr & 7)) << 3;

  const u16* Ab0 = lds + (size_t)(wm + fr) * 64;
  const u16* Bb0 = lds + 16384 + (size_t)(wn + fr) * 64;
  const u16* Ab1 = Ab0 + 24576;
  const u16* Bb1 = Bb0 + 24576;

  f32x4 acc[8][2];
  const f32x4 zero = {0.f, 0.f, 0.f, 0.f};
#pragma unroll
  for (int i = 0; i < 8; i++)
#pragma unroll
    for (int j = 0; j < 2; j++) acc[i][j] = zero;

  bf16x8 a_[8][2];
  bf16x8 b_[2][2];

  auto stageA = [&](int kt, int buf, int half) {   // 2 loads (128 rows)
    const u16* src = pA + (size_t)half * 131072 + (kt << 6);
    u16* dst = lds + buf * 24576 + half * 8192 + tid * 8;
    llds16(src, dst);
    llds16(src + 65536, dst + 4096);
  };
  auto stageB = [&](int kt, int buf) {             // 2 loads (128 rows)
    const u16* src = pB + (kt << 6);
    u16* dst = lds + buf * 24576 + 16384 + tid * 8;
    llds16(src, dst);
    llds16(src + 65536, dst + 4096);
  };
  auto loadA4 = [&](const u16* Ab, int ib) {
#pragma unroll
    for (int ii = 0; ii < 4; ii++) {
      const u16* r = Ab + (ib + ii) * 1024;
      a_[ib + ii][0] = *(const bf16x8*)(r + rsw0);
      a_[ib + ii][1] = *(const bf16x8*)(r + rsw1);
    }
  };
  auto loadB2 = [&](const u16* Bb) {
#pragma unroll
    for (int jj = 0; jj < 2; jj++) {
      const u16* r = Bb + jj * 1024;
      b_[jj][0] = *(const bf16x8*)(r + rsw0);
      b_[jj][1] = *(const bf16x8*)(r + rsw1);
    }
  };
  auto mfma16 = [&](int ib) {
    __builtin_amdgcn_s_setprio(1);
#pragma unroll
    for (int jj = 0; jj < 2; jj++)
#pragma unroll
      for (int ii = 0; ii < 4; ii++) {
        acc[ib+ii][jj] = __builtin_amdgcn_mfma_f32_16x16x32_bf16(
            a_[ib+ii][0], b_[jj][0], acc[ib+ii][jj], 0, 0, 0);
        acc[ib+ii][jj] = __builtin_amdgcn_mfma_f32_16x16x32_bf16(
            a_[ib+ii][1], b_[jj][1], acc[ib+ii][jj], 0, 0, 0);
      }
    __builtin_amdgcn_s_setprio(0);
  };
  auto mfma8 = [&](int ib, int jj) {
    __builtin_amdgcn_s_setprio(1);
#pragma unroll
    for (int ii = 0; ii < 4; ii++) {
      acc[ib+ii][jj] = __builtin_amdgcn_mfma_f32_16x16x32_bf16(
          a_[ib+ii][0], b_[jj][0], acc[ib+ii][jj], 0, 0, 0);
      acc[ib+ii][jj] = __builtin_amdgcn_mfma_f32_16x16x32_bf16(
          a_[ib+ii][1], b_[jj][1], acc[ib+ii][jj], 0, 0, 0);
    }
    __builtin_amdgcn_s_setprio(0);
  };

  // prologue: buf0 <- K-tile 0 (A0,A1,B = 6 loads), buf1.A0 <- K-tile 1 (2)
  stageA(0, 0, 0);
  stageA(0, 0, 1);
  stageB(0, 0);
  stageA(1, 1, 0);
  asm volatile("s_waitcnt vmcnt(2)" ::: "memory");
  __builtin_amdgcn_s_barrier();

  const int NTI = 8;   // K / 128
  for (int t = 0; t < NTI; ++t) {
    const bool st = (t < NTI - 1);
    const int ka = 2 * t + 1;
    const int kb = 2 * t + 2;
    const int kc = 2 * t + 3;

    // ---- K-tile 2t from buf0 ----
    loadA4(Ab0, 0); loadB2(Bb0);
    stageA(ka, 1, 1);
    __builtin_amdgcn_s_barrier();
    mfma16(0);
    __builtin_amdgcn_s_barrier();
    loadA4(Ab0, 4);
    stageB(ka, 1);
    __builtin_amdgcn_s_barrier();
    mfma8(4, 0);
    __builtin_amdgcn_s_barrier();
    if (st) stageA(kb, 0, 0);
    __builtin_amdgcn_s_barrier();
    mfma8(4, 1);
    if (st) { asm volatile("s_waitcnt vmcnt(2)" ::: "memory"); }
    else    { asm volatile("s_waitcnt vmcnt(0)" ::: "memory"); }
    __builtin_amdgcn_s_barrier();

    // ---- K-tile 2t+1 from buf1 ----
    loadA4(Ab1, 0); loadB2(Bb1);
    if (st) stageA(kb, 0, 1);
    __builtin_amdgcn_s_barrier();
    mfma16(0);
    __builtin_amdgcn_s_barrier();
    loadA4(Ab1, 4);
    if (st) stageB(kb, 0);
    __builtin_amdgcn_s_barrier();
    mfma8(4, 0);
    __builtin_amdgcn_s_barrier();
    if (st) stageA(kc, 1, 0);
    __builtin_amdgcn_s_barrier();
    mfma8(4, 1);
    if (st) { asm volatile("s_waitcnt vmcnt(2)" ::: "memory"); }
    __builtin_amdgcn_s_barrier();
  }

  // epilogue: fp32 direct stores with bias
#pragma unroll
  for (int j = 0; j < 2; j++) {
    const int n = n0 + wn + j * 16 + fr;
    const float bb = bo[n];
#pragma unroll
    for (int i = 0; i < 8; i++) {
#pragma unroll
      for (int r = 0; r < 4; r++) {
        const int m = m0 + wm + i * 16 + g * 4 + r;
        out[(size_t)m * 1024 + n] = acc[i][j][r] + bb;
      }
    }
  }
}

// ---------------- MFMA flash attention: single q-tile, PV deferred, 3 blocks/CU ----------------
__global__ __launch_bounds__(256, 3) void attn_fa(
    const u16* __restrict__ Qb, const u16* __restrict__ Kb,
    const u16* __restrict__ VT, u16* __restrict__ Ob)
{
  __shared__ u16 k_s[2 * 4096];      // dbuf [kn][d], 16B-chunks XOR'd by row
  __shared__ u16 v_s[2 * 4096];      // dbuf [dn][k], same swizzle (lags K by 1 tile)
  __shared__ u16 p_s[128 * 72];      // [q][key] bf16, stride 72 (wave-private rows)
  __shared__ float l_s[128];

  const int tid = threadIdx.x;
  const int lane = tid & 63;
  const int wave = tid >> 6;
  const int bid = (int)blockIdx.x;
  const int qt = 15 - (bid >> 6);               // big tiles first
  const int bh = (((bid >> 3) & 7) << 3) | (bid & 7);   // bh % 8 == bid % 8 (XCD)
  const size_t head = (size_t)bh << 17;
  const int fr = lane & 15;
  const int g = lane >> 4;
  const int k8 = g << 3;
  const int q0 = qt << 7;
  const int wrow = wave << 5;

  // Q fragments (pre-scaled); loop-invariant B-operands
  bf16x8 aq[2][2];
#pragma unroll
  for (int f = 0; f < 2; f++) {
    const u16* qp = Qb + head + (size_t)(q0 + wrow + (f << 4) + fr) * 64;
    aq[f][0] = *(const bf16x8*)(qp + k8);
    aq[f][1] = *(const bf16x8*)(qp + 32 + k8);
  }

  // ---- hoisted lane-constant offsets ----
  const int r0 = tid >> 3, c0 = tid & 7;
  const int r1 = 32 + r0;
  const int koff0 = r0 * 64 + (((c0 ^ r0) & 7) << 3);     // K staging src offsets
  const int koff1 = r1 * 64 + (((c0 ^ r1) & 7) << 3);
  const int voff0 = r0 * 2048 + (((c0 ^ r0) & 7) << 3);   // V^T staging src offsets
  const int voff1 = r1 * 2048 + (((c0 ^ r1) & 7) << 3);
  int kaddr[4][2], vaddr[2][4];                           // fragment-read offsets
#pragma unroll
  for (int j = 0; j < 4; j++) {
    const int kn = (j << 4) + fr;
    kaddr[j][0] = kn * 64 + (((g ^ kn) & 7) << 3);
    kaddr[j][1] = kn * 64 + ((((g + 4) ^ kn) & 7) << 3);
#pragma unroll
    for (int s2 = 0; s2 < 2; s2++)
      vaddr[s2][j] = kn * 64 + ((((s2 << 2) + g) ^ (kn & 7)) << 3);
  }
  u16* const prow0 = p_s + (wrow + fr) * 72;        // q row f=0 (write cols & read k8)
  u16* const prow1 = p_s + (wrow + 16 + fr) * 72;   // q row f=1
  const u16* Kbase = Kb + head;
  const u16* Vbase = VT + head;

  auto issueK = [&](int jt2, int buf) {
    const u16* Kt = Kbase + ((size_t)jt2 << 12);
    llds16(Kt + koff0, k_s + (buf << 12) + tid * 8);
    llds16(Kt + koff1, k_s + (buf << 12) + 2048 + tid * 8);
  };
  auto issueV = [&](int jt2, int buf) {
    const u16* Vt = Vbase + (jt2 << 6);
    llds16(Vt + voff0, v_s + (buf << 12) + tid * 8);
    llds16(Vt + voff1, v_s + (buf << 12) + 2048 + tid * 8);
  };

  f32x4 o_acc[2][4];
  const f32x4 zero = {0.f, 0.f, 0.f, 0.f};
#pragma unroll
  for (int f = 0; f < 2; f++)
#pragma unroll
    for (int j = 0; j < 4; j++) o_acc[f][j] = zero;
  float l_run[2] = {0.f, 0.f};

  const int jmax = 2 * qt + 1;                 // jmax+1 iterations (even count)
  const int jt_diag = 2 * qt + (wave >> 1);    // per-wave diagonal tile

  auto do_pv = [&](const u16* vs) {
#pragma unroll
    for (int s2 = 0; s2 < 2; s2++) {
      const bf16x8 ap0 = *(const bf16x8*)(prow0 + (s2 << 5) + k8);
      const bf16x8 ap1 = *(const bf16x8*)(prow1 + (s2 << 5) + k8);
#pragma unroll
      for (int j = 0; j < 4; j++) {
        const bf16x8 bv = *(const bf16x8*)(vs + vaddr[s2][j]);
        o_acc[0][j] = __builtin_amdgcn_mfma_f32_16x16x32_bf16(ap0, bv, o_acc[0][j], 0, 0, 0);
        o_acc[1][j] = __builtin_amdgcn_mfma_f32_16x16x32_bf16(ap1, bv, o_acc[1][j], 0, 0, 0);
      }
    }
  };

  auto do_s = [&](const u16* ks, bool dodiag, int jt) {
    f32x4 s_acc[2][4];
#pragma unroll
    for (int f = 0; f < 2; f++)
#pragma unroll
      for (int j = 0; j < 4; j++) s_acc[f][j] = zero;
#pragma unroll
    for (int j = 0; j < 4; j++) {
      const bf16x8 ka0 = *(const bf16x8*)(ks + kaddr[j][0]);
      const bf16x8 ka1 = *(const bf16x8*)(ks + kaddr[j][1]);
      s_acc[0][j] = __builtin_amdgcn_mfma_f32_16x16x32_bf16(ka0, aq[0][0], s_acc[0][j], 0, 0, 0);
      s_acc[0][j] = __builtin_amdgcn_mfma_f32_16x16x32_bf16(ka1, aq[0][1], s_acc[0][j], 0, 0, 0);
      s_acc[1][j] = __builtin_amdgcn_mfma_f32_16x16x32_bf16(ka0, aq[1][0], s_acc[1][j], 0, 0, 0);
      s_acc[1][j] = __builtin_amdgcn_mfma_f32_16x16x32_bf16(ka1, aq[1][1], s_acc[1][j], 0, 0, 0);
    }
#pragma unroll
    for (int f = 0; f < 2; f++) {
      const int qa = q0 + wrow + (f << 4) + fr;
      u16* prow = (f == 0) ? prow0 : prow1;
      if (dodiag) {
#pragma unroll
        for (int j = 0; j < 4; j++) {
          const int kb = (jt << 6) + (j << 4) + (g << 2);
          float p0 = (kb + 0 > qa) ? 0.f : __builtin_amdgcn_exp2f(s_acc[f][j][0]);
          float p1 = (kb + 1 > qa) ? 0.f : __builtin_amdgcn_exp2f(s_acc[f][j][1]);
          float p2 = (kb + 2 > qa) ? 0.f : __builtin_amdgcn_exp2f(s_acc[f][j][2]);
          float p3 = (kb + 3 > qa) ? 0.f : __builtin_amdgcn_exp2f(s_acc[f][j][3]);
          l_run[f] += (p0 + p1) + (p2 + p3);
          union { __hip_bfloat162 h; unsigned u; } ca, cb;
          ca.h = __float22bfloat162_rn(make_float2(p0, p1));
          cb.h = __float22bfloat162_rn(make_float2(p2, p3));
          *(uint2*)(prow + (j << 4) + (g << 2)) = make_uint2(ca.u, cb.u);
        }
      } else {
#pragma unroll
        for (int j = 0; j < 4; j++) {
          float p0 = __builtin_amdgcn_exp2f(s_acc[f][j][0]);
          float p1 = __builtin_amdgcn_exp2f(s_acc[f][j][1]);
          float p2 = __builtin_amdgcn_exp2f(s_acc[f][j][2]);
          float p3 = __builtin_amdgcn_exp2f(s_acc[f][j][3]);
          l_run[f] += (p0 + p1) + (p2 + p3);
          union { __hip_bfloat162 h; unsigned u; } ca, cb;
          ca.h = __float22bfloat162_rn(make_float2(p0, p1));
          cb.h = __float22bfloat162_rn(make_float2(p2, p3));
          *(uint2*)(prow + (j << 4) + (g << 2)) = make_uint2(ca.u, cb.u);
        }
      }
    }
  };

  issueK(0, 0);   // prime K pipeline (V(0) issued inside iteration 0)

  for (int jt = 0; jt <= jmax; jt++) {
    const int kb = jt & 1;
    __syncthreads();                       // K(jt) + V(jt-1) landed; LDS reads drained
    if (jt < jmax) issueK(jt + 1, kb ^ 1);
    issueV(jt, kb);
    if (jt > 0 && jt - 1 <= jt_diag) do_pv(v_s + ((kb ^ 1) << 12));   // deferred PV
    if (jt <= jt_diag) do_s(k_s + (kb << 12), jt == jt_diag, jt);
  }
  __syncthreads();                         // V(jmax) landed
  if (jt_diag == jmax) do_pv(v_s + ((jmax & 1) << 12));   // waves 2,3 final PV

  // epilogue: reduce l (q-col lives in lanes fr, fr+16, fr+32, fr+48)
#pragma unroll
  for (int f = 0; f < 2; f++) {
    float l = l_run[f];
    l += __shfl_xor(l, 16);
    l += __shfl_xor(l, 32);
    if (g == 0) l_s[wrow + (f << 4) + fr] = l;   // wave-private slot
  }
  const int b = bh >> 4, h = bh & 15;
#pragma unroll
  for (int f = 0; f < 2; f++) {
#pragma unroll
    for (int r = 0; r < 4; r++) {
      const int qloc = wrow + (f << 4) + (g << 2) + r;
      const float inv = 1.f / l_s[qloc];
      const int q_abs = q0 + qloc;
#pragma unroll
      for (int j = 0; j < 4; j++)
        Ob[((size_t)b * 2048 + q_abs) * 1024 + (h << 6) + (j << 4) + fr] =
            f2bf(o_acc[f][j][r] * inv);
    }
  }
}

// ---------------- launch ----------------
extern "C" void kernel_launch(void* const* d_in, const int* in_sizes, int n_in,
                              void* d_out, int out_size, void* d_ws, size_t ws_size,
                              hipStream_t stream) {
  const float* x  = (const float*)d_in[0];
  const float* Wq = (const float*)d_in[1];
  const float* bq = (const float*)d_in[2];
  const float* Wk = (const float*)d_in[3];
  const float* bk = (const float*)d_in[4];
  const float* Wv = (const float*)d_in[5];
  const float* bv = (const float*)d_in[6];
  const float* Wo = (const float*)d_in[7];
  const float* bo = (const float*)d_in[8];
  float* out = (float*)d_out;

  char* ws = (char*)d_ws;
  u16* xb    = (u16*)(ws);                 // 16 MB; dead after QKV GEMM
  u16* attnb = (u16*)(ws);                 // aliases xb (dead by then)
  u16* wqkv  = (u16*)(ws + 16777216);      // 6 MB packed q|k|v weights
  u16* wo    = (u16*)(ws + 23068672);      // 2 MB
  u16* qkv   = (u16*)(ws + 25165824);      // 32 MB: Q | K  [BH][S][DH]
  u16* vT    = (u16*)(ws + 58720256);      // 16 MB: V^T [BH][64][S]
  // total ws: 75,497,472 B

  // fused cast: x + all 4 weight matrices, one launch
  cast_all_kernel<<<12288, 256, 0, stream>>>(x, Wq, Wk, Wv, Wo, xb, wqkv, wo);

  // fused QKV projection + V-transpose: M=8192, N=3072, K=1024
  gemm_qkv_256<<<dim3(512), 512, 0, stream>>>(xb, wqkv, bq, bk, bv, qkv, vT);

  // MFMA flash attention (single q-tile/block, big-first dispatch, 3 blocks/CU)
  // writes attnb over the now-dead xb region
  attn_fa<<<dim3(1024), 256, 0, stream>>>(qkv, qkv + 8388608, vT, attnb);

  // output projection: M=8192, N=1024, K=1024 (256x128 6-phase, 1 clean round)
  gemm_o_256<<<dim3(256), 512, 0, stream>>>(attnb, wo, bo, out);
}

// Round 9
// 229.888 us; speedup vs baseline: 1.4153x; 1.0375x over previous
//
#include <hip/hip_runtime.h>
#include <hip/hip_bf16.h>
#include <cstdint>
#include <cstddef>

// B=4, S=2048, D=1024, H=16, DH=64.  M = B*S = 8192.
// fused cast (x + 4 weights, one launch); fused QKV GEMM via 256x192-tile
// 8-phase pipelined MFMA kernel (T2 swizzle + counted-vmcnt + setprio, raw
// s_barrier) WITH FUSED V-TRANSPOSE EPILOGUE (Q/K stored [BH][S][DH], V
// stored directly as V^T [BH][DH][S]); MFMA flash attention (single q-tile,
// big-first dispatch, 3 blocks/CU, qt-PRIORITY LADDER: long-stream blocks
// run at wave-prio 2/1 so the 32-iteration critical path wins CU
// arbitration against co-resident short blocks); output GEMM via
// 256x128-tile 6-phase kernel (1 clean round).
// Workspace 75,497,472 B: xb/attnb 16M | wqkv 6M | wo 2M | Q,K 32M | vT 16M.

typedef unsigned short u16;
typedef __bf16 bf16x8 __attribute__((ext_vector_type(8)));
typedef float  f32x4  __attribute__((ext_vector_type(4)));

__device__ __forceinline__ u16 f2bf(float f) {
  unsigned u = __float_as_uint(f);
  unsigned r = u + 0x7fffu + ((u >> 16) & 1u);   // RNE
  return (u16)(r >> 16);
}

// async global->LDS, 16B per lane (dest = wave-uniform base + lane*16)
__device__ __forceinline__ void llds16(const u16* g, u16* l) {
  __builtin_amdgcn_global_load_lds(
      (const __attribute__((address_space(1))) void*)g,
      (__attribute__((address_space(3))) void*)l, 16, 0, 0);
}

// ---------------- fused cast fp32 -> bf16 (x + Wq,Wk,Wv,Wo) ----------------
__global__ void cast_all_kernel(const float* __restrict__ x,
                                const float* __restrict__ Wq, const float* __restrict__ Wk,
                                const float* __restrict__ Wv, const float* __restrict__ Wo,
                                u16* __restrict__ xb, u16* __restrict__ wqkv,
                                u16* __restrict__ wo) {
  const int bid = (int)blockIdx.x;
  const int tid = threadIdx.x;
  if (bid < 8192) {
    const int i = (bid << 8) + tid;
    float4 f = ((const float4*)x)[i];
    ushort4 u;
    u.x = f2bf(f.x); u.y = f2bf(f.y); u.z = f2bf(f.z); u.w = f2bf(f.w);
    ((ushort4*)xb)[i] = u;
  } else {
    const int j = ((bid - 8192) << 8) + tid;   // 0..1048575
    const int w = j >> 18;                     // 0..3
    const int idx = j & 262143;
    const float* src = (w == 0) ? Wq : (w == 1) ? Wk : (w == 2) ? Wv : Wo;
    u16* dst = (w == 3) ? wo : (wqkv + (w << 20));
    float4 f = ((const float4*)src)[idx];
    ushort4 u;
    u.x = f2bf(f.x); u.y = f2bf(f.y); u.z = f2bf(f.z); u.w = f2bf(f.w);
    ((ushort4*)dst)[idx] = u;
  }
}

// ---------------- 256x192 8-phase QKV GEMM + fused V-transpose ----------------
__global__ __launch_bounds__(512) void gemm_qkv_256(
    const u16* __restrict__ A, const u16* __restrict__ Bw,
    const float* __restrict__ b0, const float* __restrict__ b1, const float* __restrict__ b2,
    u16* __restrict__ qkv_out, u16* __restrict__ vT_out)
{
  __shared__ u16 lds[57344];   // 112 KiB (reused as epilogue staging)

  const int tid = threadIdx.x;
  const int lane = tid & 63;
  const int wave = tid >> 6;

  // XCD-grouped decode: xcd = bid&7; each XCD owns 4 m-panels x all 16 n-tiles.
  const int bid = (int)blockIdx.x;
  const int xcd = bid & 7;
  const int idx = bid >> 3;                 // 0..63
  const int mt = (xcd << 2) | (idx & 3);    // 0..31
  const int nt = idx >> 2;                  // 0..15
  const int m0 = mt << 8;
  const int n0 = nt * 192;

  const int warp_m = wave >> 2;       // 0..1
  const int warp_n = wave & 3;        // 0..3
  const int wm = warp_m << 7;         // 0,128
  const int wn = warp_n * 48;         // 0,48,96,144
  const int fr = lane & 15;
  const int g  = lane >> 4;           // 0..3

  // staging source (pre-swizzled global addr so linear LDS dest lands swizzled)
  const int srow = tid >> 3;                       // 0..63
  const int schk = ((tid & 7) ^ (srow & 7)) << 3;  // stored chunk -> logical col
  const u16* pA = A  + (size_t)(m0 + srow) * 1024 + schk;
  const u16* pB = Bw + (size_t)(n0 + srow) * 1024 + schk;

  // fragment-read swizzled chunk offsets (chunk = s*4+g, stored = chunk^(row&7))
  const int rsw0 = ((g    ) ^ (fr & 7)) << 3;
  const int rsw1 = ((g ^ 4) ^ (fr & 7)) << 3;

  // read bases (include fr*64 row offset); buf stride 28672 u16
  const u16* Ab0 = lds + (size_t)(wm + fr) * 64;
  const u16* Bb0 = lds + 16384 + (size_t)(wn + fr) * 64;
  const u16* Ab1 = Ab0 + 28672;
  const u16* Bb1 = Bb0 + 28672;

  f32x4 acc[8][3];
  const f32x4 zero = {0.f, 0.f, 0.f, 0.f};
#pragma unroll
  for (int i = 0; i < 8; i++)
#pragma unroll
    for (int j = 0; j < 3; j++) acc[i][j] = zero;

  bf16x8 a_[4][2];
  bf16x8 b_[3][2];

  auto stageA = [&](int kt, int buf, int half) {   // 2 loads (128 rows)
    const u16* src = pA + (size_t)half * 131072 + (kt << 6);
    u16* dst = lds + buf * 28672 + half * 8192 + tid * 8;
    llds16(src, dst);
    llds16(src + 65536, dst + 4096);
  };
  auto stageB0 = [&](int kt, int buf) {            // 2 loads (rows 0-127)
    const u16* src = pB + (kt << 6);
    u16* dst = lds + buf * 28672 + 16384 + tid * 8;
    llds16(src, dst);
    llds16(src + 65536, dst + 4096);
  };
  auto stageB1 = [&](int kt, int buf) {            // 1 load (rows 128-191)
    const u16* src = pB + 131072 + (kt << 6);
    u16* dst = lds + buf * 28672 + 24576 + tid * 8;
    llds16(src, dst);
  };
  auto loadA4 = [&](const u16* Ab, int ib) {
#pragma unroll
    for (int ii = 0; ii < 4; ii++) {
      const u16* r = Ab + (ib + ii) * 1024;
      a_[ii][0] = *(const bf16x8*)(r + rsw0);
      a_[ii][1] = *(const bf16x8*)(r + rsw1);
    }
  };
  auto loadB = [&](const u16* Bb, int j0, int nj) {
#pragma unroll
    for (int jj = 0; jj < 3; jj++) {
      if (jj < nj) {
        const u16* r = Bb + (j0 + jj) * 1024;
        b_[j0 + jj][0] = *(const bf16x8*)(r + rsw0);
        b_[j0 + jj][1] = *(const bf16x8*)(r + rsw1);
      }
    }
  };
  auto mfmaQ = [&](int ib, int j0, int nj) {
    __builtin_amdgcn_s_setprio(1);
#pragma unroll
    for (int jj = 0; jj < 3; jj++) {
      if (jj < nj) {
#pragma unroll
        for (int ii = 0; ii < 4; ii++) {
          acc[ib+ii][j0+jj] = __builtin_amdgcn_mfma_f32_16x16x32_bf16(
              a_[ii][0], b_[j0+jj][0], acc[ib+ii][j0+jj], 0, 0, 0);
          acc[ib+ii][j0+jj] = __builtin_amdgcn_mfma_f32_16x16x32_bf16(
              a_[ii][1], b_[j0+jj][1], acc[ib+ii][j0+jj], 0, 0, 0);
        }
      }
    }
    __builtin_amdgcn_s_setprio(0);
  };

  // prologue: buf0 <- K-tile 0 (A0,A1,B0,B1 = 7 loads), buf1.A0 <- K-tile 1 (2)
  stageA(0, 0, 0);
  stageA(0, 0, 1);
  stageB0(0, 0);
  stageB1(0, 0);
  stageA(1, 1, 0);
  asm volatile("s_waitcnt vmcnt(2)" ::: "memory");  // tile0 landed; tile1.A0 in flight
  __builtin_amdgcn_s_barrier();

  const int NTI = 8;   // K / 128
  for (int t = 0; t < NTI; ++t) {
    const bool st = (t < NTI - 1);
    const int ka = 2 * t + 1;
    const int kb = 2 * t + 2;
    const int kc = 2 * t + 3;

    // ---- K-tile 2t from buf0 ----
    // p0
    loadA4(Ab0, 0); loadB(Bb0, 0, 2);
    stageA(ka, 1, 1);
    __builtin_amdgcn_s_barrier();
    mfmaQ(0, 0, 2);
    __builtin_amdgcn_s_barrier();
    // p1
    loadB(Bb0, 2, 1);
    stageB0(ka, 1);
    __builtin_amdgcn_s_barrier();
    mfmaQ(0, 2, 1);
    __builtin_amdgcn_s_barrier();
    // p2
    loadA4(Ab0, 4);
    stageB1(ka, 1);
    __builtin_amdgcn_s_barrier();
    mfmaQ(4, 2, 1);
    __builtin_amdgcn_s_barrier();
    // p3 (no ds_reads -> MFMA starts with zero lgkm drain)
    if (st) stageA(kb, 0, 0);
    __builtin_amdgcn_s_barrier();
    mfmaQ(4, 0, 2);
    if (st) { asm volatile("s_waitcnt vmcnt(2)" ::: "memory"); }
    else    { asm volatile("s_waitcnt vmcnt(0)" ::: "memory"); }
    __builtin_amdgcn_s_barrier();

    // ---- K-tile 2t+1 from buf1 ----
    // p4
    loadA4(Ab1, 0); loadB(Bb1, 0, 2);
    if (st) stageA(kb, 0, 1);
    __builtin_amdgcn_s_barrier();
    mfmaQ(0, 0, 2);
    __builtin_amdgcn_s_barrier();
    // p5
    loadB(Bb1, 2, 1);
    if (st) stageB0(kb, 0);
    __builtin_amdgcn_s_barrier();
    mfmaQ(0, 2, 1);
    __builtin_amdgcn_s_barrier();
    // p6
    loadA4(Ab1, 4);
    if (st) stageB1(kb, 0);
    __builtin_amdgcn_s_barrier();
    mfmaQ(4, 2, 1);
    __builtin_amdgcn_s_barrier();
    // p7 (no ds_reads)
    if (st) stageA(kc, 1, 0);
    __builtin_amdgcn_s_barrier();
    mfmaQ(4, 0, 2);
    if (st) { asm volatile("s_waitcnt vmcnt(2)" ::: "memory"); }
    __builtin_amdgcn_s_barrier();
  }

  // ---- epilogue ----
  __syncthreads();
  const int bI  = m0 >> 11;
  const int s0m = m0 & 2047;
  // vs0 = first V-range local column (192 = none, 0 = all V; multiple of 64)
  const int vs0 = (n0 >= 2048) ? 0 : ((n0 + 192 <= 2048) ? 192 : (2048 - n0));

  // pass 1: Q/K columns -> row-major LDS [256][200] -> [BH][S][DH] stores
  if (vs0 > 0) {
#pragma unroll
    for (int j = 0; j < 3; j++) {
      const int cl = wn + j * 16 + fr;
      if (cl < vs0) {
        const int ncol = n0 + cl;
        const int which = ncol >> 10;             // 0 or 1 here
        const float bb = ((which == 0) ? b0 : b1)[ncol & 1023];
        const float post = (which == 0) ? 0.18033688011f : 1.0f;  // 0.125*log2(e)
#pragma unroll
        for (int i = 0; i < 8; i++) {
#pragma unroll
          for (int r = 0; r < 4; r++) {
            const int row = wm + i * 16 + g * 4 + r;
            lds[row * 200 + cl] = f2bf((acc[i][j][r] + bb) * post);
          }
        }
      }
    }
    __syncthreads();
    const int part = tid & 7;
#pragma unroll
    for (int p = 0; p < 12; p++) {
      const int hc = p >> 2;
      if (hc * 64 < vs0) {                        // chunk fully Q/K
        const int ml = ((p & 3) << 6) + (tid >> 3);
        const int ncol0 = n0 + hc * 64;
        const int which = ncol0 >> 10;
        const int h = (ncol0 >> 6) & 15;
        const bf16x8 v = *(const bf16x8*)(lds + ml * 200 + hc * 64 + part * 8);
        *(bf16x8*)(qkv_out + (size_t)which * 8388608 +
                   ((size_t)(bI * 16 + h) * 2048 + s0m + ml) * 64 + part * 8) = v;
      }
    }
  }

  // pass 2: V columns -> col-major LDS [clv][264] -> coalesced V^T [BH][DH][S]
  if (vs0 < 192) {
    __syncthreads();                              // pass-1 LDS reads drained
#pragma unroll
    for (int j = 0; j < 3; j++) {
      const int cl = wn + j * 16 + fr;
      const int clv = cl - vs0;
      if (clv >= 0) {
        const int ncol = n0 + cl;
        const float bb = b2[ncol & 1023];
#pragma unroll
        for (int i = 0; i < 8; i++) {
#pragma unroll
          for (int r = 0; r < 4; r++) {
            const int row = wm + i * 16 + g * 4 + r;
            lds[clv * 264 + row] = f2bf(acc[i][j][r] + bb);
          }
        }
      }
    }
    __syncthreads();
    const int vcols = 192 - vs0;
    const int mg = tid & 31;                      // s-group: lanes contiguous in s
    const int cidx = tid >> 5;                    // 0..15
    for (int cc = cidx; cc < vcols; cc += 16) {
      const int ncol = n0 + vs0 + cc;
      const int h = (ncol >> 6) & 15;
      const int dh = ncol & 63;
      const bf16x8 v = *(const bf16x8*)(lds + cc * 264 + mg * 8);
      *(bf16x8*)(vT_out + ((size_t)(bI * 16 + h) * 64 + dh) * 2048 + s0m + mg * 8) = v;
    }
  }
}

// ---------------- 256x128 6-phase output GEMM: out = attn * Wo^T + bo (fp32) ----------------
__global__ __launch_bounds__(512) void gemm_o_256(
    const u16* __restrict__ A, const u16* __restrict__ Bw,
    const float* __restrict__ bo, float* __restrict__ out)
{
  __shared__ u16 lds[49152];   // 96 KiB

  const int tid = threadIdx.x;
  const int lane = tid & 63;
  const int wave = tid >> 6;

  const int bid = (int)blockIdx.x;
  const int xcd = bid & 7;
  const int idx = bid >> 3;                 // 0..31
  const int mt = (xcd << 2) | (idx & 3);    // 0..31
  const int nt = idx >> 2;                  // 0..7
  const int m0 = mt << 8;
  const int n0 = nt << 7;

  const int warp_m = wave >> 2;
  const int warp_n = wave & 3;
  const int wm = warp_m << 7;
  const int wn = warp_n << 5;               // 0,32,64,96
  const int fr = lane & 15;
  const int g  = lane >> 4;

  const int srow = tid >> 3;
  const int schk = ((tid & 7) ^ (srow & 7)) << 3;
  const u16* pA = A  + (size_t)(m0 + srow) * 1024 + schk;
  const u16* pB = Bw + (size_t)(n0 + srow) * 1024 + schk;

  const int rsw0 = ((g    ) ^ (fr & 7)) << 3;
  const int rsw1 = ((g ^ 4) ^ (fr & 7)) << 3;

  const u16* Ab0 = lds + (size_t)(wm + fr) * 64;
  const u16* Bb0 = lds + 16384 + (size_t)(wn + fr) * 64;
  const u16* Ab1 = Ab0 + 24576;
  const u16* Bb1 = Bb0 + 24576;

  f32x4 acc[8][2];
  const f32x4 zero = {0.f, 0.f, 0.f, 0.f};
#pragma unroll
  for (int i = 0; i < 8; i++)
#pragma unroll
    for (int j = 0; j < 2; j++) acc[i][j] = zero;

  bf16x8 a_[8][2];
  bf16x8 b_[2][2];

  auto stageA = [&](int kt, int buf, int half) {   // 2 loads (128 rows)
    const u16* src = pA + (size_t)half * 131072 + (kt << 6);
    u16* dst = lds + buf * 24576 + half * 8192 + tid * 8;
    llds16(src, dst);
    llds16(src + 65536, dst + 4096);
  };
  auto stageB = [&](int kt, int buf) {             // 2 loads (128 rows)
    const u16* src = pB + (kt << 6);
    u16* dst = lds + buf * 24576 + 16384 + tid * 8;
    llds16(src, dst);
    llds16(src + 65536, dst + 4096);
  };
  auto loadA4 = [&](const u16* Ab, int ib) {
#pragma unroll
    for (int ii = 0; ii < 4; ii++) {
      const u16* r = Ab + (ib + ii) * 1024;
      a_[ib + ii][0] = *(const bf16x8*)(r + rsw0);
      a_[ib + ii][1] = *(const bf16x8*)(r + rsw1);
    }
  };
  auto loadB2 = [&](const u16* Bb) {
#pragma unroll
    for (int jj = 0; jj < 2; jj++) {
      const u16* r = Bb + jj * 1024;
      b_[jj][0] = *(const bf16x8*)(r + rsw0);
      b_[jj][1] = *(const bf16x8*)(r + rsw1);
    }
  };
  auto mfma16 = [&](int ib) {
    __builtin_amdgcn_s_setprio(1);
#pragma unroll
    for (int jj = 0; jj < 2; jj++)
#pragma unroll
      for (int ii = 0; ii < 4; ii++) {
        acc[ib+ii][jj] = __builtin_amdgcn_mfma_f32_16x16x32_bf16(
            a_[ib+ii][0], b_[jj][0], acc[ib+ii][jj], 0, 0, 0);
        acc[ib+ii][jj] = __builtin_amdgcn_mfma_f32_16x16x32_bf16(
            a_[ib+ii][1], b_[jj][1], acc[ib+ii][jj], 0, 0, 0);
      }
    __builtin_amdgcn_s_setprio(0);
  };
  auto mfma8 = [&](int ib, int jj) {
    __builtin_amdgcn_s_setprio(1);
#pragma unroll
    for (int ii = 0; ii < 4; ii++) {
      acc[ib+ii][jj] = __builtin_amdgcn_mfma_f32_16x16x32_bf16(
          a_[ib+ii][0], b_[jj][0], acc[ib+ii][jj], 0, 0, 0);
      acc[ib+ii][jj] = __builtin_amdgcn_mfma_f32_16x16x32_bf16(
          a_[ib+ii][1], b_[jj][1], acc[ib+ii][jj], 0, 0, 0);
    }
    __builtin_amdgcn_s_setprio(0);
  };

  // prologue: buf0 <- K-tile 0 (A0,A1,B = 6 loads), buf1.A0 <- K-tile 1 (2)
  stageA(0, 0, 0);
  stageA(0, 0, 1);
  stageB(0, 0);
  stageA(1, 1, 0);
  asm volatile("s_waitcnt vmcnt(2)" ::: "memory");
  __builtin_amdgcn_s_barrier();

  const int NTI = 8;   // K / 128
  for (int t = 0; t < NTI; ++t) {
    const bool st = (t < NTI - 1);
    const int ka = 2 * t + 1;
    const int kb = 2 * t + 2;
    const int kc = 2 * t + 3;

    // ---- K-tile 2t from buf0 ----
    loadA4(Ab0, 0); loadB2(Bb0);
    stageA(ka, 1, 1);
    __builtin_amdgcn_s_barrier();
    mfma16(0);
    __builtin_amdgcn_s_barrier();
    loadA4(Ab0, 4);
    stageB(ka, 1);
    __builtin_amdgcn_s_barrier();
    mfma8(4, 0);
    __builtin_amdgcn_s_barrier();
    if (st) stageA(kb, 0, 0);
    __builtin_amdgcn_s_barrier();
    mfma8(4, 1);
    if (st) { asm volatile("s_waitcnt vmcnt(2)" ::: "memory"); }
    else    { asm volatile("s_waitcnt vmcnt(0)" ::: "memory"); }
    __builtin_amdgcn_s_barrier();

    // ---- K-tile 2t+1 from buf1 ----
    loadA4(Ab1, 0); loadB2(Bb1);
    if (st) stageA(kb, 0, 1);
    __builtin_amdgcn_s_barrier();
    mfma16(0);
    __builtin_amdgcn_s_barrier();
    loadA4(Ab1, 4);
    if (st) stageB(kb, 0);
    __builtin_amdgcn_s_barrier();
    mfma8(4, 0);
    __builtin_amdgcn_s_barrier();
    if (st) stageA(kc, 1, 0);
    __builtin_amdgcn_s_barrier();
    mfma8(4, 1);
    if (st) { asm volatile("s_waitcnt vmcnt(2)" ::: "memory"); }
    __builtin_amdgcn_s_barrier();
  }

  // epilogue: fp32 direct stores with bias
#pragma unroll
  for (int j = 0; j < 2; j++) {
    const int n = n0 + wn + j * 16 + fr;
    const float bb = bo[n];
#pragma unroll
    for (int i = 0; i < 8; i++) {
#pragma unroll
      for (int r = 0; r < 4; r++) {
        const int m = m0 + wm + i * 16 + g * 4 + r;
        out[(size_t)m * 1024 + n] = acc[i][j][r] + bb;
      }
    }
  }
}

// ---------------- MFMA flash attention: single q-tile, PV deferred, 3 blocks/CU ----------------
// qt-priority ladder: the qt=15 block is a 32-iteration serial critical path
// sharing its CU with two short-qt blocks (9+ units of slack).  Long blocks
// run at wave-prio 2 (qt>=14) / 1 (qt>=8) so every CU arbitration (MFMA
// issue, VALU, vmem) favors the critical path; short blocks absorb delay.
__global__ __launch_bounds__(256, 3) void attn_fa(
    const u16* __restrict__ Qb, const u16* __restrict__ Kb,
    const u16* __restrict__ VT, u16* __restrict__ Ob)
{
  __shared__ u16 k_s[2 * 4096];      // dbuf [kn][d], 16B-chunks XOR'd by row
  __shared__ u16 v_s[2 * 4096];      // dbuf [dn][k], same swizzle (lags K by 1 tile)
  __shared__ u16 p_s[128 * 72];      // [q][key] bf16, stride 72 (wave-private rows)
  __shared__ float l_s[128];

  const int tid = threadIdx.x;
  const int lane = tid & 63;
  const int wave = tid >> 6;
  const int bid = (int)blockIdx.x;
  const int qt = 15 - (bid >> 6);               // big tiles first
  const int bh = (((bid >> 3) & 7) << 3) | (bid & 7);   // bh % 8 == bid % 8 (XCD)
  const size_t head = (size_t)bh << 17;
  const int fr = lane & 15;
  const int g = lane >> 4;
  const int k8 = g << 3;
  const int q0 = qt << 7;
  const int wrow = wave << 5;

  // critical-path priority ladder (wave-uniform; persists for the kernel)
  if (qt >= 14)     __builtin_amdgcn_s_setprio(2);
  else if (qt >= 8) __builtin_amdgcn_s_setprio(1);

  // Q fragments (pre-scaled); loop-invariant B-operands
  bf16x8 aq[2][2];
#pragma unroll
  for (int f = 0; f < 2; f++) {
    const u16* qp = Qb + head + (size_t)(q0 + wrow + (f << 4) + fr) * 64;
    aq[f][0] = *(const bf16x8*)(qp + k8);
    aq[f][1] = *(const bf16x8*)(qp + 32 + k8);
  }

  // ---- hoisted lane-constant offsets ----
  const int r0 = tid >> 3, c0 = tid & 7;
  const int r1 = 32 + r0;
  const int koff0 = r0 * 64 + (((c0 ^ r0) & 7) << 3);     // K staging src offsets
  const int koff1 = r1 * 64 + (((c0 ^ r1) & 7) << 3);
  const int voff0 = r0 * 2048 + (((c0 ^ r0) & 7) << 3);   // V^T staging src offsets
  const int voff1 = r1 * 2048 + (((c0 ^ r1) & 7) << 3);
  int kaddr[4][2], vaddr[2][4];                           // fragment-read offsets
#pragma unroll
  for (int j = 0; j < 4; j++) {
    const int kn = (j << 4) + fr;
    kaddr[j][0] = kn * 64 + (((g ^ kn) & 7) << 3);
    kaddr[j][1] = kn * 64 + ((((g + 4) ^ kn) & 7) << 3);
#pragma unroll
    for (int s2 = 0; s2 < 2; s2++)
      vaddr[s2][j] = kn * 64 + ((((s2 << 2) + g) ^ (kn & 7)) << 3);
  }
  u16* const prow0 = p_s + (wrow + fr) * 72;        // q row f=0 (write cols & read k8)
  u16* const prow1 = p_s + (wrow + 16 + fr) * 72;   // q row f=1
  const u16* Kbase = Kb + head;
  const u16* Vbase = VT + head;

  auto issueK = [&](int jt2, int buf) {
    const u16* Kt = Kbase + ((size_t)jt2 << 12);
    llds16(Kt + koff0, k_s + (buf << 12) + tid * 8);
    llds16(Kt + koff1, k_s + (buf << 12) + 2048 + tid * 8);
  };
  auto issueV = [&](int jt2, int buf) {
    const u16* Vt = Vbase + (jt2 << 6);
    llds16(Vt + voff0, v_s + (buf << 12) + tid * 8);
    llds16(Vt + voff1, v_s + (buf << 12) + 2048 + tid * 8);
  };

  f32x4 o_acc[2][4];
  const f32x4 zero = {0.f, 0.f, 0.f, 0.f};
#pragma unroll
  for (int f = 0; f < 2; f++)
#pragma unroll
    for (int j = 0; j < 4; j++) o_acc[f][j] = zero;
  float l_run[2] = {0.f, 0.f};

  const int jmax = 2 * qt + 1;                 // jmax+1 iterations (even count)
  const int jt_diag = 2 * qt + (wave >> 1);    // per-wave diagonal tile

  auto do_pv = [&](const u16* vs) {
#pragma unroll
    for (int s2 = 0; s2 < 2; s2++) {
      const bf16x8 ap0 = *(const bf16x8*)(prow0 + (s2 << 5) + k8);
      const bf16x8 ap1 = *(const bf16x8*)(prow1 + (s2 << 5) + k8);
#pragma unroll
      for (int j = 0; j < 4; j++) {
        const bf16x8 bv = *(const bf16x8*)(vs + vaddr[s2][j]);
        o_acc[0][j] = __builtin_amdgcn_mfma_f32_16x16x32_bf16(ap0, bv, o_acc[0][j], 0, 0, 0);
        o_acc[1][j] = __builtin_amdgcn_mfma_f32_16x16x32_bf16(ap1, bv, o_acc[1][j], 0, 0, 0);
      }
    }
  };

  auto do_s = [&](const u16* ks, bool dodiag, int jt) {
    f32x4 s_acc[2][4];
#pragma unroll
    for (int f = 0; f < 2; f++)
#pragma unroll
      for (int j = 0; j < 4; j++) s_acc[f][j] = zero;
#pragma unroll
    for (int j = 0; j < 4; j++) {
      const bf16x8 ka0 = *(const bf16x8*)(ks + kaddr[j][0]);
      const bf16x8 ka1 = *(const bf16x8*)(ks + kaddr[j][1]);
      s_acc[0][j] = __builtin_amdgcn_mfma_f32_16x16x32_bf16(ka0, aq[0][0], s_acc[0][j], 0, 0, 0);
      s_acc[0][j] = __builtin_amdgcn_mfma_f32_16x16x32_bf16(ka1, aq[0][1], s_acc[0][j], 0, 0, 0);
      s_acc[1][j] = __builtin_amdgcn_mfma_f32_16x16x32_bf16(ka0, aq[1][0], s_acc[1][j], 0, 0, 0);
      s_acc[1][j] = __builtin_amdgcn_mfma_f32_16x16x32_bf16(ka1, aq[1][1], s_acc[1][j], 0, 0, 0);
    }
#pragma unroll
    for (int f = 0; f < 2; f++) {
      const int qa = q0 + wrow + (f << 4) + fr;
      u16* prow = (f == 0) ? prow0 : prow1;
      if (dodiag) {
#pragma unroll
        for (int j = 0; j < 4; j++) {
          const int kb = (jt << 6) + (j << 4) + (g << 2);
          float p0 = (kb + 0 > qa) ? 0.f : __builtin_amdgcn_exp2f(s_acc[f][j][0]);
          float p1 = (kb + 1 > qa) ? 0.f : __builtin_amdgcn_exp2f(s_acc[f][j][1]);
          float p2 = (kb + 2 > qa) ? 0.f : __builtin_amdgcn_exp2f(s_acc[f][j][2]);
          float p3 = (kb + 3 > qa) ? 0.f : __builtin_amdgcn_exp2f(s_acc[f][j][3]);
          l_run[f] += (p0 + p1) + (p2 + p3);
          union { __hip_bfloat162 h; unsigned u; } ca, cb;
          ca.h = __float22bfloat162_rn(make_float2(p0, p1));
          cb.h = __float22bfloat162_rn(make_float2(p2, p3));
          *(uint2*)(prow + (j << 4) + (g << 2)) = make_uint2(ca.u, cb.u);
        }
      } else {
#pragma unroll
        for (int j = 0; j < 4; j++) {
          float p0 = __builtin_amdgcn_exp2f(s_acc[f][j][0]);
          float p1 = __builtin_amdgcn_exp2f(s_acc[f][j][1]);
          float p2 = __builtin_amdgcn_exp2f(s_acc[f][j][2]);
          float p3 = __builtin_amdgcn_exp2f(s_acc[f][j][3]);
          l_run[f] += (p0 + p1) + (p2 + p3);
          union { __hip_bfloat162 h; unsigned u; } ca, cb;
          ca.h = __float22bfloat162_rn(make_float2(p0, p1));
          cb.h = __float22bfloat162_rn(make_float2(p2, p3));
          *(uint2*)(prow + (j << 4) + (g << 2)) = make_uint2(ca.u, cb.u);
        }
      }
    }
  };

  issueK(0, 0);   // prime K pipeline (V(0) issued inside iteration 0)

  for (int jt = 0; jt <= jmax; jt++) {
    const int kb = jt & 1;
    __syncthreads();                       // K(jt) + V(jt-1) landed; LDS reads drained
    if (jt < jmax) issueK(jt + 1, kb ^ 1);
    issueV(jt, kb);
    if (jt > 0 && jt - 1 <= jt_diag) do_pv(v_s + ((kb ^ 1) << 12));   // deferred PV
    if (jt <= jt_diag) do_s(k_s + (kb << 12), jt == jt_diag, jt);
  }
  __syncthreads();                         // V(jmax) landed
  if (jt_diag == jmax) do_pv(v_s + ((jmax & 1) << 12));   // waves 2,3 final PV

  // epilogue: reduce l (q-col lives in lanes fr, fr+16, fr+32, fr+48)
#pragma unroll
  for (int f = 0; f < 2; f++) {
    float l = l_run[f];
    l += __shfl_xor(l, 16);
    l += __shfl_xor(l, 32);
    if (g == 0) l_s[wrow + (f << 4) + fr] = l;   // wave-private slot
  }
  const int b = bh >> 4, h = bh & 15;
#pragma unroll
  for (int f = 0; f < 2; f++) {
#pragma unroll
    for (int r = 0; r < 4; r++) {
      const int qloc = wrow + (f << 4) + (g << 2) + r;
      const float inv = 1.f / l_s[qloc];
      const int q_abs = q0 + qloc;
#pragma unroll
      for (int j = 0; j < 4; j++)
        Ob[((size_t)b * 2048 + q_abs) * 1024 + (h << 6) + (j << 4) + fr] =
            f2bf(o_acc[f][j][r] * inv);
    }
  }
}

// ---------------- launch ----------------
extern "C" void kernel_launch(void* const* d_in, const int* in_sizes, int n_in,
                              void* d_out, int out_size, void* d_ws, size_t ws_size,
                              hipStream_t stream) {
  const float* x  = (const float*)d_in[0];
  const float* Wq = (const float*)d_in[1];
  const float* bq = (const float*)d_in[2];
  const float* Wk = (const float*)d_in[3];
  const float* bk = (const float*)d_in[4];
  const float* Wv = (const float*)d_in[5];
  const float* bv = (const float*)d_in[6];
  const float* Wo = (const float*)d_in[7];
  const float* bo = (const float*)d_in[8];
  float* out = (float*)d_out;

  char* ws = (char*)d_ws;
  u16* xb    = (u16*)(ws);                 // 16 MB; dead after QKV GEMM
  u16* attnb = (u16*)(ws);                 // aliases xb (dead by then)
  u16* wqkv  = (u16*)(ws + 16777216);      // 6 MB packed q|k|v weights
  u16* wo    = (u16*)(ws + 23068672);      // 2 MB
  u16* qkv   = (u16*)(ws + 25165824);      // 32 MB: Q | K  [BH][S][DH]
  u16* vT    = (u16*)(ws + 58720256);      // 16 MB: V^T [BH][64][S]
  // total ws: 75,497,472 B

  // fused cast: x + all 4 weight matrices, one launch
  cast_all_kernel<<<12288, 256, 0, stream>>>(x, Wq, Wk, Wv, Wo, xb, wqkv, wo);

  // fused QKV projection + V-transpose: M=8192, N=3072, K=1024
  gemm_qkv_256<<<dim3(512), 512, 0, stream>>>(xb, wqkv, bq, bk, bv, qkv, vT);

  // MFMA flash attention (single q-tile/block, big-first dispatch, 3 blocks/CU,
  // qt-priority ladder); writes attnb over the now-dead xb region
  attn_fa<<<dim3(1024), 256, 0, stream>>>(qkv, qkv + 8388608, vT, attnb);

  // output projection: M=8192, N=1024, K=1024 (256x128 6-phase, 1 clean round)
  gemm_o_256<<<dim3(256), 512, 0, stream>>>(attnb, wo, bo, out);
}